// Round 12
// baseline (763.798 us; speedup 1.0000x reference)
//
#include <hip/hip_runtime.h>
#include <math.h>

// Performer encoder on MI355X: B=4, S=4096, D=256, H=4, DH=64, L=4, M=266.
// bf16 MFMA everywhere; fp32 residual stream / LN stats / softmax logic.
// Round 23: r22 base (750.8 µs) +
//   * gemm_fullrow templated on RT (row-tiles): K=256 instances (Wo, EPI2)
//     use RT=1 (16 rows, grid 1024 = 4 blocks/CU, LDS 34KB); K=1024 (FFN2)
//     keeps RT=2 (32 rows; 16-row would double B L2 traffic to ~512MB and
//     bind on L2 BW). Bit-exact: MFMA order + 8-wave LN reduce unchanged.
//   * pool_denom merged into pool_out (identical denom reduction per block;
//     one fewer dispatch, pdenom buffer removed).

#define WS_ALIGN(x) (((x) + 255) & ~(size_t)255)

#define DN 0.35355339059327373f      // 64^-0.25
#define DIAGC 0.0625f                 // 0.5 * 64^-0.5
#define RATIO 0.06131393394849658f    // 266^-0.5
#define FEPS 1e-4f

typedef __attribute__((__ext_vector_type__(8))) __bf16 bf16x8;
typedef __attribute__((__ext_vector_type__(4))) float f32x4;

__device__ __forceinline__ float wredsum(float v) {
    v += __shfl_xor(v, 32); v += __shfl_xor(v, 16); v += __shfl_xor(v, 8);
    v += __shfl_xor(v, 4);  v += __shfl_xor(v, 2);  v += __shfl_xor(v, 1);
    return v;
}
__device__ __forceinline__ float wredmax(float v) {
    v = fmaxf(v, __shfl_xor(v, 32)); v = fmaxf(v, __shfl_xor(v, 16));
    v = fmaxf(v, __shfl_xor(v, 8));  v = fmaxf(v, __shfl_xor(v, 4));
    v = fmaxf(v, __shfl_xor(v, 2));  v = fmaxf(v, __shfl_xor(v, 1));
    return v;
}

__device__ __forceinline__ unsigned short f2bf(float f) {
    unsigned u = __builtin_bit_cast(unsigned, f);
    return (unsigned short)((u + 0x7fffu + ((u >> 16) & 1u)) >> 16);
}
__device__ __forceinline__ float blo(unsigned x) { return __builtin_bit_cast(float, x << 16); }
__device__ __forceinline__ float bhi(unsigned x) { return __builtin_bit_cast(float, x & 0xffff0000u); }
__device__ __forceinline__ float sumsq8(uint4 u) {
    float s = 0.f;
    s += blo(u.x)*blo(u.x) + bhi(u.x)*bhi(u.x);
    s += blo(u.y)*blo(u.y) + bhi(u.y)*bhi(u.y);
    s += blo(u.z)*blo(u.z) + bhi(u.z)*bhi(u.z);
    s += blo(u.w)*blo(u.w) + bhi(u.w)*bhi(u.w);
    return s;
}
__device__ __forceinline__ unsigned pack2(float a, float b) {
    return (unsigned)f2bf(a) | ((unsigned)f2bf(b) << 16);
}

// async global -> LDS, 16B per lane: LDS dest is wave-uniform base + lane*16,
// global src is per-lane.
__device__ __forceinline__ void gload_lds16(const unsigned short* g, unsigned short* lds) {
    __builtin_amdgcn_global_load_lds(
        (const __attribute__((address_space(1))) unsigned int*)g,
        (__attribute__((address_space(3))) unsigned int*)lds, 16, 0, 0);
}

// ---------------- fused double LayerNorm: x = LN0(in+pos); h = bf16(LN1(x)) ----------------
// Wave-per-row: 4 waves/block, lane holds float4 -> all reductions are shfl butterflies.
__global__ __launch_bounds__(256) void add_ln2_kernel(
    const float* __restrict__ in, const float* __restrict__ pos,
    const float* __restrict__ g0, const float* __restrict__ b0,
    const float* __restrict__ g1, const float* __restrict__ b1,
    float* __restrict__ xout, unsigned short* __restrict__ hout)
{
    int t = threadIdx.x;
    int row = blockIdx.x * 4 + (t >> 6);
    int l = t & 63;
    float4 vi = ((const float4*)(in + (size_t)row * 256))[l];
    float4 vp = ((const float4*)(pos + (size_t)(row & 4095) * 256))[l];
    float4 v = {vi.x + vp.x, vi.y + vp.y, vi.z + vp.z, vi.w + vp.w};
    float mean = wredsum(v.x + v.y + v.z + v.w) * (1.0f / 256.0f);
    float4 d = {v.x - mean, v.y - mean, v.z - mean, v.w - mean};
    float var = wredsum(d.x * d.x + d.y * d.y + d.z * d.z + d.w * d.w) * (1.0f / 256.0f);
    float rs = rsqrtf(var + 1e-12f);
    float4 g = ((const float4*)g0)[l], bb = ((const float4*)b0)[l];
    float4 y1 = {d.x * rs * g.x + bb.x, d.y * rs * g.y + bb.y,
                 d.z * rs * g.z + bb.z, d.w * rs * g.w + bb.w};
    ((float4*)(xout + (size_t)row * 256))[l] = y1;
    float mean1 = wredsum(y1.x + y1.y + y1.z + y1.w) * (1.0f / 256.0f);
    float4 d1 = {y1.x - mean1, y1.y - mean1, y1.z - mean1, y1.w - mean1};
    float var1 = wredsum(d1.x * d1.x + d1.y * d1.y + d1.z * d1.z + d1.w * d1.w) * (1.0f / 256.0f);
    float rs1 = rsqrtf(var1 + 1e-12f);
    float4 g1v = ((const float4*)g1)[l], b1v = ((const float4*)b1)[l];
    ushort4 o;
    o.x = f2bf(d1.x * rs1 * g1v.x + b1v.x);
    o.y = f2bf(d1.y * rs1 * g1v.y + b1v.y);
    o.z = f2bf(d1.z * rs1 * g1v.z + b1v.z);
    o.w = f2bf(d1.w * rs1 * g1v.w + b1v.w);
    ((ushort4*)(hout + (size_t)row * 256))[l] = o;
}

// ---------------- weight cast/transpose: fp32 [R][C] -> bf16 [C][R] ----------------
__global__ __launch_bounds__(256) void cast_transpose_kernel(
    const float* __restrict__ in, unsigned short* __restrict__ out, int R, int C)
{
    __shared__ float tile[32][33];
    size_t zo = (size_t)blockIdx.z * R * C;
    int c0 = blockIdx.x * 32, r0 = blockIdx.y * 32;
    int t = threadIdx.x, tc = t & 31, tr = t >> 5;
#pragma unroll
    for (int j = 0; j < 4; j++)
        tile[tr + j * 8][tc] = in[zo + (size_t)(r0 + tr + j * 8) * C + c0 + tc];
    __syncthreads();
#pragma unroll
    for (int j = 0; j < 4; j++) {
        int cc = tr + j * 8, rr = tc;
        out[zo + (size_t)(c0 + cc) * R + r0 + rr] = f2bf(tile[rr][cc]);
    }
}

// 4-way merged 256x256x4-layer cast/transpose (Wq,Wk,Wv,Wo in one dispatch)
__global__ __launch_bounds__(256) void cast_transpose4_kernel(
    const float* __restrict__ i0, const float* __restrict__ i1,
    const float* __restrict__ i2, const float* __restrict__ i3,
    unsigned short* __restrict__ o0, unsigned short* __restrict__ o1,
    unsigned short* __restrict__ o2, unsigned short* __restrict__ o3)
{
    __shared__ float tile[32][33];
    int z = blockIdx.z;
    int which = z >> 2, layer = z & 3;
    const float* in = (which == 0) ? i0 : (which == 1) ? i1 : (which == 2) ? i2 : i3;
    unsigned short* out = (which == 0) ? o0 : (which == 1) ? o1 : (which == 2) ? o2 : o3;
    size_t zo = (size_t)layer * 65536;
    int c0 = blockIdx.x * 32, r0 = blockIdx.y * 32;
    int t = threadIdx.x, tc = t & 31, tr = t >> 5;
#pragma unroll
    for (int j = 0; j < 4; j++)
        tile[tr + j * 8][tc] = in[zo + (size_t)(r0 + tr + j * 8) * 256 + c0 + tc];
    __syncthreads();
#pragma unroll
    for (int j = 0; j < 4; j++) {
        int cc = tr + j * 8, rr = tc;
        out[zo + (size_t)(c0 + cc) * 256 + r0 + rr] = f2bf(tile[rr][cc]);
    }
}

// ---------------- proj fp32 [L][266][64] -> bf16 [L][320][64] (zero-padded) --------------
__global__ __launch_bounds__(256) void proj_cast_kernel(
    const float* __restrict__ proj, unsigned short* __restrict__ projbf)
{
    int idx = blockIdx.x * 256 + threadIdx.x;   // 4*320*8 = 10240 chunks of 16B
    if (idx >= 10240) return;
    int li = idx / 2560; int rem = idx - li * 2560;
    int m = rem >> 3; int c = rem & 7;
    uint4 pk = {0, 0, 0, 0};
    if (m < 266) {
        const float* src = proj + ((size_t)li * 266 + m) * 64 + c * 8;
        float4 f0 = *(const float4*)(src);
        float4 f1 = *(const float4*)(src + 4);
        pk.x = pack2(f0.x, f0.y); pk.y = pack2(f0.z, f0.w);
        pk.z = pack2(f1.x, f1.y); pk.w = pack2(f1.z, f1.w);
    }
    *(uint4*)(projbf + (size_t)idx * 8) = pk;
}

// ---------------- ctx partial reduce (16 z) + cast: fp32 -> bf16 [1024][288] -----------
__global__ __launch_bounds__(256) void ctx_reduce_cast_kernel(
    const float* __restrict__ ctxP, unsigned short* __restrict__ ctxbf)
{
    int idx = blockIdx.x * 256 + threadIdx.x;   // 36864 chunks = 1024 rows * 36
    int row = idx / 36;
    int c = idx - row * 36;
    int m = c * 8;
    uint4 pk = {0, 0, 0, 0};
    if (m < 272) {
        float4 s0 = {0.f, 0.f, 0.f, 0.f}, s1 = {0.f, 0.f, 0.f, 0.f};
#pragma unroll
        for (int z = 0; z < 16; z++) {
            const float* p = ctxP + ((size_t)(z * 1024 + row) * 272 + m);
            float4 a = *(const float4*)p;
            float4 b = *(const float4*)(p + 4);
            s0.x += a.x; s0.y += a.y; s0.z += a.z; s0.w += a.w;
            s1.x += b.x; s1.y += b.y; s1.z += b.z; s1.w += b.w;
        }
        pk.x = pack2(s0.x, s0.y); pk.y = pack2(s0.z, s0.w);
        pk.z = pack2(s1.x, s1.y); pk.w = pack2(s1.z, s1.w);
    }
    *(uint4*)(ctxbf + (size_t)row * 288 + c * 8) = pk;
}

// ---------------- fused QKV GEMM (N=768 over q|k|v), K=256 — 2-phase gload_lds dbuf ------
// vT epilogue: acc -> LDS [64e][136] (union-aliased onto staging) -> coalesced 16B stores.
__global__ __launch_bounds__(256) void qkv_kernel(
    const unsigned short* __restrict__ A,
    const unsigned short* __restrict__ Wqt, const unsigned short* __restrict__ Wkt,
    const unsigned short* __restrict__ Wvt,
    const float* __restrict__ bq, const float* __restrict__ bk, const float* __restrict__ bv,
    unsigned short* __restrict__ qbf, unsigned short* __restrict__ kbf,
    unsigned short* __restrict__ vT)
{
    __shared__ union {
        struct { unsigned short As[2][4096]; unsigned short Bs[2][2048]; } st;
        unsigned short vt[64][136];   // 17408 B < 24576 B
    } u;
    const int K = 256;
    int t = threadIdx.x;
    int bm = blockIdx.y * 128, bn = blockIdx.x * 64;
    int grp = bn >> 8, lbn = bn & 255;
    const unsigned short* Bt = (grp == 0) ? Wqt : (grp == 1) ? Wkt : Wvt;
    const float* bias = (grp == 0) ? bq : (grp == 1) ? bk : bv;
    int w = t >> 6, l = t & 63, lm16 = l & 15, quad = l >> 4;
    int gc8 = ((l & 3) ^ ((l >> 3) & 3)) * 8;          // lane-constant source chunk swizzle
    int rc8 = (quad ^ ((lm16 >> 1) & 3)) * 8;          // read-side chunk swizzle
    const unsigned short* pa0 = A + (size_t)(bm + w * 16 + (l >> 2)) * K + gc8;
    const unsigned short* pa1 = pa0 + (size_t)64 * K;
    const unsigned short* pb0 = Bt + (size_t)(lbn + w * 16 + (l >> 2)) * K + gc8;
    auto stage = [&](int buf, int k0) {
        gload_lds16(pa0 + k0, &u.st.As[buf][w * 512]);
        gload_lds16(pa1 + k0, &u.st.As[buf][w * 512 + 2048]);
        gload_lds16(pb0 + k0, &u.st.Bs[buf][w * 512]);
    };
    stage(0, 0);
    f32x4 acc[2][4] = {};
    __syncthreads();
    for (int kt = 0; kt < 8; ++kt) {
        int cur = kt & 1;
        if (kt < 7) stage(cur ^ 1, (kt + 1) * 32);
        bf16x8 af[2], bfr[4];
        af[0] = *(const bf16x8*)&u.st.As[cur][(w * 32 + lm16) * 32 + rc8];
        af[1] = *(const bf16x8*)&u.st.As[cur][(w * 32 + 16 + lm16) * 32 + rc8];
#pragma unroll
        for (int j = 0; j < 4; j++) bfr[j] = *(const bf16x8*)&u.st.Bs[cur][(j * 16 + lm16) * 32 + rc8];
#pragma unroll
        for (int i = 0; i < 2; i++)
#pragma unroll
            for (int j = 0; j < 4; j++)
                acc[i][j] = __builtin_amdgcn_mfma_f32_16x16x32_bf16(af[i], bfr[j], acc[i][j], 0, 0, 0);
        __syncthreads();
    }
    if (grp == 2) {
        // v group: LDS transpose -> coalesced stores (staging LDS dead after loop barrier)
#pragma unroll
        for (int i = 0; i < 2; i++)
#pragma unroll
            for (int j = 0; j < 4; j++) {
                float bs = bias[lbn + j * 16 + lm16];
#pragma unroll
                for (int r = 0; r < 4; r++)
                    u.vt[j * 16 + lm16][w * 32 + i * 16 + quad * 4 + r] = f2bf(acc[i][j][r] + bs);
            }
        __syncthreads();
        int b = bm >> 12, s0 = bm & 4095;
        size_t base = (size_t)((b << 2) + (lbn >> 6)) * 64 * 4096 + s0;
        int e = t >> 2, c = t & 3;
#pragma unroll
        for (int k = 0; k < 4; k++) {
            uint4 vv = *(const uint4*)&u.vt[e][c * 32 + k * 8];
            *(uint4*)(vT + base + (size_t)e * 4096 + c * 32 + k * 8) = vv;
        }
        return;
    }
#pragma unroll
    for (int i = 0; i < 2; i++)
#pragma unroll
        for (int j = 0; j < 4; j++) {
            int lcol = lbn + j * 16 + lm16;
            float bs = bias[lcol];
            int h = lcol >> 6, e = lcol & 63;
#pragma unroll
            for (int r = 0; r < 4; r++) {
                int row = bm + w * 32 + i * 16 + quad * 4 + r;
                int b = row >> 12, s = row & 4095;
                float v = acc[i][j][r] + bs;
                if (grp == 0)
                    qbf[((size_t)((b << 2) + h) * 4096 + s) * 64 + e] = f2bf(v);
                else
                    kbf[((size_t)((b << 2) + h) * 4096 + s) * 64 + e] = f2bf(v);
            }
        }
}

// ---------------- FFN1 GEMM — 2-phase gload_lds dbuf: gelu(tanh) epilogue, bf16 out -------
__global__ __launch_bounds__(256) void ffn1_kernel(
    const unsigned short* __restrict__ A, const unsigned short* __restrict__ Bt,
    const float* __restrict__ bias, unsigned short* __restrict__ Cb, int N, int K)
{
    __shared__ unsigned short As[2][4096];
    __shared__ unsigned short Bs[2][2048];
    int t = threadIdx.x;
    int bm = blockIdx.y * 128, bn = blockIdx.x * 64;
    int w = t >> 6, l = t & 63, lm16 = l & 15, quad = l >> 4;
    int gc8 = ((l & 3) ^ ((l >> 3) & 3)) * 8;
    int rc8 = (quad ^ ((lm16 >> 1) & 3)) * 8;
    const unsigned short* pa0 = A + (size_t)(bm + w * 16 + (l >> 2)) * K + gc8;
    const unsigned short* pa1 = pa0 + (size_t)64 * K;
    const unsigned short* pb0 = Bt + (size_t)(bn + w * 16 + (l >> 2)) * K + gc8;
    auto stage = [&](int buf, int k0) {
        gload_lds16(pa0 + k0, &As[buf][w * 512]);
        gload_lds16(pa1 + k0, &As[buf][w * 512 + 2048]);
        gload_lds16(pb0 + k0, &Bs[buf][w * 512]);
    };
    stage(0, 0);
    f32x4 acc[2][4] = {};
    __syncthreads();
    int nt = K >> 5;
    for (int kt = 0; kt < nt; ++kt) {
        int cur = kt & 1;
        if (kt < nt - 1) stage(cur ^ 1, (kt + 1) * 32);
        bf16x8 af[2], bfr[4];
        af[0] = *(const bf16x8*)&As[cur][(w * 32 + lm16) * 32 + rc8];
        af[1] = *(const bf16x8*)&As[cur][(w * 32 + 16 + lm16) * 32 + rc8];
#pragma unroll
        for (int j = 0; j < 4; j++) bfr[j] = *(const bf16x8*)&Bs[cur][(j * 16 + lm16) * 32 + rc8];
#pragma unroll
        for (int i = 0; i < 2; i++)
#pragma unroll
            for (int j = 0; j < 4; j++)
                acc[i][j] = __builtin_amdgcn_mfma_f32_16x16x32_bf16(af[i], bfr[j], acc[i][j], 0, 0, 0);
        __syncthreads();
    }
#pragma unroll
    for (int i = 0; i < 2; i++)
#pragma unroll
        for (int j = 0; j < 4; j++) {
            int col = bn + j * 16 + lm16;
            float bsv = bias[col];
#pragma unroll
            for (int r = 0; r < 4; r++) {
                int row = bm + w * 32 + i * 16 + quad * 4 + r;
                float v = acc[i][j][r] + bsv;
                float inner = 0.7978845608028654f * (v + 0.044715f * v * v * v);
                float gl = 0.5f * v * (1.0f + tanhf(inner));
                Cb[(size_t)row * N + col] = f2bf(gl);
            }
        }
}

// ---------------- fused full-row GEMM: RT*16 rows x N=256 per block, 512 threads --------
// 2-phase gload_lds dbuf; grid = 16384/(RT*16) blocks. RT=1 (K=256): 4 blocks/CU;
// RT=2 (K=1024): 2 blocks/CU (16-row would double B L2 traffic and bind on L2).
// `red` aliased onto As2 (dead after K-loop).
template <int EPI, int RT>
__global__ __launch_bounds__(512) void gemm_fullrow_kernel(
    const unsigned short* __restrict__ A, const unsigned short* __restrict__ Bt,
    const float* __restrict__ bias, float* __restrict__ xio,
    const float* __restrict__ lng, const float* __restrict__ lnb,
    unsigned short* __restrict__ outb,
    const float* __restrict__ p2w, const float* __restrict__ p2b,
    const float* __restrict__ mask, float* __restrict__ alphab, int K)
{
    __shared__ unsigned short As2[2][RT * 512];   // [RT*16 rows][32 hw]
    __shared__ unsigned short Bs2[2][8192];       // [256 rows][32 hw]
    float (*red)[RT * 16] = (float (*)[RT * 16])As2;  // aliased; used only after K-loop
    int t = threadIdx.x;
    int bm = blockIdx.x * (RT * 16);
    int w = t >> 6, l = t & 63, lm16 = l & 15, quad = l >> 4;
    int gc8 = ((l & 3) ^ ((l >> 3) & 3)) * 8;
    int rc8 = (quad ^ ((lm16 >> 1) & 3)) * 8;
    const unsigned short* pa = A + (size_t)(bm + (w & (RT - 1)) * 16 + (l >> 2)) * K + gc8;
    const unsigned short* pb0 = Bt + (size_t)(w * 16 + (l >> 2)) * K + gc8;
    const unsigned short* pb1 = pb0 + (size_t)128 * K;
    auto stage = [&](int buf, int k0) {
        if (w < RT) gload_lds16(pa + k0, &As2[buf][w * 512]);
        gload_lds16(pb0 + k0, &Bs2[buf][w * 512]);
        gload_lds16(pb1 + k0, &Bs2[buf][w * 512 + 4096]);
    };
    stage(0, 0);
    f32x4 acc[RT][2] = {};
    __syncthreads();
    int nt = K >> 5;
    for (int kt = 0; kt < nt; ++kt) {
        int cur = kt & 1;
        if (kt < nt - 1) stage(cur ^ 1, (kt + 1) * 32);
        bf16x8 af[RT], bfv[2];
#pragma unroll
        for (int i = 0; i < RT; i++) af[i] = *(const bf16x8*)&As2[cur][(i * 16 + lm16) * 32 + rc8];
#pragma unroll
        for (int j = 0; j < 2; j++) bfv[j] = *(const bf16x8*)&Bs2[cur][(w * 32 + j * 16 + lm16) * 32 + rc8];
#pragma unroll
        for (int i = 0; i < RT; i++)
#pragma unroll
            for (int j = 0; j < 2; j++)
                acc[i][j] = __builtin_amdgcn_mfma_f32_16x16x32_bf16(af[i], bfv[j], acc[i][j], 0, 0, 0);
        __syncthreads();
    }
    int colbase = w * 32;
    if (EPI == 2) {
        float rs[RT][4] = {};
#pragma unroll
        for (int j = 0; j < 2; j++) {
            int col = colbase + j * 16 + lm16;
            float bs = bias[col], pw = p2w[col];
#pragma unroll
            for (int i = 0; i < RT; i++)
#pragma unroll
                for (int r = 0; r < 4; r++)
                    rs[i][r] += tanhf(acc[i][j][r] + bs) * pw;
        }
#pragma unroll
        for (int m2 = 1; m2 <= 8; m2 <<= 1)
#pragma unroll
            for (int i = 0; i < RT; i++)
#pragma unroll
                for (int r = 0; r < 4; r++) rs[i][r] += __shfl_xor(rs[i][r], m2);
        __syncthreads();
        if (lm16 == 0) {
#pragma unroll
            for (int i = 0; i < RT; i++)
#pragma unroll
                for (int r = 0; r < 4; r++) red[w][i * 16 + quad * 4 + r] = rs[i][r];
        }
        __syncthreads();
        if (t < RT * 16) {
            float sc = p2b[0];
#pragma unroll
            for (int ww = 0; ww < 8; ww++) sc += red[ww][t];
            int row = bm + t;
            alphab[row] = expf(sc) * mask[row];
        }
        return;
    }
    float rs[RT][4] = {};
#pragma unroll
    for (int j = 0; j < 2; j++) {
        int col = colbase + j * 16 + lm16;
        float bs = bias[col];
#pragma unroll
        for (int i = 0; i < RT; i++)
#pragma unroll
            for (int r = 0; r < 4; r++) {
                int row = bm + i * 16 + quad * 4 + r;
                float v = acc[i][j][r] + bs + xio[(size_t)row * 256 + col];
                acc[i][j][r] = v;
                rs[i][r] += v;
            }
    }
    float mean[RT][4], rstd[RT][4];
    if (EPI == 0) {
#pragma unroll
        for (int m2 = 1; m2 <= 8; m2 <<= 1)
#pragma unroll
            for (int i = 0; i < RT; i++)
#pragma unroll
                for (int r = 0; r < 4; r++) rs[i][r] += __shfl_xor(rs[i][r], m2);
        __syncthreads();
        if (lm16 == 0) {
#pragma unroll
            for (int i = 0; i < RT; i++)
#pragma unroll
                for (int r = 0; r < 4; r++) red[w][i * 16 + quad * 4 + r] = rs[i][r];
        }
        __syncthreads();
        float vs[RT][4] = {};
#pragma unroll
        for (int i = 0; i < RT; i++)
#pragma unroll
            for (int r = 0; r < 4; r++) {
                int rr = i * 16 + quad * 4 + r;
                float s = 0.f;
#pragma unroll
                for (int ww = 0; ww < 8; ww++) s += red[ww][rr];
                mean[i][r] = s * (1.0f / 256.0f);
            }
#pragma unroll
        for (int j = 0; j < 2; j++)
#pragma unroll
            for (int i = 0; i < RT; i++)
#pragma unroll
                for (int r = 0; r < 4; r++) {
                    float d = acc[i][j][r] - mean[i][r];
                    vs[i][r] += d * d;
                }
#pragma unroll
        for (int m2 = 1; m2 <= 8; m2 <<= 1)
#pragma unroll
            for (int i = 0; i < RT; i++)
#pragma unroll
                for (int r = 0; r < 4; r++) vs[i][r] += __shfl_xor(vs[i][r], m2);
        __syncthreads();
        if (lm16 == 0) {
#pragma unroll
            for (int i = 0; i < RT; i++)
#pragma unroll
                for (int r = 0; r < 4; r++) red[w][i * 16 + quad * 4 + r] = vs[i][r];
        }
        __syncthreads();
#pragma unroll
        for (int i = 0; i < RT; i++)
#pragma unroll
            for (int r = 0; r < 4; r++) {
                int rr = i * 16 + quad * 4 + r;
                float s = 0.f;
#pragma unroll
                for (int ww = 0; ww < 8; ww++) s += red[ww][rr];
                rstd[i][r] = rsqrtf(s * (1.0f / 256.0f) + 1e-12f);
            }
    }
#pragma unroll
    for (int j = 0; j < 2; j++) {
        int col = colbase + j * 16 + lm16;
        float g  = (EPI == 0) ? lng[col] : 0.f;
        float bb = (EPI == 0) ? lnb[col] : 0.f;
#pragma unroll
        for (int i = 0; i < RT; i++)
#pragma unroll
            for (int r = 0; r < 4; r++) {
                int row = bm + i * 16 + quad * 4 + r;
                float v = acc[i][j][r];
                xio[(size_t)row * 256 + col] = v;
                float y = (EPI == 0) ? ((v - mean[i][r]) * rstd[i][r] * g + bb) : v;
                outb[(size_t)row * 256 + col] = f2bf(y);
            }
    }
}

// ---------------- k-max kernel: dash block-max -> pmax; also zeros ksum ----------------
#define ZERO_FLOATS 4352   // 16*272 floats (ksum only; ctx partials are overwritten)
__global__ __launch_bounds__(256) void phi_kmax_kernel(
    const unsigned short* __restrict__ kbf, const unsigned short* __restrict__ projbf,
    float* __restrict__ pmax, float* __restrict__ zbase)
{
    __shared__ uint4 As[64][9];
    __shared__ uint4 Bs[272][8];   // chunk-swizzled proj (slot c holds chunk c ^ (row&7))
    __shared__ float diag_s[64];
    __shared__ float sred[4];
    int t = threadIdx.x;
    int s0 = blockIdx.x * 64;
    int bh = blockIdx.y;
    int w = t >> 6, l = t & 63, lm16 = l & 15, quad = l >> 4;
    {
        int bid = blockIdx.y * 64 + blockIdx.x;
        for (int i = bid * 256 + t; i < ZERO_FLOATS; i += 1024 * 256) zbase[i] = 0.f;
    }
    {
        int arow = t >> 2, akoff = (t & 3) * 16;
        const uint4* ga = (const uint4*)(kbf + ((size_t)bh * 4096 + s0 + arow) * 64 + akoff);
        uint4 u0 = ga[0], u1 = ga[1];
        As[arow][(akoff >> 3)] = u0; As[arow][(akoff >> 3) + 1] = u1;
        float ss = sumsq8(u0) + sumsq8(u1);
        ss += __shfl_xor(ss, 1); ss += __shfl_xor(ss, 2);
        if ((t & 3) == 0) diag_s[arow] = DIAGC * ss;
    }
    {
        unsigned short* Pl = (unsigned short*)Bs;
        int gcp8 = ((l & 7) ^ ((l >> 3) & 7)) * 8;
        const unsigned short* ps = projbf + (size_t)(l >> 3) * 64 + gcp8;
        for (int i = w; i < 34; i += 4)
            gload_lds16(ps + (size_t)i * 512, Pl + i * 512);
    }
    __syncthreads();
    f32x4 acc[17] = {};
#pragma unroll
    for (int ks = 0; ks < 2; ks++) {
        bf16x8 af = *(const bf16x8*)&As[w * 16 + lm16][ks * 4 + quad];
#pragma unroll
        for (int j = 0; j < 17; j++) {
            bf16x8 bfv = *(const bf16x8*)&Bs[j * 16 + lm16][(ks * 4 + quad) ^ (lm16 & 7)];
            acc[j] = __builtin_amdgcn_mfma_f32_16x16x32_bf16(af, bfv, acc[j], 0, 0, 0);
        }
    }
    int rloc = w * 16 + quad * 4;
    float kmax = -1e30f;
#pragma unroll
    for (int j = 0; j < 17; j++) {
        int m = j * 16 + lm16;
        bool valid = m < 266;
#pragma unroll
        for (int r = 0; r < 4; r++)
            if (valid) kmax = fmaxf(kmax, acc[j][r] * DN - diag_s[rloc + r]);
    }
    kmax = wredmax(kmax);
    if (l == 0) sred[w] = kmax;
    __syncthreads();
    if (t == 0)
        pmax[(size_t)bh * 64 + blockIdx.x] =
            fmaxf(fmaxf(sred[0], sred[1]), fmaxf(sred[2], sred[3]));
}

// ---------------- fused ctx: m-half blocks; dash->exp->LDS->ctx MFMA + ksum ------------
// grid (2 m-halves, 16 bh, 16 z) = 512 blocks (2/CU). Wave = s-tile for dash,
// e-quarter for PV. One-chunk-ahead register prefetch of K/V. ctx partials go to
// private ctxP[z][bh][64][272] slices via plain stores (NO atomics).
__global__ __launch_bounds__(256) void ctx_fused_kernel(
    const unsigned short* __restrict__ kbf, const unsigned short* __restrict__ vT,
    const unsigned short* __restrict__ projbf, const float* __restrict__ pmax,
    float* __restrict__ ksum, float* __restrict__ ctxP)
{
    __shared__ uint4 Ap[144][8];              // proj m-half, chunk-swizzled (18432 B)
    __shared__ uint4 Ks[64][9];               // 9216 B
    __shared__ uint4 Vs[64][9];               // 9216 B
    __shared__ unsigned short kp_s[144][72];  // [m][s] bf16 (20736 B)
    __shared__ float diag_s[64];
    __shared__ float sred2[4];
    int t = threadIdx.x;
    int m0 = blockIdx.x * 144;                // 0 or 144
    int bh = blockIdx.y;
    int sb = blockIdx.z * 256;                // 4 chunks of 64 s
    int w = t >> 6, l = t & 63, lm16 = l & 15, quad = l >> 4;
    // ---- stage proj half via gload_lds (lane-constant source chunk swizzle) ----
    {
        unsigned short* Pl = (unsigned short*)Ap;
        int gcp8 = ((l & 7) ^ ((l >> 3) & 7)) * 8;
        const unsigned short* ps = projbf + (size_t)(m0 + (l >> 3)) * 64 + gcp8;
        for (int i = w; i < 18; i += 4)
            gload_lds16(ps + (size_t)i * 512, Pl + i * 512);
    }
    // ---- global k stabilizer ----
    float pm = -1e30f;
    for (int i = t; i < 1024; i += 256) pm = fmaxf(pm, pmax[i]);
    pm = wredmax(pm);
    if (l == 0) sred2[w] = pm;
    // ---- preload chunk 0 K/V to regs ----
    int srow = t >> 2, skoff = (t & 3) * 16, sk4 = skoff >> 3;
    const uint4* gk = (const uint4*)(kbf + ((size_t)bh * 4096 + sb + srow) * 64 + skoff);
    uint4 k0 = gk[0], k1 = gk[1];
    const uint4* gv = (const uint4*)(vT + ((size_t)bh * 64 + srow) * 4096 + sb + skoff);
    uint4 v0 = gv[0], v1 = gv[1];
    __syncthreads();
    float st = fmaxf(fmaxf(sred2[0], sred2[1]), fmaxf(sred2[2], sred2[3]));
    f32x4 accc[9] = {};
    float ksacc[9][4] = {};
    for (int kc = 0; kc < 4; kc++) {
        if (kc) __syncthreads();                   // A: prior PV reads done
        Ks[srow][sk4] = k0; Ks[srow][sk4 + 1] = k1;
        Vs[srow][sk4] = v0; Vs[srow][sk4 + 1] = v1;
        float ss = sumsq8(k0) + sumsq8(k1);
        ss += __shfl_xor(ss, 1); ss += __shfl_xor(ss, 2);
        if ((t & 3) == 0) diag_s[srow] = DIAGC * ss;
        __syncthreads();                           // B: staging visible (drains gloads)
        if (kc < 3) {                              // prefetch next chunk; hides under dash+exp
            int sc = sb + (kc + 1) * 64;
            const uint4* gk2 = (const uint4*)(kbf + ((size_t)bh * 4096 + sc + srow) * 64 + skoff);
            k0 = gk2[0]; k1 = gk2[1];
            const uint4* gv2 = (const uint4*)(vT + ((size_t)bh * 64 + srow) * 4096 + sc + skoff);
            v0 = gv2[0]; v1 = gv2[1];
        }
        // ---- dash [144 m][64 s]: wave w owns s-tile w; diag is per-thread scalar ----
        float dgv = diag_s[w * 16 + lm16];
#pragma unroll
        for (int jm = 0; jm < 9; jm++) {
            f32x4 accd = {};
#pragma unroll
            for (int ks = 0; ks < 2; ks++) {
                bf16x8 af = *(const bf16x8*)&Ap[jm * 16 + lm16][(ks * 4 + quad) ^ (lm16 & 7)];
                bf16x8 bfv = *(const bf16x8*)&Ks[w * 16 + lm16][ks * 4 + quad];
                accd = __builtin_amdgcn_mfma_f32_16x16x32_bf16(af, bfv, accd, 0, 0, 0);
            }
#pragma unroll
            for (int r = 0; r < 4; r++) {
                int mg = m0 + jm * 16 + quad * 4 + r;
                float v = accd[r] * DN - dgv;
                float e = (mg < 266) ? RATIO * (__expf(v - st) + FEPS) : 0.f;
                kp_s[jm * 16 + quad * 4 + r][w * 16 + lm16] = f2bf(e);
                ksacc[jm][r] += e;
            }
        }
        __syncthreads();                           // C: kp visible
        // ---- PV: ctx[m][e] += kp[s][m]^T v[s][e]; wave w owns e-quarter w ----
#pragma unroll
        for (int ks = 0; ks < 2; ks++) {
            bf16x8 af = *(const bf16x8*)&Vs[w * 16 + lm16][ks * 4 + quad];
#pragma unroll
            for (int jt = 0; jt < 9; jt++) {
                bf16x8 bfv = *(const bf16x8*)&kp_s[jt * 16 + lm16][ks * 32 + quad * 8];
                accc[jt] = __builtin_amdgcn_mfma_f32_16x16x32_bf16(af, bfv, accc[jt], 0, 0, 0);
            }
        }
    }
    // ---- ksum: reduce over this wave's 16 s-lanes, one atomic per (m, wave) ----
#pragma unroll
    for (int jm = 0; jm < 9; jm++)
#pragma unroll
        for (int r = 0; r < 4; r++) {
            float vv = ksacc[jm][r];
            vv += __shfl_xor(vv, 1); vv += __shfl_xor(vv, 2);
            vv += __shfl_xor(vv, 4); vv += __shfl_xor(vv, 8);
            if (lm16 == 0) {
                int mg = m0 + jm * 16 + quad * 4 + r;
                if (mg < 272) atomicAdd(&ksum[bh * 272 + mg], vv);
            }
        }
    // ---- ctx partial store (private slice, no atomics) ----
    float* dst = ctxP + (size_t)(blockIdx.z * 16 + bh) * 64 * 272;
#pragma unroll
    for (int jt = 0; jt < 9; jt++) {
        int mg = m0 + jt * 16 + lm16;
        if (mg >= 272) continue;
#pragma unroll
        for (int r = 0; r < 4; r++) {
            int e = w * 16 + quad * 4 + r;
            dst[(size_t)e * 272 + mg] = accc[jt][r];
        }
    }
}

// ---------------- fused q-side: dash -> rowmax -> exp -> denom -> attn out ----------------
// ctx staged via global_load_lds (bf16, precast), double-buffered 16-e-row quarters,
// first two quarters prefetched under the exp phase. proj staged via global_load_lds.
__global__ __launch_bounds__(256) void phi_q_attn_kernel(
    const unsigned short* __restrict__ qbf, const unsigned short* __restrict__ projbf,
    const float* __restrict__ ksum, const unsigned short* __restrict__ ctxbf,
    unsigned short* __restrict__ abf)
{
    __shared__ uint4 uA[1152];       // stage1: q tile [64][9] (9216B); stage2: ctx dbuf 2x[16][288]us (18432B)
    __shared__ uint4 bufB[272][8];   // stage1: proj chunk-swizzled; stage2: qp ushort[64][272]
    __shared__ float diag_s[64];
    __shared__ float den_s[64];
    int t = threadIdx.x;
    int s0 = blockIdx.x * 64;
    int bh = blockIdx.y;
    int w = t >> 6, l = t & 63, lm16 = l & 15, quad = l >> 4;
    uint4 (*bufA)[9] = (uint4(*)[9])uA;
    {
        int arow = t >> 2, akoff = (t & 3) * 16;
        const uint4* ga = (const uint4*)(qbf + ((size_t)bh * 4096 + s0 + arow) * 64 + akoff);
        uint4 u0 = ga[0], u1 = ga[1];
        bufA[arow][(akoff >> 3)] = u0; bufA[arow][(akoff >> 3) + 1] = u1;
        float ss = sumsq8(u0) + sumsq8(u1);
        ss += __shfl_xor(ss, 1); ss += __shfl_xor(ss, 2);
        if ((t & 3) == 0) diag_s[arow] = DIAGC * ss;
    }
    {
        unsigned short* Pl = (unsigned short*)bufB;
        int gcp8 = ((l & 7) ^ ((l >> 3) & 7)) * 8;
        const unsigned short* ps = projbf + (size_t)(l >> 3) * 64 + gcp8;
        for (int i = w; i < 34; i += 4)
            gload_lds16(ps + (size_t)i * 512, Pl + i * 512);
    }
    // ksum -> registers (saves LDS; keeps 3 blocks/CU)
    float ksv[17];
#pragma unroll
    for (int j = 0; j < 17; j++) ksv[j] = ksum[bh * 272 + j * 16 + lm16];
    __syncthreads();
    // ---- stage 1: dash[64 s][272 m] via 34 MFMAs; swizzled proj reads are bank-uniform ----
    f32x4 acc[17] = {};
#pragma unroll
    for (int ks = 0; ks < 2; ks++) {
        bf16x8 af = *(const bf16x8*)&bufA[w * 16 + lm16][ks * 4 + quad];
#pragma unroll
        for (int j = 0; j < 17; j++) {
            bf16x8 bfv = *(const bf16x8*)&bufB[j * 16 + lm16][(ks * 4 + quad) ^ (lm16 & 7)];
            acc[j] = __builtin_amdgcn_mfma_f32_16x16x32_bf16(af, bfv, acc[j], 0, 0, 0);
        }
    }
    int rloc = w * 16 + quad * 4;
    float dg[4];
#pragma unroll
    for (int r = 0; r < 4; r++) dg[r] = diag_s[rloc + r];
    float vmax[4] = {-1e30f, -1e30f, -1e30f, -1e30f};
#pragma unroll
    for (int j = 0; j < 17; j++) {
        int m = j * 16 + lm16;
        bool valid = m < 266;
#pragma unroll
        for (int r = 0; r < 4; r++) {
            float v = acc[j][r] * DN - dg[r];
            acc[j][r] = v;
            if (valid) vmax[r] = fmaxf(vmax[r], v);
        }
    }
#pragma unroll
    for (int m2 = 1; m2 <= 8; m2 <<= 1)
#pragma unroll
        for (int r = 0; r < 4; r++) vmax[r] = fmaxf(vmax[r], __shfl_xor(vmax[r], m2));
    __syncthreads();   // all waves done reading bufA/bufB -> safe to overwrite with ctx/qp
    // ---- prefetch ctx quarters 0+1 (18KB) into dbuf; latency hides under exp phase ----
    unsigned short* ctxs = (unsigned short*)uA;
    const unsigned short* ctxg = ctxbf + (size_t)bh * 64 * 288;
    for (int i = w; i < 18; i += 4)
        gload_lds16(ctxg + i * 512 + l * 8, ctxs + i * 512);
    // ---- exp phase: qp -> LDS (bf16), denom via register ksum ----
    unsigned short* qp_s = (unsigned short*)bufB;    // [64][272]
    float den[4] = {0.f, 0.f, 0.f, 0.f};
#pragma unroll
    for (int j = 0; j < 17; j++) {
        int m = j * 16 + lm16;
        bool valid = m < 266;
#pragma unroll
        for (int r = 0; r < 4; r++) {
            float e = valid ? RATIO * (__expf(acc[j][r] - vmax[r]) + FEPS) : 0.f;
            qp_s[(rloc + r) * 272 + m] = f2bf(e);
            den[r] += e * ksv[j];
        }
    }
#pragma unroll
    for (int m2 = 1; m2 <= 8; m2 <<= 1)
#pragma unroll
        for (int r = 0; r < 4; r++) den[r] += __shfl_xor(den[r], m2);
    if (lm16 == 0) {
#pragma unroll
        for (int r = 0; r < 4; r++) den_s[rloc + r] = den[r];
    }
    // qp rows [w*16, w*16+16) written by this wave only -> A-frags readable without barrier
    bf16x8 paf[9];
#pragma unroll
    for (int kk = 0; kk < 9; kk++)
        paf[kk] = *(const bf16x8*)&qp_s[(w * 16 + lm16) * 272 + kk * 32 + quad * 8];
    __syncthreads();   // drains gload_lds vmcnt: quarters 0+1 resident
    // ---- stage 2: out[64 s][64 e] = qp @ ctx^T, 4 quarters x 9 MFMAs, dbuf'd ----
    int b = bh >> 2, h = bh & 3;
    f32x4 oacc[4] = {};
#pragma unroll
    for (int qd = 0; qd < 4; qd++) {
        const unsigned short* cs = ctxs + (qd & 1) * 4608;
#pragma unroll
        for (int kk = 0; kk < 9; kk++) {
            bf16x8 bfv = *(const bf16x8*)&cs[lm16 * 288 + kk * 32 + quad * 8];
            oacc[qd] = __builtin_amdgcn_mfma_f32_16x16x32_bf16(paf[kk], bfv, oacc[qd], 0, 0, 0);
        }
        if (qd < 3) {
            __syncthreads();   // waves done reading this buf; drains in-flight quarter loads
            if (qd < 2) {
                for (int i = w; i < 9; i += 4)
                    gload_lds16(ctxg + (qd + 2) * 4608 + i * 512 + l * 8,
                                ctxs + (qd & 1) * 4608 + i * 512);
            }
        }
    }
#pragma unroll
    for (int qd = 0; qd < 4; qd++) {
        int e = qd * 16 + lm16;
#pragma unroll
        for (int r = 0; r < 4; r++) {
            int sl = rloc + r;
            abf[((size_t)(b * 4096 + s0 + sl)) * 256 + h * 64 + e] = f2bf(oacc[qd][r] / den_s[sl]);
        }
    }
}

// ---------------- pooling tail: denom + weighted sum in ONE kernel ----------------
__global__ __launch_bounds__(256) void pool_out_kernel(
    const float* __restrict__ x, const float* __restrict__ alpha,
    float* __restrict__ out)
{
    __shared__ float sred[4];
    int b = blockIdx.x, chunk = blockIdx.y, t = threadIdx.x;
    float p = 0.f;
    for (int s = t; s < 4096; s += 256) p += alpha[b * 4096 + s];
    p = wredsum(p);
    if ((t & 63) == 0) sred[t >> 6] = p;
    __syncthreads();
    float inv = 1.0f / (sred[0] + sred[1] + sred[2] + sred[3] + 1e-8f);
    float acc = 0.f;
    int s0 = chunk * 128;
    for (int s = s0; s < s0 + 128; s++)
        acc += x[((size_t)(b << 12) + s) * 256 + t] * alpha[(b << 12) + s];
    atomicAdd(&out[b * 256 + t], acc * inv);
}

extern "C" void kernel_launch(void* const* d_in, const int* in_sizes, int n_in,
                              void* d_out, int out_size, void* d_ws, size_t ws_size,
                              hipStream_t stream)
{
    const float* input_embs = (const float*)d_in[0];
    const float* mask  = (const float*)d_in[1];
    const float* pos   = (const float*)d_in[2];
    const float* ln_g  = (const float*)d_in[3];
    const float* ln_b  = (const float*)d_in[4];
    const float* proj  = (const float*)d_in[5];
    const float* Wq = (const float*)d_in[6];  const float* bq = (const float*)d_in[7];
    const float* Wk = (const float*)d_in[8];  const float* bk = (const float*)d_in[9];
    const float* Wv = (const float*)d_in[10]; const float* bv = (const float*)d_in[11];
    const float* Wo = (const float*)d_in[12]; const float* bo = (const float*)d_in[13];
    const float* ln1g = (const float*)d_in[14]; const float* ln1b = (const float*)d_in[15];
    const float* W1 = (const float*)d_in[16]; const float* b1 = (const float*)d_in[17];
    const float* W2 = (const float*)d_in[18]; const float* b2 = (const float*)d_in[19];
    const float* ln2g = (const float*)d_in[20]; const float* ln2b = (const float*)d_in[21];
    const float* p1w = (const float*)d_in[22]; const float* p1b = (const float*)d_in[23];
    const float* p2w = (const float*)d_in[24]; const float* p2b = (const float*)d_in[25];
    float* out = (float*)d_out;
    char* ws = (char*)d_ws;

    size_t off = 0;
    auto alloc = [&](size_t bytes) { size_t o = off; off += WS_ALIGN(bytes); return o; };
    float* xbuf = (float*)(ws + alloc(16384ull * 256 * 4));
    unsigned short* hbf = (unsigned short*)(ws + alloc(16384ull * 256 * 2));   // ln-out / attn-out
    unsigned short* qbf = (unsigned short*)(ws + alloc(16384ull * 256 * 2));
    unsigned short* kbf = (unsigned short*)(ws + alloc(16384ull * 256 * 2));
    unsigned short* vT  = (unsigned short*)(ws + alloc(16384ull * 256 * 2));
    unsigned short* midbf = (unsigned short*)(ws + alloc(16384ull * 1024 * 2)); // FFN mid
    float* ksum = (float*)(ws + alloc(16ull * 272 * 4));      // zeroed in phi_kmax
    float* ctxP = (float*)(ws + alloc(16ull * 16 * 64 * 272 * 4)); // z-partials (17.8 MB)
    float* pmaxb = (float*)(ws + alloc(1024ull * 4));
    float* alphab = (float*)(ws + alloc(16384ull * 4));
    unsigned short* Wqt = (unsigned short*)(ws + alloc(4ull * 65536 * 2));
    unsigned short* Wkt = (unsigned short*)(ws + alloc(4ull * 65536 * 2));
    unsigned short* Wvt = (unsigned short*)(ws + alloc(4ull * 65536 * 2));
    unsigned short* Wot = (unsigned short*)(ws + alloc(4ull * 65536 * 2));
    unsigned short* W1t = (unsigned short*)(ws + alloc(4ull * 262144 * 2));
    unsigned short* W2t = (unsigned short*)(ws + alloc(4ull * 262144 * 2));
    unsigned short* projbf = (unsigned short*)(ws + alloc(4ull * 20480 * 2)); // padded [L][320][64]
    unsigned short* p1t = (unsigned short*)(ws + alloc(65536ull * 2));
    unsigned short* ctxbf = (unsigned short*)(ws + alloc(16ull * 64 * 288 * 2)); // padded bf16 ctx
    unsigned short* abf = hbf;
    // total ~111 MB (< 256 MiB)

    // ---- weight casts (all layers up front) ----
    cast_transpose4_kernel<<<dim3(8, 8, 16), 256, 0, stream>>>(Wq, Wk, Wv, Wo, Wqt, Wkt, Wvt, Wot);
    cast_transpose_kernel<<<dim3(32, 8, 4), 256, 0, stream>>>(W1, W1t, 256, 1024);
    cast_transpose_kernel<<<dim3(8, 32, 4), 256, 0, stream>>>(W2, W2t, 1024, 256);
    cast_transpose_kernel<<<dim3(8, 8, 1), 256, 0, stream>>>(p1w, p1t, 256, 256);
    proj_cast_kernel<<<40, 256, 0, stream>>>(proj, projbf);

    // ---- x = LN(input + pos); hbf = LN1_0(x) — single fused kernel (wave-per-row) ----
    add_ln2_kernel<<<4096, 256, 0, stream>>>(input_embs, pos, ln_g, ln_b, ln1g, ln1b, xbuf, hbf);

    for (int i = 0; i < 4; i++) {
        const unsigned short* pj = projbf + (size_t)i * 20480;
        // QKV fused (2-phase gload_lds dbuf; coalesced vT epilogue)
        qkv_kernel<<<dim3(12, 128), 256, 0, stream>>>(hbf,
            Wqt + (size_t)i * 65536, Wkt + (size_t)i * 65536, Wvt + (size_t)i * 65536,
            bq + i * 256, bk + i * 256, bv + i * 256, qbf, kbf, vT);
        // k stabilizer block-max + zero ksum
        phi_kmax_kernel<<<dim3(64, 16), 256, 0, stream>>>(kbf, pj, pmaxb, ksum);
        // fused k-exp + ksum + ctx partials (m-halves, reg prefetch, no ctx atomics)
        ctx_fused_kernel<<<dim3(2, 16, 16), 256, 0, stream>>>(kbf, vT, pj, pmaxb, ksum, ctxP);
        // ctx partial reduce (16 z) + cast -> bf16 [bh][64][288]
        ctx_reduce_cast_kernel<<<144, 256, 0, stream>>>(ctxP, ctxbf);
        // fused q-side: dash + exp + denom + attn out (ctx async-staged, dbuf'd)
        phi_q_attn_kernel<<<dim3(64, 16), 256, 0, stream>>>(qbf, pj, ksum, ctxbf, abf);
        // Wo + residual + LN2 fused (16-row blocks, 4 blocks/CU)
        gemm_fullrow_kernel<0, 1><<<1024, 512, 0, stream>>>(abf, Wot + (size_t)i * 65536,
            bo + i * 256, xbuf, ln2g + i * 256, ln2b + i * 256, hbf,
            nullptr, nullptr, nullptr, nullptr, 256);
        // FFN (2-phase gload_lds dbuf)
        ffn1_kernel<<<dim3(16, 128), 256, 0, stream>>>(hbf, W1t + (size_t)i * 262144,
            b1 + i * 1024, midbf, 1024, 256);
        if (i < 3)
            gemm_fullrow_kernel<0, 2><<<512, 512, 0, stream>>>(midbf, W2t + (size_t)i * 262144,
                b2 + i * 256, xbuf, ln1g + (i + 1) * 256, ln1b + (i + 1) * 256, hbf,
                nullptr, nullptr, nullptr, nullptr, 1024);
        else
            gemm_fullrow_kernel<1, 2><<<512, 512, 0, stream>>>(midbf, W2t + (size_t)i * 262144,
                b2 + i * 256, xbuf, nullptr, nullptr, hbf,
                nullptr, nullptr, nullptr, nullptr, 1024);
    }

    // ---- attention pooling (score fused into GEMM; 16-row blocks) ----
    gemm_fullrow_kernel<2, 1><<<1024, 512, 0, stream>>>(hbf, p1t, p1b, nullptr, nullptr, nullptr,
        nullptr, p2w, p2b, mask, alphab, 256);
    hipMemsetAsync(d_out, 0, (size_t)out_size * sizeof(float), stream);
    pool_out_kernel<<<dim3(4, 32), 256, 0, stream>>>(xbuf, alphab, out);
}

// Round 14
// 753.077 us; speedup vs baseline: 1.0142x; 1.0142x over previous
//
#include <hip/hip_runtime.h>
#include <math.h>

// Performer encoder on MI355X: B=4, S=4096, D=256, H=4, DH=64, L=4, M=266.
// bf16 MFMA everywhere; fp32 residual stream / LN stats / softmax logic.
// Round 25 == Round 24 resubmit (container-level infra failure, no kernel
// verdict). This is the round-22 exact source: proven best at 750.8 µs.
// r22/r23 bracket RT=2 fullrow as optimum; r17/r19 bracket qkv/ffn1 structure;
// all decomposition dims measured-bracketed. Holding this configuration.

#define WS_ALIGN(x) (((x) + 255) & ~(size_t)255)

#define DN 0.35355339059327373f      // 64^-0.25
#define DIAGC 0.0625f                 // 0.5 * 64^-0.5
#define RATIO 0.06131393394849658f    // 266^-0.5
#define FEPS 1e-4f

typedef __attribute__((__ext_vector_type__(8))) __bf16 bf16x8;
typedef __attribute__((__ext_vector_type__(4))) float f32x4;

__device__ __forceinline__ float wredsum(float v) {
    v += __shfl_xor(v, 32); v += __shfl_xor(v, 16); v += __shfl_xor(v, 8);
    v += __shfl_xor(v, 4);  v += __shfl_xor(v, 2);  v += __shfl_xor(v, 1);
    return v;
}
__device__ __forceinline__ float wredmax(float v) {
    v = fmaxf(v, __shfl_xor(v, 32)); v = fmaxf(v, __shfl_xor(v, 16));
    v = fmaxf(v, __shfl_xor(v, 8));  v = fmaxf(v, __shfl_xor(v, 4));
    v = fmaxf(v, __shfl_xor(v, 2));  v = fmaxf(v, __shfl_xor(v, 1));
    return v;
}

__device__ __forceinline__ unsigned short f2bf(float f) {
    unsigned u = __builtin_bit_cast(unsigned, f);
    return (unsigned short)((u + 0x7fffu + ((u >> 16) & 1u)) >> 16);
}
__device__ __forceinline__ float blo(unsigned x) { return __builtin_bit_cast(float, x << 16); }
__device__ __forceinline__ float bhi(unsigned x) { return __builtin_bit_cast(float, x & 0xffff0000u); }
__device__ __forceinline__ float sumsq8(uint4 u) {
    float s = 0.f;
    s += blo(u.x)*blo(u.x) + bhi(u.x)*bhi(u.x);
    s += blo(u.y)*blo(u.y) + bhi(u.y)*bhi(u.y);
    s += blo(u.z)*blo(u.z) + bhi(u.z)*bhi(u.z);
    s += blo(u.w)*blo(u.w) + bhi(u.w)*bhi(u.w);
    return s;
}
__device__ __forceinline__ unsigned pack2(float a, float b) {
    return (unsigned)f2bf(a) | ((unsigned)f2bf(b) << 16);
}

// async global -> LDS, 16B per lane: LDS dest is wave-uniform base + lane*16,
// global src is per-lane.
__device__ __forceinline__ void gload_lds16(const unsigned short* g, unsigned short* lds) {
    __builtin_amdgcn_global_load_lds(
        (const __attribute__((address_space(1))) unsigned int*)g,
        (__attribute__((address_space(3))) unsigned int*)lds, 16, 0, 0);
}

// ---------------- fused double LayerNorm: x = LN0(in+pos); h = bf16(LN1(x)) ----------------
// Wave-per-row: 4 waves/block, lane holds float4 -> all reductions are shfl butterflies.
__global__ __launch_bounds__(256) void add_ln2_kernel(
    const float* __restrict__ in, const float* __restrict__ pos,
    const float* __restrict__ g0, const float* __restrict__ b0,
    const float* __restrict__ g1, const float* __restrict__ b1,
    float* __restrict__ xout, unsigned short* __restrict__ hout)
{
    int t = threadIdx.x;
    int row = blockIdx.x * 4 + (t >> 6);
    int l = t & 63;
    float4 vi = ((const float4*)(in + (size_t)row * 256))[l];
    float4 vp = ((const float4*)(pos + (size_t)(row & 4095) * 256))[l];
    float4 v = {vi.x + vp.x, vi.y + vp.y, vi.z + vp.z, vi.w + vp.w};
    float mean = wredsum(v.x + v.y + v.z + v.w) * (1.0f / 256.0f);
    float4 d = {v.x - mean, v.y - mean, v.z - mean, v.w - mean};
    float var = wredsum(d.x * d.x + d.y * d.y + d.z * d.z + d.w * d.w) * (1.0f / 256.0f);
    float rs = rsqrtf(var + 1e-12f);
    float4 g = ((const float4*)g0)[l], bb = ((const float4*)b0)[l];
    float4 y1 = {d.x * rs * g.x + bb.x, d.y * rs * g.y + bb.y,
                 d.z * rs * g.z + bb.z, d.w * rs * g.w + bb.w};
    ((float4*)(xout + (size_t)row * 256))[l] = y1;
    float mean1 = wredsum(y1.x + y1.y + y1.z + y1.w) * (1.0f / 256.0f);
    float4 d1 = {y1.x - mean1, y1.y - mean1, y1.z - mean1, y1.w - mean1};
    float var1 = wredsum(d1.x * d1.x + d1.y * d1.y + d1.z * d1.z + d1.w * d1.w) * (1.0f / 256.0f);
    float rs1 = rsqrtf(var1 + 1e-12f);
    float4 g1v = ((const float4*)g1)[l], b1v = ((const float4*)b1)[l];
    ushort4 o;
    o.x = f2bf(d1.x * rs1 * g1v.x + b1v.x);
    o.y = f2bf(d1.y * rs1 * g1v.y + b1v.y);
    o.z = f2bf(d1.z * rs1 * g1v.z + b1v.z);
    o.w = f2bf(d1.w * rs1 * g1v.w + b1v.w);
    ((ushort4*)(hout + (size_t)row * 256))[l] = o;
}

// ---------------- weight cast/transpose: fp32 [R][C] -> bf16 [C][R] ----------------
__global__ __launch_bounds__(256) void cast_transpose_kernel(
    const float* __restrict__ in, unsigned short* __restrict__ out, int R, int C)
{
    __shared__ float tile[32][33];
    size_t zo = (size_t)blockIdx.z * R * C;
    int c0 = blockIdx.x * 32, r0 = blockIdx.y * 32;
    int t = threadIdx.x, tc = t & 31, tr = t >> 5;
#pragma unroll
    for (int j = 0; j < 4; j++)
        tile[tr + j * 8][tc] = in[zo + (size_t)(r0 + tr + j * 8) * C + c0 + tc];
    __syncthreads();
#pragma unroll
    for (int j = 0; j < 4; j++) {
        int cc = tr + j * 8, rr = tc;
        out[zo + (size_t)(c0 + cc) * R + r0 + rr] = f2bf(tile[rr][cc]);
    }
}

// 4-way merged 256x256x4-layer cast/transpose (Wq,Wk,Wv,Wo in one dispatch)
__global__ __launch_bounds__(256) void cast_transpose4_kernel(
    const float* __restrict__ i0, const float* __restrict__ i1,
    const float* __restrict__ i2, const float* __restrict__ i3,
    unsigned short* __restrict__ o0, unsigned short* __restrict__ o1,
    unsigned short* __restrict__ o2, unsigned short* __restrict__ o3)
{
    __shared__ float tile[32][33];
    int z = blockIdx.z;
    int which = z >> 2, layer = z & 3;
    const float* in = (which == 0) ? i0 : (which == 1) ? i1 : (which == 2) ? i2 : i3;
    unsigned short* out = (which == 0) ? o0 : (which == 1) ? o1 : (which == 2) ? o2 : o3;
    size_t zo = (size_t)layer * 65536;
    int c0 = blockIdx.x * 32, r0 = blockIdx.y * 32;
    int t = threadIdx.x, tc = t & 31, tr = t >> 5;
#pragma unroll
    for (int j = 0; j < 4; j++)
        tile[tr + j * 8][tc] = in[zo + (size_t)(r0 + tr + j * 8) * 256 + c0 + tc];
    __syncthreads();
#pragma unroll
    for (int j = 0; j < 4; j++) {
        int cc = tr + j * 8, rr = tc;
        out[zo + (size_t)(c0 + cc) * 256 + r0 + rr] = f2bf(tile[rr][cc]);
    }
}

// ---------------- proj fp32 [L][266][64] -> bf16 [L][320][64] (zero-padded) --------------
__global__ __launch_bounds__(256) void proj_cast_kernel(
    const float* __restrict__ proj, unsigned short* __restrict__ projbf)
{
    int idx = blockIdx.x * 256 + threadIdx.x;   // 4*320*8 = 10240 chunks of 16B
    if (idx >= 10240) return;
    int li = idx / 2560; int rem = idx - li * 2560;
    int m = rem >> 3; int c = rem & 7;
    uint4 pk = {0, 0, 0, 0};
    if (m < 266) {
        const float* src = proj + ((size_t)li * 266 + m) * 64 + c * 8;
        float4 f0 = *(const float4*)(src);
        float4 f1 = *(const float4*)(src + 4);
        pk.x = pack2(f0.x, f0.y); pk.y = pack2(f0.z, f0.w);
        pk.z = pack2(f1.x, f1.y); pk.w = pack2(f1.z, f1.w);
    }
    *(uint4*)(projbf + (size_t)idx * 8) = pk;
}

// ---------------- ctx partial reduce (16 z) + cast: fp32 -> bf16 [1024][288] -----------
__global__ __launch_bounds__(256) void ctx_reduce_cast_kernel(
    const float* __restrict__ ctxP, unsigned short* __restrict__ ctxbf)
{
    int idx = blockIdx.x * 256 + threadIdx.x;   // 36864 chunks = 1024 rows * 36
    int row = idx / 36;
    int c = idx - row * 36;
    int m = c * 8;
    uint4 pk = {0, 0, 0, 0};
    if (m < 272) {
        float4 s0 = {0.f, 0.f, 0.f, 0.f}, s1 = {0.f, 0.f, 0.f, 0.f};
#pragma unroll
        for (int z = 0; z < 16; z++) {
            const float* p = ctxP + ((size_t)(z * 1024 + row) * 272 + m);
            float4 a = *(const float4*)p;
            float4 b = *(const float4*)(p + 4);
            s0.x += a.x; s0.y += a.y; s0.z += a.z; s0.w += a.w;
            s1.x += b.x; s1.y += b.y; s1.z += b.z; s1.w += b.w;
        }
        pk.x = pack2(s0.x, s0.y); pk.y = pack2(s0.z, s0.w);
        pk.z = pack2(s1.x, s1.y); pk.w = pack2(s1.z, s1.w);
    }
    *(uint4*)(ctxbf + (size_t)row * 288 + c * 8) = pk;
}

// ---------------- fused QKV GEMM (N=768 over q|k|v), K=256 — 2-phase gload_lds dbuf ------
// vT epilogue: acc -> LDS [64e][136] (union-aliased onto staging) -> coalesced 16B stores.
__global__ __launch_bounds__(256) void qkv_kernel(
    const unsigned short* __restrict__ A,
    const unsigned short* __restrict__ Wqt, const unsigned short* __restrict__ Wkt,
    const unsigned short* __restrict__ Wvt,
    const float* __restrict__ bq, const float* __restrict__ bk, const float* __restrict__ bv,
    unsigned short* __restrict__ qbf, unsigned short* __restrict__ kbf,
    unsigned short* __restrict__ vT)
{
    __shared__ union {
        struct { unsigned short As[2][4096]; unsigned short Bs[2][2048]; } st;
        unsigned short vt[64][136];   // 17408 B < 24576 B
    } u;
    const int K = 256;
    int t = threadIdx.x;
    int bm = blockIdx.y * 128, bn = blockIdx.x * 64;
    int grp = bn >> 8, lbn = bn & 255;
    const unsigned short* Bt = (grp == 0) ? Wqt : (grp == 1) ? Wkt : Wvt;
    const float* bias = (grp == 0) ? bq : (grp == 1) ? bk : bv;
    int w = t >> 6, l = t & 63, lm16 = l & 15, quad = l >> 4;
    int gc8 = ((l & 3) ^ ((l >> 3) & 3)) * 8;          // lane-constant source chunk swizzle
    int rc8 = (quad ^ ((lm16 >> 1) & 3)) * 8;          // read-side chunk swizzle
    const unsigned short* pa0 = A + (size_t)(bm + w * 16 + (l >> 2)) * K + gc8;
    const unsigned short* pa1 = pa0 + (size_t)64 * K;
    const unsigned short* pb0 = Bt + (size_t)(lbn + w * 16 + (l >> 2)) * K + gc8;
    auto stage = [&](int buf, int k0) {
        gload_lds16(pa0 + k0, &u.st.As[buf][w * 512]);
        gload_lds16(pa1 + k0, &u.st.As[buf][w * 512 + 2048]);
        gload_lds16(pb0 + k0, &u.st.Bs[buf][w * 512]);
    };
    stage(0, 0);
    f32x4 acc[2][4] = {};
    __syncthreads();
    for (int kt = 0; kt < 8; ++kt) {
        int cur = kt & 1;
        if (kt < 7) stage(cur ^ 1, (kt + 1) * 32);
        bf16x8 af[2], bfr[4];
        af[0] = *(const bf16x8*)&u.st.As[cur][(w * 32 + lm16) * 32 + rc8];
        af[1] = *(const bf16x8*)&u.st.As[cur][(w * 32 + 16 + lm16) * 32 + rc8];
#pragma unroll
        for (int j = 0; j < 4; j++) bfr[j] = *(const bf16x8*)&u.st.Bs[cur][(j * 16 + lm16) * 32 + rc8];
#pragma unroll
        for (int i = 0; i < 2; i++)
#pragma unroll
            for (int j = 0; j < 4; j++)
                acc[i][j] = __builtin_amdgcn_mfma_f32_16x16x32_bf16(af[i], bfr[j], acc[i][j], 0, 0, 0);
        __syncthreads();
    }
    if (grp == 2) {
        // v group: LDS transpose -> coalesced stores (staging LDS dead after loop barrier)
#pragma unroll
        for (int i = 0; i < 2; i++)
#pragma unroll
            for (int j = 0; j < 4; j++) {
                float bs = bias[lbn + j * 16 + lm16];
#pragma unroll
                for (int r = 0; r < 4; r++)
                    u.vt[j * 16 + lm16][w * 32 + i * 16 + quad * 4 + r] = f2bf(acc[i][j][r] + bs);
            }
        __syncthreads();
        int b = bm >> 12, s0 = bm & 4095;
        size_t base = (size_t)((b << 2) + (lbn >> 6)) * 64 * 4096 + s0;
        int e = t >> 2, c = t & 3;
#pragma unroll
        for (int k = 0; k < 4; k++) {
            uint4 vv = *(const uint4*)&u.vt[e][c * 32 + k * 8];
            *(uint4*)(vT + base + (size_t)e * 4096 + c * 32 + k * 8) = vv;
        }
        return;
    }
#pragma unroll
    for (int i = 0; i < 2; i++)
#pragma unroll
        for (int j = 0; j < 4; j++) {
            int lcol = lbn + j * 16 + lm16;
            float bs = bias[lcol];
            int h = lcol >> 6, e = lcol & 63;
#pragma unroll
            for (int r = 0; r < 4; r++) {
                int row = bm + w * 32 + i * 16 + quad * 4 + r;
                int b = row >> 12, s = row & 4095;
                float v = acc[i][j][r] + bs;
                if (grp == 0)
                    qbf[((size_t)((b << 2) + h) * 4096 + s) * 64 + e] = f2bf(v);
                else
                    kbf[((size_t)((b << 2) + h) * 4096 + s) * 64 + e] = f2bf(v);
            }
        }
}

// ---------------- FFN1 GEMM — 2-phase gload_lds dbuf: gelu(tanh) epilogue, bf16 out -------
__global__ __launch_bounds__(256) void ffn1_kernel(
    const unsigned short* __restrict__ A, const unsigned short* __restrict__ Bt,
    const float* __restrict__ bias, unsigned short* __restrict__ Cb, int N, int K)
{
    __shared__ unsigned short As[2][4096];
    __shared__ unsigned short Bs[2][2048];
    int t = threadIdx.x;
    int bm = blockIdx.y * 128, bn = blockIdx.x * 64;
    int w = t >> 6, l = t & 63, lm16 = l & 15, quad = l >> 4;
    int gc8 = ((l & 3) ^ ((l >> 3) & 3)) * 8;
    int rc8 = (quad ^ ((lm16 >> 1) & 3)) * 8;
    const unsigned short* pa0 = A + (size_t)(bm + w * 16 + (l >> 2)) * K + gc8;
    const unsigned short* pa1 = pa0 + (size_t)64 * K;
    const unsigned short* pb0 = Bt + (size_t)(bn + w * 16 + (l >> 2)) * K + gc8;
    auto stage = [&](int buf, int k0) {
        gload_lds16(pa0 + k0, &As[buf][w * 512]);
        gload_lds16(pa1 + k0, &As[buf][w * 512 + 2048]);
        gload_lds16(pb0 + k0, &Bs[buf][w * 512]);
    };
    stage(0, 0);
    f32x4 acc[2][4] = {};
    __syncthreads();
    int nt = K >> 5;
    for (int kt = 0; kt < nt; ++kt) {
        int cur = kt & 1;
        if (kt < nt - 1) stage(cur ^ 1, (kt + 1) * 32);
        bf16x8 af[2], bfr[4];
        af[0] = *(const bf16x8*)&As[cur][(w * 32 + lm16) * 32 + rc8];
        af[1] = *(const bf16x8*)&As[cur][(w * 32 + 16 + lm16) * 32 + rc8];
#pragma unroll
        for (int j = 0; j < 4; j++) bfr[j] = *(const bf16x8*)&Bs[cur][(j * 16 + lm16) * 32 + rc8];
#pragma unroll
        for (int i = 0; i < 2; i++)
#pragma unroll
            for (int j = 0; j < 4; j++)
                acc[i][j] = __builtin_amdgcn_mfma_f32_16x16x32_bf16(af[i], bfr[j], acc[i][j], 0, 0, 0);
        __syncthreads();
    }
#pragma unroll
    for (int i = 0; i < 2; i++)
#pragma unroll
        for (int j = 0; j < 4; j++) {
            int col = bn + j * 16 + lm16;
            float bsv = bias[col];
#pragma unroll
            for (int r = 0; r < 4; r++) {
                int row = bm + w * 32 + i * 16 + quad * 4 + r;
                float v = acc[i][j][r] + bsv;
                float inner = 0.7978845608028654f * (v + 0.044715f * v * v * v);
                float gl = 0.5f * v * (1.0f + tanhf(inner));
                Cb[(size_t)row * N + col] = f2bf(gl);
            }
        }
}

// ---------------- fused full-row GEMM: 32 rows x N=256 per block, 512 threads ----------
// 2-phase gload_lds dbuf; 36 KB LDS; grid 512 = 2 blocks/CU (mutual stall cover).
// `red` aliased onto As2 (dead after K-loop).
template <int EPI>
__global__ __launch_bounds__(512) void gemm_fullrow_kernel(
    const unsigned short* __restrict__ A, const unsigned short* __restrict__ Bt,
    const float* __restrict__ bias, float* __restrict__ xio,
    const float* __restrict__ lng, const float* __restrict__ lnb,
    unsigned short* __restrict__ outb,
    const float* __restrict__ p2w, const float* __restrict__ p2b,
    const float* __restrict__ mask, float* __restrict__ alphab, int K)
{
    __shared__ unsigned short As2[2][1024];   // [32 rows][32 hw]
    __shared__ unsigned short Bs2[2][8192];   // [256 rows][32 hw]
    float (*red)[32] = (float (*)[32])As2;    // aliased; used only after K-loop (1KB < 4KB)
    int t = threadIdx.x;
    int bm = blockIdx.x * 32;
    int w = t >> 6, l = t & 63, lm16 = l & 15, quad = l >> 4;
    int gc8 = ((l & 3) ^ ((l >> 3) & 3)) * 8;
    int rc8 = (quad ^ ((lm16 >> 1) & 3)) * 8;
    const unsigned short* pa = A + (size_t)(bm + (w & 1) * 16 + (l >> 2)) * K + gc8;
    const unsigned short* pb0 = Bt + (size_t)(w * 16 + (l >> 2)) * K + gc8;
    const unsigned short* pb1 = pb0 + (size_t)128 * K;
    auto stage = [&](int buf, int k0) {
        if (w < 2) gload_lds16(pa + k0, &As2[buf][w * 512]);
        gload_lds16(pb0 + k0, &Bs2[buf][w * 512]);
        gload_lds16(pb1 + k0, &Bs2[buf][w * 512 + 4096]);
    };
    stage(0, 0);
    f32x4 acc[2][2] = {};
    __syncthreads();
    int nt = K >> 5;
    for (int kt = 0; kt < nt; ++kt) {
        int cur = kt & 1;
        if (kt < nt - 1) stage(cur ^ 1, (kt + 1) * 32);
        bf16x8 af[2], bfv[2];
#pragma unroll
        for (int i = 0; i < 2; i++) af[i] = *(const bf16x8*)&As2[cur][(i * 16 + lm16) * 32 + rc8];
#pragma unroll
        for (int j = 0; j < 2; j++) bfv[j] = *(const bf16x8*)&Bs2[cur][(w * 32 + j * 16 + lm16) * 32 + rc8];
#pragma unroll
        for (int i = 0; i < 2; i++)
#pragma unroll
            for (int j = 0; j < 2; j++)
                acc[i][j] = __builtin_amdgcn_mfma_f32_16x16x32_bf16(af[i], bfv[j], acc[i][j], 0, 0, 0);
        __syncthreads();
    }
    int colbase = w * 32;
    if (EPI == 2) {
        float rs[2][4] = {};
#pragma unroll
        for (int j = 0; j < 2; j++) {
            int col = colbase + j * 16 + lm16;
            float bs = bias[col], pw = p2w[col];
#pragma unroll
            for (int i = 0; i < 2; i++)
#pragma unroll
                for (int r = 0; r < 4; r++)
                    rs[i][r] += tanhf(acc[i][j][r] + bs) * pw;
        }
#pragma unroll
        for (int m2 = 1; m2 <= 8; m2 <<= 1)
#pragma unroll
            for (int i = 0; i < 2; i++)
#pragma unroll
                for (int r = 0; r < 4; r++) rs[i][r] += __shfl_xor(rs[i][r], m2);
        __syncthreads();
        if (lm16 == 0) {
#pragma unroll
            for (int i = 0; i < 2; i++)
#pragma unroll
                for (int r = 0; r < 4; r++) red[w][i * 16 + quad * 4 + r] = rs[i][r];
        }
        __syncthreads();
        if (t < 32) {
            float sc = p2b[0];
#pragma unroll
            for (int ww = 0; ww < 8; ww++) sc += red[ww][t];
            int row = bm + t;
            alphab[row] = expf(sc) * mask[row];
        }
        return;
    }
    float rs[2][4] = {};
#pragma unroll
    for (int j = 0; j < 2; j++) {
        int col = colbase + j * 16 + lm16;
        float bs = bias[col];
#pragma unroll
        for (int i = 0; i < 2; i++)
#pragma unroll
            for (int r = 0; r < 4; r++) {
                int row = bm + i * 16 + quad * 4 + r;
                float v = acc[i][j][r] + bs + xio[(size_t)row * 256 + col];
                acc[i][j][r] = v;
                rs[i][r] += v;
            }
    }
    float mean[2][4], rstd[2][4];
    if (EPI == 0) {
#pragma unroll
        for (int m2 = 1; m2 <= 8; m2 <<= 1)
#pragma unroll
            for (int i = 0; i < 2; i++)
#pragma unroll
                for (int r = 0; r < 4; r++) rs[i][r] += __shfl_xor(rs[i][r], m2);
        __syncthreads();
        if (lm16 == 0) {
#pragma unroll
            for (int i = 0; i < 2; i++)
#pragma unroll
                for (int r = 0; r < 4; r++) red[w][i * 16 + quad * 4 + r] = rs[i][r];
        }
        __syncthreads();
        float vs[2][4] = {};
#pragma unroll
        for (int i = 0; i < 2; i++)
#pragma unroll
            for (int r = 0; r < 4; r++) {
                int rr = i * 16 + quad * 4 + r;
                float s = 0.f;
#pragma unroll
                for (int ww = 0; ww < 8; ww++) s += red[ww][rr];
                mean[i][r] = s * (1.0f / 256.0f);
            }
#pragma unroll
        for (int j = 0; j < 2; j++)
#pragma unroll
            for (int i = 0; i < 2; i++)
#pragma unroll
                for (int r = 0; r < 4; r++) {
                    float d = acc[i][j][r] - mean[i][r];
                    vs[i][r] += d * d;
                }
#pragma unroll
        for (int m2 = 1; m2 <= 8; m2 <<= 1)
#pragma unroll
            for (int i = 0; i < 2; i++)
#pragma unroll
                for (int r = 0; r < 4; r++) vs[i][r] += __shfl_xor(vs[i][r], m2);
        __syncthreads();
        if (lm16 == 0) {
#pragma unroll
            for (int i = 0; i < 2; i++)
#pragma unroll
                for (int r = 0; r < 4; r++) red[w][i * 16 + quad * 4 + r] = vs[i][r];
        }
        __syncthreads();
#pragma unroll
        for (int i = 0; i < 2; i++)
#pragma unroll
            for (int r = 0; r < 4; r++) {
                int rr = i * 16 + quad * 4 + r;
                float s = 0.f;
#pragma unroll
                for (int ww = 0; ww < 8; ww++) s += red[ww][rr];
                rstd[i][r] = rsqrtf(s * (1.0f / 256.0f) + 1e-12f);
            }
    }
#pragma unroll
    for (int j = 0; j < 2; j++) {
        int col = colbase + j * 16 + lm16;
        float g  = (EPI == 0) ? lng[col] : 0.f;
        float bb = (EPI == 0) ? lnb[col] : 0.f;
#pragma unroll
        for (int i = 0; i < 2; i++)
#pragma unroll
            for (int r = 0; r < 4; r++) {
                int row = bm + i * 16 + quad * 4 + r;
                float v = acc[i][j][r];
                xio[(size_t)row * 256 + col] = v;
                float y = (EPI == 0) ? ((v - mean[i][r]) * rstd[i][r] * g + bb) : v;
                outb[(size_t)row * 256 + col] = f2bf(y);
            }
    }
}

// ---------------- k-max kernel: dash block-max -> pmax; also zeros ksum ----------------
#define ZERO_FLOATS 4352   // 16*272 floats (ksum only; ctx partials are overwritten)
__global__ __launch_bounds__(256) void phi_kmax_kernel(
    const unsigned short* __restrict__ kbf, const unsigned short* __restrict__ projbf,
    float* __restrict__ pmax, float* __restrict__ zbase)
{
    __shared__ uint4 As[64][9];
    __shared__ uint4 Bs[272][8];   // chunk-swizzled proj (slot c holds chunk c ^ (row&7))
    __shared__ float diag_s[64];
    __shared__ float sred[4];
    int t = threadIdx.x;
    int s0 = blockIdx.x * 64;
    int bh = blockIdx.y;
    int w = t >> 6, l = t & 63, lm16 = l & 15, quad = l >> 4;
    {
        int bid = blockIdx.y * 64 + blockIdx.x;
        for (int i = bid * 256 + t; i < ZERO_FLOATS; i += 1024 * 256) zbase[i] = 0.f;
    }
    {
        int arow = t >> 2, akoff = (t & 3) * 16;
        const uint4* ga = (const uint4*)(kbf + ((size_t)bh * 4096 + s0 + arow) * 64 + akoff);
        uint4 u0 = ga[0], u1 = ga[1];
        As[arow][(akoff >> 3)] = u0; As[arow][(akoff >> 3) + 1] = u1;
        float ss = sumsq8(u0) + sumsq8(u1);
        ss += __shfl_xor(ss, 1); ss += __shfl_xor(ss, 2);
        if ((t & 3) == 0) diag_s[arow] = DIAGC * ss;
    }
    {
        unsigned short* Pl = (unsigned short*)Bs;
        int gcp8 = ((l & 7) ^ ((l >> 3) & 7)) * 8;
        const unsigned short* ps = projbf + (size_t)(l >> 3) * 64 + gcp8;
        for (int i = w; i < 34; i += 4)
            gload_lds16(ps + (size_t)i * 512, Pl + i * 512);
    }
    __syncthreads();
    f32x4 acc[17] = {};
#pragma unroll
    for (int ks = 0; ks < 2; ks++) {
        bf16x8 af = *(const bf16x8*)&As[w * 16 + lm16][ks * 4 + quad];
#pragma unroll
        for (int j = 0; j < 17; j++) {
            bf16x8 bfv = *(const bf16x8*)&Bs[j * 16 + lm16][(ks * 4 + quad) ^ (lm16 & 7)];
            acc[j] = __builtin_amdgcn_mfma_f32_16x16x32_bf16(af, bfv, acc[j], 0, 0, 0);
        }
    }
    int rloc = w * 16 + quad * 4;
    float kmax = -1e30f;
#pragma unroll
    for (int j = 0; j < 17; j++) {
        int m = j * 16 + lm16;
        bool valid = m < 266;
#pragma unroll
        for (int r = 0; r < 4; r++)
            if (valid) kmax = fmaxf(kmax, acc[j][r] * DN - diag_s[rloc + r]);
    }
    kmax = wredmax(kmax);
    if (l == 0) sred[w] = kmax;
    __syncthreads();
    if (t == 0)
        pmax[(size_t)bh * 64 + blockIdx.x] =
            fmaxf(fmaxf(sred[0], sred[1]), fmaxf(sred[2], sred[3]));
}

// ---------------- fused ctx: m-half blocks; dash->exp->LDS->ctx MFMA + ksum ------------
// grid (2 m-halves, 16 bh, 16 z) = 512 blocks (2/CU). Wave = s-tile for dash,
// e-quarter for PV. One-chunk-ahead register prefetch of K/V. ctx partials go to
// private ctxP[z][bh][64][272] slices via plain stores (NO atomics).
__global__ __launch_bounds__(256) void ctx_fused_kernel(
    const unsigned short* __restrict__ kbf, const unsigned short* __restrict__ vT,
    const unsigned short* __restrict__ projbf, const float* __restrict__ pmax,
    float* __restrict__ ksum, float* __restrict__ ctxP)
{
    __shared__ uint4 Ap[144][8];              // proj m-half, chunk-swizzled (18432 B)
    __shared__ uint4 Ks[64][9];               // 9216 B
    __shared__ uint4 Vs[64][9];               // 9216 B
    __shared__ unsigned short kp_s[144][72];  // [m][s] bf16 (20736 B)
    __shared__ float diag_s[64];
    __shared__ float sred2[4];
    int t = threadIdx.x;
    int m0 = blockIdx.x * 144;                // 0 or 144
    int bh = blockIdx.y;
    int sb = blockIdx.z * 256;                // 4 chunks of 64 s
    int w = t >> 6, l = t & 63, lm16 = l & 15, quad = l >> 4;
    // ---- stage proj half via gload_lds (lane-constant source chunk swizzle) ----
    {
        unsigned short* Pl = (unsigned short*)Ap;
        int gcp8 = ((l & 7) ^ ((l >> 3) & 7)) * 8;
        const unsigned short* ps = projbf + (size_t)(m0 + (l >> 3)) * 64 + gcp8;
        for (int i = w; i < 18; i += 4)
            gload_lds16(ps + (size_t)i * 512, Pl + i * 512);
    }
    // ---- global k stabilizer ----
    float pm = -1e30f;
    for (int i = t; i < 1024; i += 256) pm = fmaxf(pm, pmax[i]);
    pm = wredmax(pm);
    if (l == 0) sred2[w] = pm;
    // ---- preload chunk 0 K/V to regs ----
    int srow = t >> 2, skoff = (t & 3) * 16, sk4 = skoff >> 3;
    const uint4* gk = (const uint4*)(kbf + ((size_t)bh * 4096 + sb + srow) * 64 + skoff);
    uint4 k0 = gk[0], k1 = gk[1];
    const uint4* gv = (const uint4*)(vT + ((size_t)bh * 64 + srow) * 4096 + sb + skoff);
    uint4 v0 = gv[0], v1 = gv[1];
    __syncthreads();
    float st = fmaxf(fmaxf(sred2[0], sred2[1]), fmaxf(sred2[2], sred2[3]));
    f32x4 accc[9] = {};
    float ksacc[9][4] = {};
    for (int kc = 0; kc < 4; kc++) {
        if (kc) __syncthreads();                   // A: prior PV reads done
        Ks[srow][sk4] = k0; Ks[srow][sk4 + 1] = k1;
        Vs[srow][sk4] = v0; Vs[srow][sk4 + 1] = v1;
        float ss = sumsq8(k0) + sumsq8(k1);
        ss += __shfl_xor(ss, 1); ss += __shfl_xor(ss, 2);
        if ((t & 3) == 0) diag_s[srow] = DIAGC * ss;
        __syncthreads();                           // B: staging visible (drains gloads)
        if (kc < 3) {                              // prefetch next chunk; hides under dash+exp
            int sc = sb + (kc + 1) * 64;
            const uint4* gk2 = (const uint4*)(kbf + ((size_t)bh * 4096 + sc + srow) * 64 + skoff);
            k0 = gk2[0]; k1 = gk2[1];
            const uint4* gv2 = (const uint4*)(vT + ((size_t)bh * 64 + srow) * 4096 + sc + skoff);
            v0 = gv2[0]; v1 = gv2[1];
        }
        // ---- dash [144 m][64 s]: wave w owns s-tile w; diag is per-thread scalar ----
        float dgv = diag_s[w * 16 + lm16];
#pragma unroll
        for (int jm = 0; jm < 9; jm++) {
            f32x4 accd = {};
#pragma unroll
            for (int ks = 0; ks < 2; ks++) {
                bf16x8 af = *(const bf16x8*)&Ap[jm * 16 + lm16][(ks * 4 + quad) ^ (lm16 & 7)];
                bf16x8 bfv = *(const bf16x8*)&Ks[w * 16 + lm16][ks * 4 + quad];
                accd = __builtin_amdgcn_mfma_f32_16x16x32_bf16(af, bfv, accd, 0, 0, 0);
            }
#pragma unroll
            for (int r = 0; r < 4; r++) {
                int mg = m0 + jm * 16 + quad * 4 + r;
                float v = accd[r] * DN - dgv;
                float e = (mg < 266) ? RATIO * (__expf(v - st) + FEPS) : 0.f;
                kp_s[jm * 16 + quad * 4 + r][w * 16 + lm16] = f2bf(e);
                ksacc[jm][r] += e;
            }
        }
        __syncthreads();                           // C: kp visible
        // ---- PV: ctx[m][e] += kp[s][m]^T v[s][e]; wave w owns e-quarter w ----
#pragma unroll
        for (int ks = 0; ks < 2; ks++) {
            bf16x8 af = *(const bf16x8*)&Vs[w * 16 + lm16][ks * 4 + quad];
#pragma unroll
            for (int jt = 0; jt < 9; jt++) {
                bf16x8 bfv = *(const bf16x8*)&kp_s[jt * 16 + lm16][ks * 32 + quad * 8];
                accc[jt] = __builtin_amdgcn_mfma_f32_16x16x32_bf16(af, bfv, accc[jt], 0, 0, 0);
            }
        }
    }
    // ---- ksum: reduce over this wave's 16 s-lanes, one atomic per (m, wave) ----
#pragma unroll
    for (int jm = 0; jm < 9; jm++)
#pragma unroll
        for (int r = 0; r < 4; r++) {
            float vv = ksacc[jm][r];
            vv += __shfl_xor(vv, 1); vv += __shfl_xor(vv, 2);
            vv += __shfl_xor(vv, 4); vv += __shfl_xor(vv, 8);
            if (lm16 == 0) {
                int mg = m0 + jm * 16 + quad * 4 + r;
                if (mg < 272) atomicAdd(&ksum[bh * 272 + mg], vv);
            }
        }
    // ---- ctx partial store (private slice, no atomics) ----
    float* dst = ctxP + (size_t)(blockIdx.z * 16 + bh) * 64 * 272;
#pragma unroll
    for (int jt = 0; jt < 9; jt++) {
        int mg = m0 + jt * 16 + lm16;
        if (mg >= 272) continue;
#pragma unroll
        for (int r = 0; r < 4; r++) {
            int e = w * 16 + quad * 4 + r;
            dst[(size_t)e * 272 + mg] = accc[jt][r];
        }
    }
}

// ---------------- fused q-side: dash -> rowmax -> exp -> denom -> attn out ----------------
// ctx staged via global_load_lds (bf16, precast), double-buffered 16-e-row quarters,
// first two quarters prefetched under the exp phase. proj staged via global_load_lds.
__global__ __launch_bounds__(256) void phi_q_attn_kernel(
    const unsigned short* __restrict__ qbf, const unsigned short* __restrict__ projbf,
    const float* __restrict__ ksum, const unsigned short* __restrict__ ctxbf,
    unsigned short* __restrict__ abf)
{
    __shared__ uint4 uA[1152];       // stage1: q tile [64][9] (9216B); stage2: ctx dbuf 2x[16][288]us (18432B)
    __shared__ uint4 bufB[272][8];   // stage1: proj chunk-swizzled; stage2: qp ushort[64][272]
    __shared__ float diag_s[64];
    __shared__ float den_s[64];
    int t = threadIdx.x;
    int s0 = blockIdx.x * 64;
    int bh = blockIdx.y;
    int w = t >> 6, l = t & 63, lm16 = l & 15, quad = l >> 4;
    uint4 (*bufA)[9] = (uint4(*)[9])uA;
    {
        int arow = t >> 2, akoff = (t & 3) * 16;
        const uint4* ga = (const uint4*)(qbf + ((size_t)bh * 4096 + s0 + arow) * 64 + akoff);
        uint4 u0 = ga[0], u1 = ga[1];
        bufA[arow][(akoff >> 3)] = u0; bufA[arow][(akoff >> 3) + 1] = u1;
        float ss = sumsq8(u0) + sumsq8(u1);
        ss += __shfl_xor(ss, 1); ss += __shfl_xor(ss, 2);
        if ((t & 3) == 0) diag_s[arow] = DIAGC * ss;
    }
    {
        unsigned short* Pl = (unsigned short*)bufB;
        int gcp8 = ((l & 7) ^ ((l >> 3) & 7)) * 8;
        const unsigned short* ps = projbf + (size_t)(l >> 3) * 64 + gcp8;
        for (int i = w; i < 34; i += 4)
            gload_lds16(ps + (size_t)i * 512, Pl + i * 512);
    }
    // ksum -> registers (saves LDS; keeps 3 blocks/CU)
    float ksv[17];
#pragma unroll
    for (int j = 0; j < 17; j++) ksv[j] = ksum[bh * 272 + j * 16 + lm16];
    __syncthreads();
    // ---- stage 1: dash[64 s][272 m] via 34 MFMAs; swizzled proj reads are bank-uniform ----
    f32x4 acc[17] = {};
#pragma unroll
    for (int ks = 0; ks < 2; ks++) {
        bf16x8 af = *(const bf16x8*)&bufA[w * 16 + lm16][ks * 4 + quad];
#pragma unroll
        for (int j = 0; j < 17; j++) {
            bf16x8 bfv = *(const bf16x8*)&bufB[j * 16 + lm16][(ks * 4 + quad) ^ (lm16 & 7)];
            acc[j] = __builtin_amdgcn_mfma_f32_16x16x32_bf16(af, bfv, acc[j], 0, 0, 0);
        }
    }
    int rloc = w * 16 + quad * 4;
    float dg[4];
#pragma unroll
    for (int r = 0; r < 4; r++) dg[r] = diag_s[rloc + r];
    float vmax[4] = {-1e30f, -1e30f, -1e30f, -1e30f};
#pragma unroll
    for (int j = 0; j < 17; j++) {
        int m = j * 16 + lm16;
        bool valid = m < 266;
#pragma unroll
        for (int r = 0; r < 4; r++) {
            float v = acc[j][r] * DN - dg[r];
            acc[j][r] = v;
            if (valid) vmax[r] = fmaxf(vmax[r], v);
        }
    }
#pragma unroll
    for (int m2 = 1; m2 <= 8; m2 <<= 1)
#pragma unroll
        for (int r = 0; r < 4; r++) vmax[r] = fmaxf(vmax[r], __shfl_xor(vmax[r], m2));
    __syncthreads();   // all waves done reading bufA/bufB -> safe to overwrite with ctx/qp
    // ---- prefetch ctx quarters 0+1 (18KB) into dbuf; latency hides under exp phase ----
    unsigned short* ctxs = (unsigned short*)uA;
    const unsigned short* ctxg = ctxbf + (size_t)bh * 64 * 288;
    for (int i = w; i < 18; i += 4)
        gload_lds16(ctxg + i * 512 + l * 8, ctxs + i * 512);
    // ---- exp phase: qp -> LDS (bf16), denom via register ksum ----
    unsigned short* qp_s = (unsigned short*)bufB;    // [64][272]
    float den[4] = {0.f, 0.f, 0.f, 0.f};
#pragma unroll
    for (int j = 0; j < 17; j++) {
        int m = j * 16 + lm16;
        bool valid = m < 266;
#pragma unroll
        for (int r = 0; r < 4; r++) {
            float e = valid ? RATIO * (__expf(acc[j][r] - vmax[r]) + FEPS) : 0.f;
            qp_s[(rloc + r) * 272 + m] = f2bf(e);
            den[r] += e * ksv[j];
        }
    }
#pragma unroll
    for (int m2 = 1; m2 <= 8; m2 <<= 1)
#pragma unroll
        for (int r = 0; r < 4; r++) den[r] += __shfl_xor(den[r], m2);
    if (lm16 == 0) {
#pragma unroll
        for (int r = 0; r < 4; r++) den_s[rloc + r] = den[r];
    }
    // qp rows [w*16, w*16+16) written by this wave only -> A-frags readable without barrier
    bf16x8 paf[9];
#pragma unroll
    for (int kk = 0; kk < 9; kk++)
        paf[kk] = *(const bf16x8*)&qp_s[(w * 16 + lm16) * 272 + kk * 32 + quad * 8];
    __syncthreads();   // drains gload_lds vmcnt: quarters 0+1 resident
    // ---- stage 2: out[64 s][64 e] = qp @ ctx^T, 4 quarters x 9 MFMAs, dbuf'd ----
    int b = bh >> 2, h = bh & 3;
    f32x4 oacc[4] = {};
#pragma unroll
    for (int qd = 0; qd < 4; qd++) {
        const unsigned short* cs = ctxs + (qd & 1) * 4608;
#pragma unroll
        for (int kk = 0; kk < 9; kk++) {
            bf16x8 bfv = *(const bf16x8*)&cs[lm16 * 288 + kk * 32 + quad * 8];
            oacc[qd] = __builtin_amdgcn_mfma_f32_16x16x32_bf16(paf[kk], bfv, oacc[qd], 0, 0, 0);
        }
        if (qd < 3) {
            __syncthreads();   // waves done reading this buf; drains in-flight quarter loads
            if (qd < 2) {
                for (int i = w; i < 9; i += 4)
                    gload_lds16(ctxg + (qd + 2) * 4608 + i * 512 + l * 8,
                                ctxs + (qd & 1) * 4608 + i * 512);
            }
        }
    }
#pragma unroll
    for (int qd = 0; qd < 4; qd++) {
        int e = qd * 16 + lm16;
#pragma unroll
        for (int r = 0; r < 4; r++) {
            int sl = rloc + r;
            abf[((size_t)(b * 4096 + s0 + sl)) * 256 + h * 64 + e] = f2bf(oacc[qd][r] / den_s[sl]);
        }
    }
}

// ---------------- pooling tail ----------------
__global__ __launch_bounds__(256) void pool_denom_kernel(
    const float* __restrict__ alpha, float* __restrict__ denomb)
{
    __shared__ float sred[4];
    int b = blockIdx.x, t = threadIdx.x;
    float p = 0.f;
    for (int s = t; s < 4096; s += 256) p += alpha[b * 4096 + s];
    p = wredsum(p);
    if ((t & 63) == 0) sred[t >> 6] = p;
    __syncthreads();
    if (t == 0) denomb[b] = sred[0] + sred[1] + sred[2] + sred[3] + 1e-8f;
}

__global__ __launch_bounds__(256) void pool_out_kernel(
    const float* __restrict__ x, const float* __restrict__ alpha,
    const float* __restrict__ denomb, float* __restrict__ out)
{
    int b = blockIdx.x, chunk = blockIdx.y, t = threadIdx.x;
    float inv = 1.0f / denomb[b];
    float acc = 0.f;
    int s0 = chunk * 128;
    for (int s = s0; s < s0 + 128; s++)
        acc += x[((size_t)(b << 12) + s) * 256 + t] * alpha[(b << 12) + s];
    atomicAdd(&out[b * 256 + t], acc * inv);
}

extern "C" void kernel_launch(void* const* d_in, const int* in_sizes, int n_in,
                              void* d_out, int out_size, void* d_ws, size_t ws_size,
                              hipStream_t stream)
{
    const float* input_embs = (const float*)d_in[0];
    const float* mask  = (const float*)d_in[1];
    const float* pos   = (const float*)d_in[2];
    const float* ln_g  = (const float*)d_in[3];
    const float* ln_b  = (const float*)d_in[4];
    const float* proj  = (const float*)d_in[5];
    const float* Wq = (const float*)d_in[6];  const float* bq = (const float*)d_in[7];
    const float* Wk = (const float*)d_in[8];  const float* bk = (const float*)d_in[9];
    const float* Wv = (const float*)d_in[10]; const float* bv = (const float*)d_in[11];
    const float* Wo = (const float*)d_in[12]; const float* bo = (const float*)d_in[13];
    const float* ln1g = (const float*)d_in[14]; const float* ln1b = (const float*)d_in[15];
    const float* W1 = (const float*)d_in[16]; const float* b1 = (const float*)d_in[17];
    const float* W2 = (const float*)d_in[18]; const float* b2 = (const float*)d_in[19];
    const float* ln2g = (const float*)d_in[20]; const float* ln2b = (const float*)d_in[21];
    const float* p1w = (const float*)d_in[22]; const float* p1b = (const float*)d_in[23];
    const float* p2w = (const float*)d_in[24]; const float* p2b = (const float*)d_in[25];
    float* out = (float*)d_out;
    char* ws = (char*)d_ws;

    size_t off = 0;
    auto alloc = [&](size_t bytes) { size_t o = off; off += WS_ALIGN(bytes); return o; };
    float* xbuf = (float*)(ws + alloc(16384ull * 256 * 4));
    unsigned short* hbf = (unsigned short*)(ws + alloc(16384ull * 256 * 2));   // ln-out / attn-out
    unsigned short* qbf = (unsigned short*)(ws + alloc(16384ull * 256 * 2));
    unsigned short* kbf = (unsigned short*)(ws + alloc(16384ull * 256 * 2));
    unsigned short* vT  = (unsigned short*)(ws + alloc(16384ull * 256 * 2));
    unsigned short* midbf = (unsigned short*)(ws + alloc(16384ull * 1024 * 2)); // FFN mid
    float* ksum = (float*)(ws + alloc(16ull * 272 * 4));      // zeroed in phi_kmax
    float* ctxP = (float*)(ws + alloc(16ull * 16 * 64 * 272 * 4)); // z-partials (17.8 MB)
    float* pmaxb = (float*)(ws + alloc(1024ull * 4));
    float* alphab = (float*)(ws + alloc(16384ull * 4));
    float* pdenom = (float*)(ws + alloc(256));
    unsigned short* Wqt = (unsigned short*)(ws + alloc(4ull * 65536 * 2));
    unsigned short* Wkt = (unsigned short*)(ws + alloc(4ull * 65536 * 2));
    unsigned short* Wvt = (unsigned short*)(ws + alloc(4ull * 65536 * 2));
    unsigned short* Wot = (unsigned short*)(ws + alloc(4ull * 65536 * 2));
    unsigned short* W1t = (unsigned short*)(ws + alloc(4ull * 262144 * 2));
    unsigned short* W2t = (unsigned short*)(ws + alloc(4ull * 262144 * 2));
    unsigned short* projbf = (unsigned short*)(ws + alloc(4ull * 20480 * 2)); // padded [L][320][64]
    unsigned short* p1t = (unsigned short*)(ws + alloc(65536ull * 2));
    unsigned short* ctxbf = (unsigned short*)(ws + alloc(16ull * 64 * 288 * 2)); // padded bf16 ctx
    unsigned short* abf = hbf;
    // total ~111 MB (< 256 MiB)

    // ---- weight casts (all layers up front) ----
    cast_transpose4_kernel<<<dim3(8, 8, 16), 256, 0, stream>>>(Wq, Wk, Wv, Wo, Wqt, Wkt, Wvt, Wot);
    cast_transpose_kernel<<<dim3(32, 8, 4), 256, 0, stream>>>(W1, W1t, 256, 1024);
    cast_transpose_kernel<<<dim3(8, 32, 4), 256, 0, stream>>>(W2, W2t, 1024, 256);
    cast_transpose_kernel<<<dim3(8, 8, 1), 256, 0, stream>>>(p1w, p1t, 256, 256);
    proj_cast_kernel<<<40, 256, 0, stream>>>(proj, projbf);

    // ---- x = LN(input + pos); hbf = LN1_0(x) — single fused kernel (wave-per-row) ----
    add_ln2_kernel<<<4096, 256, 0, stream>>>(input_embs, pos, ln_g, ln_b, ln1g, ln1b, xbuf, hbf);

    for (int i = 0; i < 4; i++) {
        const unsigned short* pj = projbf + (size_t)i * 20480;
        // QKV fused (2-phase gload_lds dbuf; coalesced vT epilogue)
        qkv_kernel<<<dim3(12, 128), 256, 0, stream>>>(hbf,
            Wqt + (size_t)i * 65536, Wkt + (size_t)i * 65536, Wvt + (size_t)i * 65536,
            bq + i * 256, bk + i * 256, bv + i * 256, qbf, kbf, vT);
        // k stabilizer block-max + zero ksum
        phi_kmax_kernel<<<dim3(64, 16), 256, 0, stream>>>(kbf, pj, pmaxb, ksum);
        // fused k-exp + ksum + ctx partials (m-halves, reg prefetch, no ctx atomics)
        ctx_fused_kernel<<<dim3(2, 16, 16), 256, 0, stream>>>(kbf, vT, pj, pmaxb, ksum, ctxP);
        // ctx partial reduce (16 z) + cast -> bf16 [bh][64][288]
        ctx_reduce_cast_kernel<<<144, 256, 0, stream>>>(ctxP, ctxbf);
        // fused q-side: dash + exp + denom + attn out (ctx async-staged, dbuf'd)
        phi_q_attn_kernel<<<dim3(64, 16), 256, 0, stream>>>(qbf, pj, ksum, ctxbf, abf);
        // Wo + residual + LN2 fused (32-row blocks, 2 blocks/CU)
        gemm_fullrow_kernel<0><<<512, 512, 0, stream>>>(abf, Wot + (size_t)i * 65536,
            bo + i * 256, xbuf, ln2g + i * 256, ln2b + i * 256, hbf,
            nullptr, nullptr, nullptr, nullptr, 256);
        // FFN (2-phase gload_lds dbuf)
        ffn1_kernel<<<dim3(16, 128), 256, 0, stream>>>(hbf, W1t + (size_t)i * 262144,
            b1 + i * 1024, midbf, 1024, 256);
        if (i < 3)
            gemm_fullrow_kernel<0><<<512, 512, 0, stream>>>(midbf, W2t + (size_t)i * 262144,
                b2 + i * 256, xbuf, ln1g + (i + 1) * 256, ln1b + (i + 1) * 256, hbf,
                nullptr, nullptr, nullptr, nullptr, 1024);
        else
            gemm_fullrow_kernel<1><<<512, 512, 0, stream>>>(midbf, W2t + (size_t)i * 262144,
                b2 + i * 256, xbuf, nullptr, nullptr, hbf,
                nullptr, nullptr, nullptr, nullptr, 1024);
    }

    // ---- attention pooling (score fused into GEMM) ----
    gemm_fullrow_kernel<2><<<512, 512, 0, stream>>>(hbf, p1t, p1b, nullptr, nullptr, nullptr,
        nullptr, p2w, p2b, mask, alphab, 256);
    pool_denom_kernel<<<4, 256, 0, stream>>>(alphab, pdenom);
    hipMemsetAsync(d_out, 0, (size_t)out_size * sizeof(float), stream);
    pool_out_kernel<<<dim3(4, 32), 256, 0, stream>>>(xbuf, alphab, pdenom, out);
}

// Round 15
// 749.970 us; speedup vs baseline: 1.0184x; 1.0041x over previous
//
#include <hip/hip_runtime.h>
#include <math.h>

// Performer encoder on MI355X: B=4, S=4096, D=256, H=4, DH=64, L=4, M=266.
// bf16 MFMA everywhere; fp32 residual stream / LN stats / softmax logic.
// Round 26: r22 proven base (750.8/753.1 µs) + ISOLATED pooling merge from r23:
// pool_denom folded into pool_out (each block recomputes denom with the
// IDENTICAL wredsum tree/order -> bit-exact), removing one dispatch and the
// pdenom buffer. This was the only un-banked piece of r23's bundle (its
// regression was attributed to the RT=1 change by bracket analysis).
// All other kernels byte-identical to r22.

#define WS_ALIGN(x) (((x) + 255) & ~(size_t)255)

#define DN 0.35355339059327373f      // 64^-0.25
#define DIAGC 0.0625f                 // 0.5 * 64^-0.5
#define RATIO 0.06131393394849658f    // 266^-0.5
#define FEPS 1e-4f

typedef __attribute__((__ext_vector_type__(8))) __bf16 bf16x8;
typedef __attribute__((__ext_vector_type__(4))) float f32x4;

__device__ __forceinline__ float wredsum(float v) {
    v += __shfl_xor(v, 32); v += __shfl_xor(v, 16); v += __shfl_xor(v, 8);
    v += __shfl_xor(v, 4);  v += __shfl_xor(v, 2);  v += __shfl_xor(v, 1);
    return v;
}
__device__ __forceinline__ float wredmax(float v) {
    v = fmaxf(v, __shfl_xor(v, 32)); v = fmaxf(v, __shfl_xor(v, 16));
    v = fmaxf(v, __shfl_xor(v, 8));  v = fmaxf(v, __shfl_xor(v, 4));
    v = fmaxf(v, __shfl_xor(v, 2));  v = fmaxf(v, __shfl_xor(v, 1));
    return v;
}

__device__ __forceinline__ unsigned short f2bf(float f) {
    unsigned u = __builtin_bit_cast(unsigned, f);
    return (unsigned short)((u + 0x7fffu + ((u >> 16) & 1u)) >> 16);
}
__device__ __forceinline__ float blo(unsigned x) { return __builtin_bit_cast(float, x << 16); }
__device__ __forceinline__ float bhi(unsigned x) { return __builtin_bit_cast(float, x & 0xffff0000u); }
__device__ __forceinline__ float sumsq8(uint4 u) {
    float s = 0.f;
    s += blo(u.x)*blo(u.x) + bhi(u.x)*bhi(u.x);
    s += blo(u.y)*blo(u.y) + bhi(u.y)*bhi(u.y);
    s += blo(u.z)*blo(u.z) + bhi(u.z)*bhi(u.z);
    s += blo(u.w)*blo(u.w) + bhi(u.w)*bhi(u.w);
    return s;
}
__device__ __forceinline__ unsigned pack2(float a, float b) {
    return (unsigned)f2bf(a) | ((unsigned)f2bf(b) << 16);
}

// async global -> LDS, 16B per lane: LDS dest is wave-uniform base + lane*16,
// global src is per-lane.
__device__ __forceinline__ void gload_lds16(const unsigned short* g, unsigned short* lds) {
    __builtin_amdgcn_global_load_lds(
        (const __attribute__((address_space(1))) unsigned int*)g,
        (__attribute__((address_space(3))) unsigned int*)lds, 16, 0, 0);
}

// ---------------- fused double LayerNorm: x = LN0(in+pos); h = bf16(LN1(x)) ----------------
// Wave-per-row: 4 waves/block, lane holds float4 -> all reductions are shfl butterflies.
__global__ __launch_bounds__(256) void add_ln2_kernel(
    const float* __restrict__ in, const float* __restrict__ pos,
    const float* __restrict__ g0, const float* __restrict__ b0,
    const float* __restrict__ g1, const float* __restrict__ b1,
    float* __restrict__ xout, unsigned short* __restrict__ hout)
{
    int t = threadIdx.x;
    int row = blockIdx.x * 4 + (t >> 6);
    int l = t & 63;
    float4 vi = ((const float4*)(in + (size_t)row * 256))[l];
    float4 vp = ((const float4*)(pos + (size_t)(row & 4095) * 256))[l];
    float4 v = {vi.x + vp.x, vi.y + vp.y, vi.z + vp.z, vi.w + vp.w};
    float mean = wredsum(v.x + v.y + v.z + v.w) * (1.0f / 256.0f);
    float4 d = {v.x - mean, v.y - mean, v.z - mean, v.w - mean};
    float var = wredsum(d.x * d.x + d.y * d.y + d.z * d.z + d.w * d.w) * (1.0f / 256.0f);
    float rs = rsqrtf(var + 1e-12f);
    float4 g = ((const float4*)g0)[l], bb = ((const float4*)b0)[l];
    float4 y1 = {d.x * rs * g.x + bb.x, d.y * rs * g.y + bb.y,
                 d.z * rs * g.z + bb.z, d.w * rs * g.w + bb.w};
    ((float4*)(xout + (size_t)row * 256))[l] = y1;
    float mean1 = wredsum(y1.x + y1.y + y1.z + y1.w) * (1.0f / 256.0f);
    float4 d1 = {y1.x - mean1, y1.y - mean1, y1.z - mean1, y1.w - mean1};
    float var1 = wredsum(d1.x * d1.x + d1.y * d1.y + d1.z * d1.z + d1.w * d1.w) * (1.0f / 256.0f);
    float rs1 = rsqrtf(var1 + 1e-12f);
    float4 g1v = ((const float4*)g1)[l], b1v = ((const float4*)b1)[l];
    ushort4 o;
    o.x = f2bf(d1.x * rs1 * g1v.x + b1v.x);
    o.y = f2bf(d1.y * rs1 * g1v.y + b1v.y);
    o.z = f2bf(d1.z * rs1 * g1v.z + b1v.z);
    o.w = f2bf(d1.w * rs1 * g1v.w + b1v.w);
    ((ushort4*)(hout + (size_t)row * 256))[l] = o;
}

// ---------------- weight cast/transpose: fp32 [R][C] -> bf16 [C][R] ----------------
__global__ __launch_bounds__(256) void cast_transpose_kernel(
    const float* __restrict__ in, unsigned short* __restrict__ out, int R, int C)
{
    __shared__ float tile[32][33];
    size_t zo = (size_t)blockIdx.z * R * C;
    int c0 = blockIdx.x * 32, r0 = blockIdx.y * 32;
    int t = threadIdx.x, tc = t & 31, tr = t >> 5;
#pragma unroll
    for (int j = 0; j < 4; j++)
        tile[tr + j * 8][tc] = in[zo + (size_t)(r0 + tr + j * 8) * C + c0 + tc];
    __syncthreads();
#pragma unroll
    for (int j = 0; j < 4; j++) {
        int cc = tr + j * 8, rr = tc;
        out[zo + (size_t)(c0 + cc) * R + r0 + rr] = f2bf(tile[rr][cc]);
    }
}

// 4-way merged 256x256x4-layer cast/transpose (Wq,Wk,Wv,Wo in one dispatch)
__global__ __launch_bounds__(256) void cast_transpose4_kernel(
    const float* __restrict__ i0, const float* __restrict__ i1,
    const float* __restrict__ i2, const float* __restrict__ i3,
    unsigned short* __restrict__ o0, unsigned short* __restrict__ o1,
    unsigned short* __restrict__ o2, unsigned short* __restrict__ o3)
{
    __shared__ float tile[32][33];
    int z = blockIdx.z;
    int which = z >> 2, layer = z & 3;
    const float* in = (which == 0) ? i0 : (which == 1) ? i1 : (which == 2) ? i2 : i3;
    unsigned short* out = (which == 0) ? o0 : (which == 1) ? o1 : (which == 2) ? o2 : o3;
    size_t zo = (size_t)layer * 65536;
    int c0 = blockIdx.x * 32, r0 = blockIdx.y * 32;
    int t = threadIdx.x, tc = t & 31, tr = t >> 5;
#pragma unroll
    for (int j = 0; j < 4; j++)
        tile[tr + j * 8][tc] = in[zo + (size_t)(r0 + tr + j * 8) * 256 + c0 + tc];
    __syncthreads();
#pragma unroll
    for (int j = 0; j < 4; j++) {
        int cc = tr + j * 8, rr = tc;
        out[zo + (size_t)(c0 + cc) * 256 + r0 + rr] = f2bf(tile[rr][cc]);
    }
}

// ---------------- proj fp32 [L][266][64] -> bf16 [L][320][64] (zero-padded) --------------
__global__ __launch_bounds__(256) void proj_cast_kernel(
    const float* __restrict__ proj, unsigned short* __restrict__ projbf)
{
    int idx = blockIdx.x * 256 + threadIdx.x;   // 4*320*8 = 10240 chunks of 16B
    if (idx >= 10240) return;
    int li = idx / 2560; int rem = idx - li * 2560;
    int m = rem >> 3; int c = rem & 7;
    uint4 pk = {0, 0, 0, 0};
    if (m < 266) {
        const float* src = proj + ((size_t)li * 266 + m) * 64 + c * 8;
        float4 f0 = *(const float4*)(src);
        float4 f1 = *(const float4*)(src + 4);
        pk.x = pack2(f0.x, f0.y); pk.y = pack2(f0.z, f0.w);
        pk.z = pack2(f1.x, f1.y); pk.w = pack2(f1.z, f1.w);
    }
    *(uint4*)(projbf + (size_t)idx * 8) = pk;
}

// ---------------- ctx partial reduce (16 z) + cast: fp32 -> bf16 [1024][288] -----------
__global__ __launch_bounds__(256) void ctx_reduce_cast_kernel(
    const float* __restrict__ ctxP, unsigned short* __restrict__ ctxbf)
{
    int idx = blockIdx.x * 256 + threadIdx.x;   // 36864 chunks = 1024 rows * 36
    int row = idx / 36;
    int c = idx - row * 36;
    int m = c * 8;
    uint4 pk = {0, 0, 0, 0};
    if (m < 272) {
        float4 s0 = {0.f, 0.f, 0.f, 0.f}, s1 = {0.f, 0.f, 0.f, 0.f};
#pragma unroll
        for (int z = 0; z < 16; z++) {
            const float* p = ctxP + ((size_t)(z * 1024 + row) * 272 + m);
            float4 a = *(const float4*)p;
            float4 b = *(const float4*)(p + 4);
            s0.x += a.x; s0.y += a.y; s0.z += a.z; s0.w += a.w;
            s1.x += b.x; s1.y += b.y; s1.z += b.z; s1.w += b.w;
        }
        pk.x = pack2(s0.x, s0.y); pk.y = pack2(s0.z, s0.w);
        pk.z = pack2(s1.x, s1.y); pk.w = pack2(s1.z, s1.w);
    }
    *(uint4*)(ctxbf + (size_t)row * 288 + c * 8) = pk;
}

// ---------------- fused QKV GEMM (N=768 over q|k|v), K=256 — 2-phase gload_lds dbuf ------
// vT epilogue: acc -> LDS [64e][136] (union-aliased onto staging) -> coalesced 16B stores.
__global__ __launch_bounds__(256) void qkv_kernel(
    const unsigned short* __restrict__ A,
    const unsigned short* __restrict__ Wqt, const unsigned short* __restrict__ Wkt,
    const unsigned short* __restrict__ Wvt,
    const float* __restrict__ bq, const float* __restrict__ bk, const float* __restrict__ bv,
    unsigned short* __restrict__ qbf, unsigned short* __restrict__ kbf,
    unsigned short* __restrict__ vT)
{
    __shared__ union {
        struct { unsigned short As[2][4096]; unsigned short Bs[2][2048]; } st;
        unsigned short vt[64][136];   // 17408 B < 24576 B
    } u;
    const int K = 256;
    int t = threadIdx.x;
    int bm = blockIdx.y * 128, bn = blockIdx.x * 64;
    int grp = bn >> 8, lbn = bn & 255;
    const unsigned short* Bt = (grp == 0) ? Wqt : (grp == 1) ? Wkt : Wvt;
    const float* bias = (grp == 0) ? bq : (grp == 1) ? bk : bv;
    int w = t >> 6, l = t & 63, lm16 = l & 15, quad = l >> 4;
    int gc8 = ((l & 3) ^ ((l >> 3) & 3)) * 8;          // lane-constant source chunk swizzle
    int rc8 = (quad ^ ((lm16 >> 1) & 3)) * 8;          // read-side chunk swizzle
    const unsigned short* pa0 = A + (size_t)(bm + w * 16 + (l >> 2)) * K + gc8;
    const unsigned short* pa1 = pa0 + (size_t)64 * K;
    const unsigned short* pb0 = Bt + (size_t)(lbn + w * 16 + (l >> 2)) * K + gc8;
    auto stage = [&](int buf, int k0) {
        gload_lds16(pa0 + k0, &u.st.As[buf][w * 512]);
        gload_lds16(pa1 + k0, &u.st.As[buf][w * 512 + 2048]);
        gload_lds16(pb0 + k0, &u.st.Bs[buf][w * 512]);
    };
    stage(0, 0);
    f32x4 acc[2][4] = {};
    __syncthreads();
    for (int kt = 0; kt < 8; ++kt) {
        int cur = kt & 1;
        if (kt < 7) stage(cur ^ 1, (kt + 1) * 32);
        bf16x8 af[2], bfr[4];
        af[0] = *(const bf16x8*)&u.st.As[cur][(w * 32 + lm16) * 32 + rc8];
        af[1] = *(const bf16x8*)&u.st.As[cur][(w * 32 + 16 + lm16) * 32 + rc8];
#pragma unroll
        for (int j = 0; j < 4; j++) bfr[j] = *(const bf16x8*)&u.st.Bs[cur][(j * 16 + lm16) * 32 + rc8];
#pragma unroll
        for (int i = 0; i < 2; i++)
#pragma unroll
            for (int j = 0; j < 4; j++)
                acc[i][j] = __builtin_amdgcn_mfma_f32_16x16x32_bf16(af[i], bfr[j], acc[i][j], 0, 0, 0);
        __syncthreads();
    }
    if (grp == 2) {
        // v group: LDS transpose -> coalesced stores (staging LDS dead after loop barrier)
#pragma unroll
        for (int i = 0; i < 2; i++)
#pragma unroll
            for (int j = 0; j < 4; j++) {
                float bs = bias[lbn + j * 16 + lm16];
#pragma unroll
                for (int r = 0; r < 4; r++)
                    u.vt[j * 16 + lm16][w * 32 + i * 16 + quad * 4 + r] = f2bf(acc[i][j][r] + bs);
            }
        __syncthreads();
        int b = bm >> 12, s0 = bm & 4095;
        size_t base = (size_t)((b << 2) + (lbn >> 6)) * 64 * 4096 + s0;
        int e = t >> 2, c = t & 3;
#pragma unroll
        for (int k = 0; k < 4; k++) {
            uint4 vv = *(const uint4*)&u.vt[e][c * 32 + k * 8];
            *(uint4*)(vT + base + (size_t)e * 4096 + c * 32 + k * 8) = vv;
        }
        return;
    }
#pragma unroll
    for (int i = 0; i < 2; i++)
#pragma unroll
        for (int j = 0; j < 4; j++) {
            int lcol = lbn + j * 16 + lm16;
            float bs = bias[lcol];
            int h = lcol >> 6, e = lcol & 63;
#pragma unroll
            for (int r = 0; r < 4; r++) {
                int row = bm + w * 32 + i * 16 + quad * 4 + r;
                int b = row >> 12, s = row & 4095;
                float v = acc[i][j][r] + bs;
                if (grp == 0)
                    qbf[((size_t)((b << 2) + h) * 4096 + s) * 64 + e] = f2bf(v);
                else
                    kbf[((size_t)((b << 2) + h) * 4096 + s) * 64 + e] = f2bf(v);
            }
        }
}

// ---------------- FFN1 GEMM — 2-phase gload_lds dbuf: gelu(tanh) epilogue, bf16 out -------
__global__ __launch_bounds__(256) void ffn1_kernel(
    const unsigned short* __restrict__ A, const unsigned short* __restrict__ Bt,
    const float* __restrict__ bias, unsigned short* __restrict__ Cb, int N, int K)
{
    __shared__ unsigned short As[2][4096];
    __shared__ unsigned short Bs[2][2048];
    int t = threadIdx.x;
    int bm = blockIdx.y * 128, bn = blockIdx.x * 64;
    int w = t >> 6, l = t & 63, lm16 = l & 15, quad = l >> 4;
    int gc8 = ((l & 3) ^ ((l >> 3) & 3)) * 8;
    int rc8 = (quad ^ ((lm16 >> 1) & 3)) * 8;
    const unsigned short* pa0 = A + (size_t)(bm + w * 16 + (l >> 2)) * K + gc8;
    const unsigned short* pa1 = pa0 + (size_t)64 * K;
    const unsigned short* pb0 = Bt + (size_t)(bn + w * 16 + (l >> 2)) * K + gc8;
    auto stage = [&](int buf, int k0) {
        gload_lds16(pa0 + k0, &As[buf][w * 512]);
        gload_lds16(pa1 + k0, &As[buf][w * 512 + 2048]);
        gload_lds16(pb0 + k0, &Bs[buf][w * 512]);
    };
    stage(0, 0);
    f32x4 acc[2][4] = {};
    __syncthreads();
    int nt = K >> 5;
    for (int kt = 0; kt < nt; ++kt) {
        int cur = kt & 1;
        if (kt < nt - 1) stage(cur ^ 1, (kt + 1) * 32);
        bf16x8 af[2], bfr[4];
        af[0] = *(const bf16x8*)&As[cur][(w * 32 + lm16) * 32 + rc8];
        af[1] = *(const bf16x8*)&As[cur][(w * 32 + 16 + lm16) * 32 + rc8];
#pragma unroll
        for (int j = 0; j < 4; j++) bfr[j] = *(const bf16x8*)&Bs[cur][(j * 16 + lm16) * 32 + rc8];
#pragma unroll
        for (int i = 0; i < 2; i++)
#pragma unroll
            for (int j = 0; j < 4; j++)
                acc[i][j] = __builtin_amdgcn_mfma_f32_16x16x32_bf16(af[i], bfr[j], acc[i][j], 0, 0, 0);
        __syncthreads();
    }
#pragma unroll
    for (int i = 0; i < 2; i++)
#pragma unroll
        for (int j = 0; j < 4; j++) {
            int col = bn + j * 16 + lm16;
            float bsv = bias[col];
#pragma unroll
            for (int r = 0; r < 4; r++) {
                int row = bm + w * 32 + i * 16 + quad * 4 + r;
                float v = acc[i][j][r] + bsv;
                float inner = 0.7978845608028654f * (v + 0.044715f * v * v * v);
                float gl = 0.5f * v * (1.0f + tanhf(inner));
                Cb[(size_t)row * N + col] = f2bf(gl);
            }
        }
}

// ---------------- fused full-row GEMM: 32 rows x N=256 per block, 512 threads ----------
// 2-phase gload_lds dbuf; 36 KB LDS; grid 512 = 2 blocks/CU (mutual stall cover).
// `red` aliased onto As2 (dead after K-loop).
template <int EPI>
__global__ __launch_bounds__(512) void gemm_fullrow_kernel(
    const unsigned short* __restrict__ A, const unsigned short* __restrict__ Bt,
    const float* __restrict__ bias, float* __restrict__ xio,
    const float* __restrict__ lng, const float* __restrict__ lnb,
    unsigned short* __restrict__ outb,
    const float* __restrict__ p2w, const float* __restrict__ p2b,
    const float* __restrict__ mask, float* __restrict__ alphab, int K)
{
    __shared__ unsigned short As2[2][1024];   // [32 rows][32 hw]
    __shared__ unsigned short Bs2[2][8192];   // [256 rows][32 hw]
    float (*red)[32] = (float (*)[32])As2;    // aliased; used only after K-loop (1KB < 4KB)
    int t = threadIdx.x;
    int bm = blockIdx.x * 32;
    int w = t >> 6, l = t & 63, lm16 = l & 15, quad = l >> 4;
    int gc8 = ((l & 3) ^ ((l >> 3) & 3)) * 8;
    int rc8 = (quad ^ ((lm16 >> 1) & 3)) * 8;
    const unsigned short* pa = A + (size_t)(bm + (w & 1) * 16 + (l >> 2)) * K + gc8;
    const unsigned short* pb0 = Bt + (size_t)(w * 16 + (l >> 2)) * K + gc8;
    const unsigned short* pb1 = pb0 + (size_t)128 * K;
    auto stage = [&](int buf, int k0) {
        if (w < 2) gload_lds16(pa + k0, &As2[buf][w * 512]);
        gload_lds16(pb0 + k0, &Bs2[buf][w * 512]);
        gload_lds16(pb1 + k0, &Bs2[buf][w * 512 + 4096]);
    };
    stage(0, 0);
    f32x4 acc[2][2] = {};
    __syncthreads();
    int nt = K >> 5;
    for (int kt = 0; kt < nt; ++kt) {
        int cur = kt & 1;
        if (kt < nt - 1) stage(cur ^ 1, (kt + 1) * 32);
        bf16x8 af[2], bfv[2];
#pragma unroll
        for (int i = 0; i < 2; i++) af[i] = *(const bf16x8*)&As2[cur][(i * 16 + lm16) * 32 + rc8];
#pragma unroll
        for (int j = 0; j < 2; j++) bfv[j] = *(const bf16x8*)&Bs2[cur][(w * 32 + j * 16 + lm16) * 32 + rc8];
#pragma unroll
        for (int i = 0; i < 2; i++)
#pragma unroll
            for (int j = 0; j < 2; j++)
                acc[i][j] = __builtin_amdgcn_mfma_f32_16x16x32_bf16(af[i], bfv[j], acc[i][j], 0, 0, 0);
        __syncthreads();
    }
    int colbase = w * 32;
    if (EPI == 2) {
        float rs[2][4] = {};
#pragma unroll
        for (int j = 0; j < 2; j++) {
            int col = colbase + j * 16 + lm16;
            float bs = bias[col], pw = p2w[col];
#pragma unroll
            for (int i = 0; i < 2; i++)
#pragma unroll
                for (int r = 0; r < 4; r++)
                    rs[i][r] += tanhf(acc[i][j][r] + bs) * pw;
        }
#pragma unroll
        for (int m2 = 1; m2 <= 8; m2 <<= 1)
#pragma unroll
            for (int i = 0; i < 2; i++)
#pragma unroll
                for (int r = 0; r < 4; r++) rs[i][r] += __shfl_xor(rs[i][r], m2);
        __syncthreads();
        if (lm16 == 0) {
#pragma unroll
            for (int i = 0; i < 2; i++)
#pragma unroll
                for (int r = 0; r < 4; r++) red[w][i * 16 + quad * 4 + r] = rs[i][r];
        }
        __syncthreads();
        if (t < 32) {
            float sc = p2b[0];
#pragma unroll
            for (int ww = 0; ww < 8; ww++) sc += red[ww][t];
            int row = bm + t;
            alphab[row] = expf(sc) * mask[row];
        }
        return;
    }
    float rs[2][4] = {};
#pragma unroll
    for (int j = 0; j < 2; j++) {
        int col = colbase + j * 16 + lm16;
        float bs = bias[col];
#pragma unroll
        for (int i = 0; i < 2; i++)
#pragma unroll
            for (int r = 0; r < 4; r++) {
                int row = bm + i * 16 + quad * 4 + r;
                float v = acc[i][j][r] + bs + xio[(size_t)row * 256 + col];
                acc[i][j][r] = v;
                rs[i][r] += v;
            }
    }
    float mean[2][4], rstd[2][4];
    if (EPI == 0) {
#pragma unroll
        for (int m2 = 1; m2 <= 8; m2 <<= 1)
#pragma unroll
            for (int i = 0; i < 2; i++)
#pragma unroll
                for (int r = 0; r < 4; r++) rs[i][r] += __shfl_xor(rs[i][r], m2);
        __syncthreads();
        if (lm16 == 0) {
#pragma unroll
            for (int i = 0; i < 2; i++)
#pragma unroll
                for (int r = 0; r < 4; r++) red[w][i * 16 + quad * 4 + r] = rs[i][r];
        }
        __syncthreads();
        float vs[2][4] = {};
#pragma unroll
        for (int i = 0; i < 2; i++)
#pragma unroll
            for (int r = 0; r < 4; r++) {
                int rr = i * 16 + quad * 4 + r;
                float s = 0.f;
#pragma unroll
                for (int ww = 0; ww < 8; ww++) s += red[ww][rr];
                mean[i][r] = s * (1.0f / 256.0f);
            }
#pragma unroll
        for (int j = 0; j < 2; j++)
#pragma unroll
            for (int i = 0; i < 2; i++)
#pragma unroll
                for (int r = 0; r < 4; r++) {
                    float d = acc[i][j][r] - mean[i][r];
                    vs[i][r] += d * d;
                }
#pragma unroll
        for (int m2 = 1; m2 <= 8; m2 <<= 1)
#pragma unroll
            for (int i = 0; i < 2; i++)
#pragma unroll
                for (int r = 0; r < 4; r++) vs[i][r] += __shfl_xor(vs[i][r], m2);
        __syncthreads();
        if (lm16 == 0) {
#pragma unroll
            for (int i = 0; i < 2; i++)
#pragma unroll
                for (int r = 0; r < 4; r++) red[w][i * 16 + quad * 4 + r] = vs[i][r];
        }
        __syncthreads();
#pragma unroll
        for (int i = 0; i < 2; i++)
#pragma unroll
            for (int r = 0; r < 4; r++) {
                int rr = i * 16 + quad * 4 + r;
                float s = 0.f;
#pragma unroll
                for (int ww = 0; ww < 8; ww++) s += red[ww][rr];
                rstd[i][r] = rsqrtf(s * (1.0f / 256.0f) + 1e-12f);
            }
    }
#pragma unroll
    for (int j = 0; j < 2; j++) {
        int col = colbase + j * 16 + lm16;
        float g  = (EPI == 0) ? lng[col] : 0.f;
        float bb = (EPI == 0) ? lnb[col] : 0.f;
#pragma unroll
        for (int i = 0; i < 2; i++)
#pragma unroll
            for (int r = 0; r < 4; r++) {
                int row = bm + i * 16 + quad * 4 + r;
                float v = acc[i][j][r];
                xio[(size_t)row * 256 + col] = v;
                float y = (EPI == 0) ? ((v - mean[i][r]) * rstd[i][r] * g + bb) : v;
                outb[(size_t)row * 256 + col] = f2bf(y);
            }
    }
}

// ---------------- k-max kernel: dash block-max -> pmax; also zeros ksum ----------------
#define ZERO_FLOATS 4352   // 16*272 floats (ksum only; ctx partials are overwritten)
__global__ __launch_bounds__(256) void phi_kmax_kernel(
    const unsigned short* __restrict__ kbf, const unsigned short* __restrict__ projbf,
    float* __restrict__ pmax, float* __restrict__ zbase)
{
    __shared__ uint4 As[64][9];
    __shared__ uint4 Bs[272][8];   // chunk-swizzled proj (slot c holds chunk c ^ (row&7))
    __shared__ float diag_s[64];
    __shared__ float sred[4];
    int t = threadIdx.x;
    int s0 = blockIdx.x * 64;
    int bh = blockIdx.y;
    int w = t >> 6, l = t & 63, lm16 = l & 15, quad = l >> 4;
    {
        int bid = blockIdx.y * 64 + blockIdx.x;
        for (int i = bid * 256 + t; i < ZERO_FLOATS; i += 1024 * 256) zbase[i] = 0.f;
    }
    {
        int arow = t >> 2, akoff = (t & 3) * 16;
        const uint4* ga = (const uint4*)(kbf + ((size_t)bh * 4096 + s0 + arow) * 64 + akoff);
        uint4 u0 = ga[0], u1 = ga[1];
        As[arow][(akoff >> 3)] = u0; As[arow][(akoff >> 3) + 1] = u1;
        float ss = sumsq8(u0) + sumsq8(u1);
        ss += __shfl_xor(ss, 1); ss += __shfl_xor(ss, 2);
        if ((t & 3) == 0) diag_s[arow] = DIAGC * ss;
    }
    {
        unsigned short* Pl = (unsigned short*)Bs;
        int gcp8 = ((l & 7) ^ ((l >> 3) & 7)) * 8;
        const unsigned short* ps = projbf + (size_t)(l >> 3) * 64 + gcp8;
        for (int i = w; i < 34; i += 4)
            gload_lds16(ps + (size_t)i * 512, Pl + i * 512);
    }
    __syncthreads();
    f32x4 acc[17] = {};
#pragma unroll
    for (int ks = 0; ks < 2; ks++) {
        bf16x8 af = *(const bf16x8*)&As[w * 16 + lm16][ks * 4 + quad];
#pragma unroll
        for (int j = 0; j < 17; j++) {
            bf16x8 bfv = *(const bf16x8*)&Bs[j * 16 + lm16][(ks * 4 + quad) ^ (lm16 & 7)];
            acc[j] = __builtin_amdgcn_mfma_f32_16x16x32_bf16(af, bfv, acc[j], 0, 0, 0);
        }
    }
    int rloc = w * 16 + quad * 4;
    float kmax = -1e30f;
#pragma unroll
    for (int j = 0; j < 17; j++) {
        int m = j * 16 + lm16;
        bool valid = m < 266;
#pragma unroll
        for (int r = 0; r < 4; r++)
            if (valid) kmax = fmaxf(kmax, acc[j][r] * DN - diag_s[rloc + r]);
    }
    kmax = wredmax(kmax);
    if (l == 0) sred[w] = kmax;
    __syncthreads();
    if (t == 0)
        pmax[(size_t)bh * 64 + blockIdx.x] =
            fmaxf(fmaxf(sred[0], sred[1]), fmaxf(sred[2], sred[3]));
}

// ---------------- fused ctx: m-half blocks; dash->exp->LDS->ctx MFMA + ksum ------------
// grid (2 m-halves, 16 bh, 16 z) = 512 blocks (2/CU). Wave = s-tile for dash,
// e-quarter for PV. One-chunk-ahead register prefetch of K/V. ctx partials go to
// private ctxP[z][bh][64][272] slices via plain stores (NO atomics).
__global__ __launch_bounds__(256) void ctx_fused_kernel(
    const unsigned short* __restrict__ kbf, const unsigned short* __restrict__ vT,
    const unsigned short* __restrict__ projbf, const float* __restrict__ pmax,
    float* __restrict__ ksum, float* __restrict__ ctxP)
{
    __shared__ uint4 Ap[144][8];              // proj m-half, chunk-swizzled (18432 B)
    __shared__ uint4 Ks[64][9];               // 9216 B
    __shared__ uint4 Vs[64][9];               // 9216 B
    __shared__ unsigned short kp_s[144][72];  // [m][s] bf16 (20736 B)
    __shared__ float diag_s[64];
    __shared__ float sred2[4];
    int t = threadIdx.x;
    int m0 = blockIdx.x * 144;                // 0 or 144
    int bh = blockIdx.y;
    int sb = blockIdx.z * 256;                // 4 chunks of 64 s
    int w = t >> 6, l = t & 63, lm16 = l & 15, quad = l >> 4;
    // ---- stage proj half via gload_lds (lane-constant source chunk swizzle) ----
    {
        unsigned short* Pl = (unsigned short*)Ap;
        int gcp8 = ((l & 7) ^ ((l >> 3) & 7)) * 8;
        const unsigned short* ps = projbf + (size_t)(m0 + (l >> 3)) * 64 + gcp8;
        for (int i = w; i < 18; i += 4)
            gload_lds16(ps + (size_t)i * 512, Pl + i * 512);
    }
    // ---- global k stabilizer ----
    float pm = -1e30f;
    for (int i = t; i < 1024; i += 256) pm = fmaxf(pm, pmax[i]);
    pm = wredmax(pm);
    if (l == 0) sred2[w] = pm;
    // ---- preload chunk 0 K/V to regs ----
    int srow = t >> 2, skoff = (t & 3) * 16, sk4 = skoff >> 3;
    const uint4* gk = (const uint4*)(kbf + ((size_t)bh * 4096 + sb + srow) * 64 + skoff);
    uint4 k0 = gk[0], k1 = gk[1];
    const uint4* gv = (const uint4*)(vT + ((size_t)bh * 64 + srow) * 4096 + sb + skoff);
    uint4 v0 = gv[0], v1 = gv[1];
    __syncthreads();
    float st = fmaxf(fmaxf(sred2[0], sred2[1]), fmaxf(sred2[2], sred2[3]));
    f32x4 accc[9] = {};
    float ksacc[9][4] = {};
    for (int kc = 0; kc < 4; kc++) {
        if (kc) __syncthreads();                   // A: prior PV reads done
        Ks[srow][sk4] = k0; Ks[srow][sk4 + 1] = k1;
        Vs[srow][sk4] = v0; Vs[srow][sk4 + 1] = v1;
        float ss = sumsq8(k0) + sumsq8(k1);
        ss += __shfl_xor(ss, 1); ss += __shfl_xor(ss, 2);
        if ((t & 3) == 0) diag_s[srow] = DIAGC * ss;
        __syncthreads();                           // B: staging visible (drains gloads)
        if (kc < 3) {                              // prefetch next chunk; hides under dash+exp
            int sc = sb + (kc + 1) * 64;
            const uint4* gk2 = (const uint4*)(kbf + ((size_t)bh * 4096 + sc + srow) * 64 + skoff);
            k0 = gk2[0]; k1 = gk2[1];
            const uint4* gv2 = (const uint4*)(vT + ((size_t)bh * 64 + srow) * 4096 + sc + skoff);
            v0 = gv2[0]; v1 = gv2[1];
        }
        // ---- dash [144 m][64 s]: wave w owns s-tile w; diag is per-thread scalar ----
        float dgv = diag_s[w * 16 + lm16];
#pragma unroll
        for (int jm = 0; jm < 9; jm++) {
            f32x4 accd = {};
#pragma unroll
            for (int ks = 0; ks < 2; ks++) {
                bf16x8 af = *(const bf16x8*)&Ap[jm * 16 + lm16][(ks * 4 + quad) ^ (lm16 & 7)];
                bf16x8 bfv = *(const bf16x8*)&Ks[w * 16 + lm16][ks * 4 + quad];
                accd = __builtin_amdgcn_mfma_f32_16x16x32_bf16(af, bfv, accd, 0, 0, 0);
            }
#pragma unroll
            for (int r = 0; r < 4; r++) {
                int mg = m0 + jm * 16 + quad * 4 + r;
                float v = accd[r] * DN - dgv;
                float e = (mg < 266) ? RATIO * (__expf(v - st) + FEPS) : 0.f;
                kp_s[jm * 16 + quad * 4 + r][w * 16 + lm16] = f2bf(e);
                ksacc[jm][r] += e;
            }
        }
        __syncthreads();                           // C: kp visible
        // ---- PV: ctx[m][e] += kp[s][m]^T v[s][e]; wave w owns e-quarter w ----
#pragma unroll
        for (int ks = 0; ks < 2; ks++) {
            bf16x8 af = *(const bf16x8*)&Vs[w * 16 + lm16][ks * 4 + quad];
#pragma unroll
            for (int jt = 0; jt < 9; jt++) {
                bf16x8 bfv = *(const bf16x8*)&kp_s[jt * 16 + lm16][ks * 32 + quad * 8];
                accc[jt] = __builtin_amdgcn_mfma_f32_16x16x32_bf16(af, bfv, accc[jt], 0, 0, 0);
            }
        }
    }
    // ---- ksum: reduce over this wave's 16 s-lanes, one atomic per (m, wave) ----
#pragma unroll
    for (int jm = 0; jm < 9; jm++)
#pragma unroll
        for (int r = 0; r < 4; r++) {
            float vv = ksacc[jm][r];
            vv += __shfl_xor(vv, 1); vv += __shfl_xor(vv, 2);
            vv += __shfl_xor(vv, 4); vv += __shfl_xor(vv, 8);
            if (lm16 == 0) {
                int mg = m0 + jm * 16 + quad * 4 + r;
                if (mg < 272) atomicAdd(&ksum[bh * 272 + mg], vv);
            }
        }
    // ---- ctx partial store (private slice, no atomics) ----
    float* dst = ctxP + (size_t)(blockIdx.z * 16 + bh) * 64 * 272;
#pragma unroll
    for (int jt = 0; jt < 9; jt++) {
        int mg = m0 + jt * 16 + lm16;
        if (mg >= 272) continue;
#pragma unroll
        for (int r = 0; r < 4; r++) {
            int e = w * 16 + quad * 4 + r;
            dst[(size_t)e * 272 + mg] = accc[jt][r];
        }
    }
}

// ---------------- fused q-side: dash -> rowmax -> exp -> denom -> attn out ----------------
// ctx staged via global_load_lds (bf16, precast), double-buffered 16-e-row quarters,
// first two quarters prefetched under the exp phase. proj staged via global_load_lds.
__global__ __launch_bounds__(256) void phi_q_attn_kernel(
    const unsigned short* __restrict__ qbf, const unsigned short* __restrict__ projbf,
    const float* __restrict__ ksum, const unsigned short* __restrict__ ctxbf,
    unsigned short* __restrict__ abf)
{
    __shared__ uint4 uA[1152];       // stage1: q tile [64][9] (9216B); stage2: ctx dbuf 2x[16][288]us (18432B)
    __shared__ uint4 bufB[272][8];   // stage1: proj chunk-swizzled; stage2: qp ushort[64][272]
    __shared__ float diag_s[64];
    __shared__ float den_s[64];
    int t = threadIdx.x;
    int s0 = blockIdx.x * 64;
    int bh = blockIdx.y;
    int w = t >> 6, l = t & 63, lm16 = l & 15, quad = l >> 4;
    uint4 (*bufA)[9] = (uint4(*)[9])uA;
    {
        int arow = t >> 2, akoff = (t & 3) * 16;
        const uint4* ga = (const uint4*)(qbf + ((size_t)bh * 4096 + s0 + arow) * 64 + akoff);
        uint4 u0 = ga[0], u1 = ga[1];
        bufA[arow][(akoff >> 3)] = u0; bufA[arow][(akoff >> 3) + 1] = u1;
        float ss = sumsq8(u0) + sumsq8(u1);
        ss += __shfl_xor(ss, 1); ss += __shfl_xor(ss, 2);
        if ((t & 3) == 0) diag_s[arow] = DIAGC * ss;
    }
    {
        unsigned short* Pl = (unsigned short*)bufB;
        int gcp8 = ((l & 7) ^ ((l >> 3) & 7)) * 8;
        const unsigned short* ps = projbf + (size_t)(l >> 3) * 64 + gcp8;
        for (int i = w; i < 34; i += 4)
            gload_lds16(ps + (size_t)i * 512, Pl + i * 512);
    }
    // ksum -> registers (saves LDS; keeps 3 blocks/CU)
    float ksv[17];
#pragma unroll
    for (int j = 0; j < 17; j++) ksv[j] = ksum[bh * 272 + j * 16 + lm16];
    __syncthreads();
    // ---- stage 1: dash[64 s][272 m] via 34 MFMAs; swizzled proj reads are bank-uniform ----
    f32x4 acc[17] = {};
#pragma unroll
    for (int ks = 0; ks < 2; ks++) {
        bf16x8 af = *(const bf16x8*)&bufA[w * 16 + lm16][ks * 4 + quad];
#pragma unroll
        for (int j = 0; j < 17; j++) {
            bf16x8 bfv = *(const bf16x8*)&bufB[j * 16 + lm16][(ks * 4 + quad) ^ (lm16 & 7)];
            acc[j] = __builtin_amdgcn_mfma_f32_16x16x32_bf16(af, bfv, acc[j], 0, 0, 0);
        }
    }
    int rloc = w * 16 + quad * 4;
    float dg[4];
#pragma unroll
    for (int r = 0; r < 4; r++) dg[r] = diag_s[rloc + r];
    float vmax[4] = {-1e30f, -1e30f, -1e30f, -1e30f};
#pragma unroll
    for (int j = 0; j < 17; j++) {
        int m = j * 16 + lm16;
        bool valid = m < 266;
#pragma unroll
        for (int r = 0; r < 4; r++) {
            float v = acc[j][r] * DN - dg[r];
            acc[j][r] = v;
            if (valid) vmax[r] = fmaxf(vmax[r], v);
        }
    }
#pragma unroll
    for (int m2 = 1; m2 <= 8; m2 <<= 1)
#pragma unroll
        for (int r = 0; r < 4; r++) vmax[r] = fmaxf(vmax[r], __shfl_xor(vmax[r], m2));
    __syncthreads();   // all waves done reading bufA/bufB -> safe to overwrite with ctx/qp
    // ---- prefetch ctx quarters 0+1 (18KB) into dbuf; latency hides under exp phase ----
    unsigned short* ctxs = (unsigned short*)uA;
    const unsigned short* ctxg = ctxbf + (size_t)bh * 64 * 288;
    for (int i = w; i < 18; i += 4)
        gload_lds16(ctxg + i * 512 + l * 8, ctxs + i * 512);
    // ---- exp phase: qp -> LDS (bf16), denom via register ksum ----
    unsigned short* qp_s = (unsigned short*)bufB;    // [64][272]
    float den[4] = {0.f, 0.f, 0.f, 0.f};
#pragma unroll
    for (int j = 0; j < 17; j++) {
        int m = j * 16 + lm16;
        bool valid = m < 266;
#pragma unroll
        for (int r = 0; r < 4; r++) {
            float e = valid ? RATIO * (__expf(acc[j][r] - vmax[r]) + FEPS) : 0.f;
            qp_s[(rloc + r) * 272 + m] = f2bf(e);
            den[r] += e * ksv[j];
        }
    }
#pragma unroll
    for (int m2 = 1; m2 <= 8; m2 <<= 1)
#pragma unroll
        for (int r = 0; r < 4; r++) den[r] += __shfl_xor(den[r], m2);
    if (lm16 == 0) {
#pragma unroll
        for (int r = 0; r < 4; r++) den_s[rloc + r] = den[r];
    }
    // qp rows [w*16, w*16+16) written by this wave only -> A-frags readable without barrier
    bf16x8 paf[9];
#pragma unroll
    for (int kk = 0; kk < 9; kk++)
        paf[kk] = *(const bf16x8*)&qp_s[(w * 16 + lm16) * 272 + kk * 32 + quad * 8];
    __syncthreads();   // drains gload_lds vmcnt: quarters 0+1 resident
    // ---- stage 2: out[64 s][64 e] = qp @ ctx^T, 4 quarters x 9 MFMAs, dbuf'd ----
    int b = bh >> 2, h = bh & 3;
    f32x4 oacc[4] = {};
#pragma unroll
    for (int qd = 0; qd < 4; qd++) {
        const unsigned short* cs = ctxs + (qd & 1) * 4608;
#pragma unroll
        for (int kk = 0; kk < 9; kk++) {
            bf16x8 bfv = *(const bf16x8*)&cs[lm16 * 288 + kk * 32 + quad * 8];
            oacc[qd] = __builtin_amdgcn_mfma_f32_16x16x32_bf16(paf[kk], bfv, oacc[qd], 0, 0, 0);
        }
        if (qd < 3) {
            __syncthreads();   // waves done reading this buf; drains in-flight quarter loads
            if (qd < 2) {
                for (int i = w; i < 9; i += 4)
                    gload_lds16(ctxg + (qd + 2) * 4608 + i * 512 + l * 8,
                                ctxs + (qd & 1) * 4608 + i * 512);
            }
        }
    }
#pragma unroll
    for (int qd = 0; qd < 4; qd++) {
        int e = qd * 16 + lm16;
#pragma unroll
        for (int r = 0; r < 4; r++) {
            int sl = rloc + r;
            abf[((size_t)(b * 4096 + s0 + sl)) * 256 + h * 64 + e] = f2bf(oacc[qd][r] / den_s[sl]);
        }
    }
}

// ---------------- pooling tail: denom + weighted sum in ONE kernel ----------------
// Each (b,chunk) block recomputes denom with the IDENTICAL wredsum tree/order
// as the old pool_denom kernel -> bit-exact.
__global__ __launch_bounds__(256) void pool_out_kernel(
    const float* __restrict__ x, const float* __restrict__ alpha,
    float* __restrict__ out)
{
    __shared__ float sred[4];
    int b = blockIdx.x, chunk = blockIdx.y, t = threadIdx.x;
    float p = 0.f;
    for (int s = t; s < 4096; s += 256) p += alpha[b * 4096 + s];
    p = wredsum(p);
    if ((t & 63) == 0) sred[t >> 6] = p;
    __syncthreads();
    float inv = 1.0f / (sred[0] + sred[1] + sred[2] + sred[3] + 1e-8f);
    float acc = 0.f;
    int s0 = chunk * 128;
    for (int s = s0; s < s0 + 128; s++)
        acc += x[((size_t)(b << 12) + s) * 256 + t] * alpha[(b << 12) + s];
    atomicAdd(&out[b * 256 + t], acc * inv);
}

extern "C" void kernel_launch(void* const* d_in, const int* in_sizes, int n_in,
                              void* d_out, int out_size, void* d_ws, size_t ws_size,
                              hipStream_t stream)
{
    const float* input_embs = (const float*)d_in[0];
    const float* mask  = (const float*)d_in[1];
    const float* pos   = (const float*)d_in[2];
    const float* ln_g  = (const float*)d_in[3];
    const float* ln_b  = (const float*)d_in[4];
    const float* proj  = (const float*)d_in[5];
    const float* Wq = (const float*)d_in[6];  const float* bq = (const float*)d_in[7];
    const float* Wk = (const float*)d_in[8];  const float* bk = (const float*)d_in[9];
    const float* Wv = (const float*)d_in[10]; const float* bv = (const float*)d_in[11];
    const float* Wo = (const float*)d_in[12]; const float* bo = (const float*)d_in[13];
    const float* ln1g = (const float*)d_in[14]; const float* ln1b = (const float*)d_in[15];
    const float* W1 = (const float*)d_in[16]; const float* b1 = (const float*)d_in[17];
    const float* W2 = (const float*)d_in[18]; const float* b2 = (const float*)d_in[19];
    const float* ln2g = (const float*)d_in[20]; const float* ln2b = (const float*)d_in[21];
    const float* p1w = (const float*)d_in[22]; const float* p1b = (const float*)d_in[23];
    const float* p2w = (const float*)d_in[24]; const float* p2b = (const float*)d_in[25];
    float* out = (float*)d_out;
    char* ws = (char*)d_ws;

    size_t off = 0;
    auto alloc = [&](size_t bytes) { size_t o = off; off += WS_ALIGN(bytes); return o; };
    float* xbuf = (float*)(ws + alloc(16384ull * 256 * 4));
    unsigned short* hbf = (unsigned short*)(ws + alloc(16384ull * 256 * 2));   // ln-out / attn-out
    unsigned short* qbf = (unsigned short*)(ws + alloc(16384ull * 256 * 2));
    unsigned short* kbf = (unsigned short*)(ws + alloc(16384ull * 256 * 2));
    unsigned short* vT  = (unsigned short*)(ws + alloc(16384ull * 256 * 2));
    unsigned short* midbf = (unsigned short*)(ws + alloc(16384ull * 1024 * 2)); // FFN mid
    float* ksum = (float*)(ws + alloc(16ull * 272 * 4));      // zeroed in phi_kmax
    float* ctxP = (float*)(ws + alloc(16ull * 16 * 64 * 272 * 4)); // z-partials (17.8 MB)
    float* pmaxb = (float*)(ws + alloc(1024ull * 4));
    float* alphab = (float*)(ws + alloc(16384ull * 4));
    unsigned short* Wqt = (unsigned short*)(ws + alloc(4ull * 65536 * 2));
    unsigned short* Wkt = (unsigned short*)(ws + alloc(4ull * 65536 * 2));
    unsigned short* Wvt = (unsigned short*)(ws + alloc(4ull * 65536 * 2));
    unsigned short* Wot = (unsigned short*)(ws + alloc(4ull * 65536 * 2));
    unsigned short* W1t = (unsigned short*)(ws + alloc(4ull * 262144 * 2));
    unsigned short* W2t = (unsigned short*)(ws + alloc(4ull * 262144 * 2));
    unsigned short* projbf = (unsigned short*)(ws + alloc(4ull * 20480 * 2)); // padded [L][320][64]
    unsigned short* p1t = (unsigned short*)(ws + alloc(65536ull * 2));
    unsigned short* ctxbf = (unsigned short*)(ws + alloc(16ull * 64 * 288 * 2)); // padded bf16 ctx
    unsigned short* abf = hbf;
    // total ~111 MB (< 256 MiB)

    // ---- weight casts (all layers up front) ----
    cast_transpose4_kernel<<<dim3(8, 8, 16), 256, 0, stream>>>(Wq, Wk, Wv, Wo, Wqt, Wkt, Wvt, Wot);
    cast_transpose_kernel<<<dim3(32, 8, 4), 256, 0, stream>>>(W1, W1t, 256, 1024);
    cast_transpose_kernel<<<dim3(8, 32, 4), 256, 0, stream>>>(W2, W2t, 1024, 256);
    cast_transpose_kernel<<<dim3(8, 8, 1), 256, 0, stream>>>(p1w, p1t, 256, 256);
    proj_cast_kernel<<<40, 256, 0, stream>>>(proj, projbf);

    // ---- x = LN(input + pos); hbf = LN1_0(x) — single fused kernel (wave-per-row) ----
    add_ln2_kernel<<<4096, 256, 0, stream>>>(input_embs, pos, ln_g, ln_b, ln1g, ln1b, xbuf, hbf);

    for (int i = 0; i < 4; i++) {
        const unsigned short* pj = projbf + (size_t)i * 20480;
        // QKV fused (2-phase gload_lds dbuf; coalesced vT epilogue)
        qkv_kernel<<<dim3(12, 128), 256, 0, stream>>>(hbf,
            Wqt + (size_t)i * 65536, Wkt + (size_t)i * 65536, Wvt + (size_t)i * 65536,
            bq + i * 256, bk + i * 256, bv + i * 256, qbf, kbf, vT);
        // k stabilizer block-max + zero ksum
        phi_kmax_kernel<<<dim3(64, 16), 256, 0, stream>>>(kbf, pj, pmaxb, ksum);
        // fused k-exp + ksum + ctx partials (m-halves, reg prefetch, no ctx atomics)
        ctx_fused_kernel<<<dim3(2, 16, 16), 256, 0, stream>>>(kbf, vT, pj, pmaxb, ksum, ctxP);
        // ctx partial reduce (16 z) + cast -> bf16 [bh][64][288]
        ctx_reduce_cast_kernel<<<144, 256, 0, stream>>>(ctxP, ctxbf);
        // fused q-side: dash + exp + denom + attn out (ctx async-staged, dbuf'd)
        phi_q_attn_kernel<<<dim3(64, 16), 256, 0, stream>>>(qbf, pj, ksum, ctxbf, abf);
        // Wo + residual + LN2 fused (32-row blocks, 2 blocks/CU)
        gemm_fullrow_kernel<0><<<512, 512, 0, stream>>>(abf, Wot + (size_t)i * 65536,
            bo + i * 256, xbuf, ln2g + i * 256, ln2b + i * 256, hbf,
            nullptr, nullptr, nullptr, nullptr, 256);
        // FFN (2-phase gload_lds dbuf)
        ffn1_kernel<<<dim3(16, 128), 256, 0, stream>>>(hbf, W1t + (size_t)i * 262144,
            b1 + i * 1024, midbf, 1024, 256);
        if (i < 3)
            gemm_fullrow_kernel<0><<<512, 512, 0, stream>>>(midbf, W2t + (size_t)i * 262144,
                b2 + i * 256, xbuf, ln1g + (i + 1) * 256, ln1b + (i + 1) * 256, hbf,
                nullptr, nullptr, nullptr, nullptr, 1024);
        else
            gemm_fullrow_kernel<1><<<512, 512, 0, stream>>>(midbf, W2t + (size_t)i * 262144,
                b2 + i * 256, xbuf, nullptr, nullptr, hbf,
                nullptr, nullptr, nullptr, nullptr, 1024);
    }

    // ---- attention pooling (score fused into GEMM) ----
    gemm_fullrow_kernel<2><<<512, 512, 0, stream>>>(hbf, p1t, p1b, nullptr, nullptr, nullptr,
        nullptr, p2w, p2b, mask, alphab, 256);
    hipMemsetAsync(d_out, 0, (size_t)out_size * sizeof(float), stream);
    pool_out_kernel<<<dim3(4, 32), 256, 0, stream>>>(xbuf, alphab, out);
}

// Round 16
// 743.707 us; speedup vs baseline: 1.0270x; 1.0084x over previous
//
#include <hip/hip_runtime.h>
#include <math.h>

// Performer encoder on MI355X: B=4, S=4096, D=256, H=4, DH=64, L=4, M=266.
// bf16 MFMA everywhere; fp32 residual stream / LN stats / softmax logic.
// Round 27: r26 base (749.97 µs) + prelude fusion: add_ln2 + all 4 weight-cast
// kernels merged into ONE 7272-block dispatch (they are mutually independent;
// first consumer qkv needs both LN output and cast weights). LN's memory-bound
// work now overlaps the casts; 5 launch gaps removed. Per-element code copied
// verbatim with blockIdx remapping only -> bit-exact.

#define WS_ALIGN(x) (((x) + 255) & ~(size_t)255)

#define DN 0.35355339059327373f      // 64^-0.25
#define DIAGC 0.0625f                 // 0.5 * 64^-0.5
#define RATIO 0.06131393394849658f    // 266^-0.5
#define FEPS 1e-4f

typedef __attribute__((__ext_vector_type__(8))) __bf16 bf16x8;
typedef __attribute__((__ext_vector_type__(4))) float f32x4;

__device__ __forceinline__ float wredsum(float v) {
    v += __shfl_xor(v, 32); v += __shfl_xor(v, 16); v += __shfl_xor(v, 8);
    v += __shfl_xor(v, 4);  v += __shfl_xor(v, 2);  v += __shfl_xor(v, 1);
    return v;
}
__device__ __forceinline__ float wredmax(float v) {
    v = fmaxf(v, __shfl_xor(v, 32)); v = fmaxf(v, __shfl_xor(v, 16));
    v = fmaxf(v, __shfl_xor(v, 8));  v = fmaxf(v, __shfl_xor(v, 4));
    v = fmaxf(v, __shfl_xor(v, 2));  v = fmaxf(v, __shfl_xor(v, 1));
    return v;
}

__device__ __forceinline__ unsigned short f2bf(float f) {
    unsigned u = __builtin_bit_cast(unsigned, f);
    return (unsigned short)((u + 0x7fffu + ((u >> 16) & 1u)) >> 16);
}
__device__ __forceinline__ float blo(unsigned x) { return __builtin_bit_cast(float, x << 16); }
__device__ __forceinline__ float bhi(unsigned x) { return __builtin_bit_cast(float, x & 0xffff0000u); }
__device__ __forceinline__ float sumsq8(uint4 u) {
    float s = 0.f;
    s += blo(u.x)*blo(u.x) + bhi(u.x)*bhi(u.x);
    s += blo(u.y)*blo(u.y) + bhi(u.y)*bhi(u.y);
    s += blo(u.z)*blo(u.z) + bhi(u.z)*bhi(u.z);
    s += blo(u.w)*blo(u.w) + bhi(u.w)*bhi(u.w);
    return s;
}
__device__ __forceinline__ unsigned pack2(float a, float b) {
    return (unsigned)f2bf(a) | ((unsigned)f2bf(b) << 16);
}

// async global -> LDS, 16B per lane: LDS dest is wave-uniform base + lane*16,
// global src is per-lane.
__device__ __forceinline__ void gload_lds16(const unsigned short* g, unsigned short* lds) {
    __builtin_amdgcn_global_load_lds(
        (const __attribute__((address_space(1))) unsigned int*)g,
        (__attribute__((address_space(3))) unsigned int*)lds, 16, 0, 0);
}

// ---------------- fused prelude: add+LN2 (4096 blk) | weight transposes (3136 blk)
// | proj cast (40 blk) — all mutually independent, one dispatch ----------------
__global__ __launch_bounds__(256) void prelude_kernel(
    const float* __restrict__ in, const float* __restrict__ pos,
    const float* __restrict__ g0, const float* __restrict__ b0,
    const float* __restrict__ g1, const float* __restrict__ b1,
    float* __restrict__ xout, unsigned short* __restrict__ hout,
    const float* __restrict__ Wq, const float* __restrict__ Wk,
    const float* __restrict__ Wv, const float* __restrict__ Wo,
    unsigned short* __restrict__ Wqt, unsigned short* __restrict__ Wkt,
    unsigned short* __restrict__ Wvt, unsigned short* __restrict__ Wot,
    const float* __restrict__ W1, unsigned short* __restrict__ W1t,
    const float* __restrict__ W2, unsigned short* __restrict__ W2t,
    const float* __restrict__ p1w, unsigned short* __restrict__ p1t,
    const float* __restrict__ proj, unsigned short* __restrict__ projbf)
{
    __shared__ float tile[32][33];
    int bid = blockIdx.x;
    int t = threadIdx.x;
    if (bid < 4096) {
        // ---- add + double LN (wave-per-row; identical to r26 add_ln2_kernel) ----
        int row = bid * 4 + (t >> 6);
        int l = t & 63;
        float4 vi = ((const float4*)(in + (size_t)row * 256))[l];
        float4 vp = ((const float4*)(pos + (size_t)(row & 4095) * 256))[l];
        float4 v = {vi.x + vp.x, vi.y + vp.y, vi.z + vp.z, vi.w + vp.w};
        float mean = wredsum(v.x + v.y + v.z + v.w) * (1.0f / 256.0f);
        float4 d = {v.x - mean, v.y - mean, v.z - mean, v.w - mean};
        float var = wredsum(d.x * d.x + d.y * d.y + d.z * d.z + d.w * d.w) * (1.0f / 256.0f);
        float rs = rsqrtf(var + 1e-12f);
        float4 g = ((const float4*)g0)[l], bb = ((const float4*)b0)[l];
        float4 y1 = {d.x * rs * g.x + bb.x, d.y * rs * g.y + bb.y,
                     d.z * rs * g.z + bb.z, d.w * rs * g.w + bb.w};
        ((float4*)(xout + (size_t)row * 256))[l] = y1;
        float mean1 = wredsum(y1.x + y1.y + y1.z + y1.w) * (1.0f / 256.0f);
        float4 d1 = {y1.x - mean1, y1.y - mean1, y1.z - mean1, y1.w - mean1};
        float var1 = wredsum(d1.x * d1.x + d1.y * d1.y + d1.z * d1.z + d1.w * d1.w) * (1.0f / 256.0f);
        float rs1 = rsqrtf(var1 + 1e-12f);
        float4 g1v = ((const float4*)g1)[l], b1v = ((const float4*)b1)[l];
        ushort4 o;
        o.x = f2bf(d1.x * rs1 * g1v.x + b1v.x);
        o.y = f2bf(d1.y * rs1 * g1v.y + b1v.y);
        o.z = f2bf(d1.z * rs1 * g1v.z + b1v.z);
        o.w = f2bf(d1.w * rs1 * g1v.w + b1v.w);
        ((ushort4*)(hout + (size_t)row * 256))[l] = o;
        return;
    }
    bid -= 4096;
    if (bid < 3136) {
        // ---- fp32 [R][C] -> bf16 [C][R] transposes (identical inner body) ----
        const float* src; unsigned short* dst; int R, C, bx, by;
        size_t zo;
        if (bid < 1024) {                 // Wq/Wk/Wv/Wo: 256x256 x 4 layers x 4 mats
            int z = bid >> 6, rem = bid & 63;
            by = rem >> 3; bx = rem & 7;
            int which = z >> 2, layer = z & 3;
            src = (which == 0) ? Wq : (which == 1) ? Wk : (which == 2) ? Wv : Wo;
            dst = (which == 0) ? Wqt : (which == 1) ? Wkt : (which == 2) ? Wvt : Wot;
            R = 256; C = 256; zo = (size_t)layer * 65536;
        } else if (bid < 2048) {          // W1: R=256, C=1024, 4 layers
            int i2 = bid - 1024;
            int z = i2 >> 8, rem = i2 & 255;
            by = rem >> 5; bx = rem & 31;
            src = W1; dst = W1t; R = 256; C = 1024; zo = (size_t)z * 262144;
        } else if (bid < 3072) {          // W2: R=1024, C=256, 4 layers
            int i3 = bid - 2048;
            int z = i3 >> 8, rem = i3 & 255;
            by = rem >> 3; bx = rem & 7;
            src = W2; dst = W2t; R = 1024; C = 256; zo = (size_t)z * 262144;
        } else {                          // p1w: 256x256
            int i4 = bid - 3072;
            by = i4 >> 3; bx = i4 & 7;
            src = p1w; dst = p1t; R = 256; C = 256; zo = 0;
        }
        int c0 = bx * 32, r0 = by * 32;
        int tc = t & 31, tr = t >> 5;
#pragma unroll
        for (int j = 0; j < 4; j++)
            tile[tr + j * 8][tc] = src[zo + (size_t)(r0 + tr + j * 8) * C + c0 + tc];
        __syncthreads();
#pragma unroll
        for (int j = 0; j < 4; j++) {
            int cc = tr + j * 8, rr = tc;
            dst[zo + (size_t)(c0 + cc) * R + r0 + rr] = f2bf(tile[rr][cc]);
        }
        return;
    }
    // ---- proj fp32 [L][266][64] -> bf16 [L][320][64] (zero-padded) ----
    int idx = (bid - 3136) * 256 + t;
    if (idx >= 10240) return;
    int li = idx / 2560; int rem = idx - li * 2560;
    int m = rem >> 3; int c = rem & 7;
    uint4 pk = {0, 0, 0, 0};
    if (m < 266) {
        const float* srcp = proj + ((size_t)li * 266 + m) * 64 + c * 8;
        float4 f0 = *(const float4*)(srcp);
        float4 f1 = *(const float4*)(srcp + 4);
        pk.x = pack2(f0.x, f0.y); pk.y = pack2(f0.z, f0.w);
        pk.z = pack2(f1.x, f1.y); pk.w = pack2(f1.z, f1.w);
    }
    *(uint4*)(projbf + (size_t)idx * 8) = pk;
}

// ---------------- ctx partial reduce (16 z) + cast: fp32 -> bf16 [1024][288] -----------
__global__ __launch_bounds__(256) void ctx_reduce_cast_kernel(
    const float* __restrict__ ctxP, unsigned short* __restrict__ ctxbf)
{
    int idx = blockIdx.x * 256 + threadIdx.x;   // 36864 chunks = 1024 rows * 36
    int row = idx / 36;
    int c = idx - row * 36;
    int m = c * 8;
    uint4 pk = {0, 0, 0, 0};
    if (m < 272) {
        float4 s0 = {0.f, 0.f, 0.f, 0.f}, s1 = {0.f, 0.f, 0.f, 0.f};
#pragma unroll
        for (int z = 0; z < 16; z++) {
            const float* p = ctxP + ((size_t)(z * 1024 + row) * 272 + m);
            float4 a = *(const float4*)p;
            float4 b = *(const float4*)(p + 4);
            s0.x += a.x; s0.y += a.y; s0.z += a.z; s0.w += a.w;
            s1.x += b.x; s1.y += b.y; s1.z += b.z; s1.w += b.w;
        }
        pk.x = pack2(s0.x, s0.y); pk.y = pack2(s0.z, s0.w);
        pk.z = pack2(s1.x, s1.y); pk.w = pack2(s1.z, s1.w);
    }
    *(uint4*)(ctxbf + (size_t)row * 288 + c * 8) = pk;
}

// ---------------- fused QKV GEMM (N=768 over q|k|v), K=256 — 2-phase gload_lds dbuf ------
// vT epilogue: acc -> LDS [64e][136] (union-aliased onto staging) -> coalesced 16B stores.
__global__ __launch_bounds__(256) void qkv_kernel(
    const unsigned short* __restrict__ A,
    const unsigned short* __restrict__ Wqt, const unsigned short* __restrict__ Wkt,
    const unsigned short* __restrict__ Wvt,
    const float* __restrict__ bq, const float* __restrict__ bk, const float* __restrict__ bv,
    unsigned short* __restrict__ qbf, unsigned short* __restrict__ kbf,
    unsigned short* __restrict__ vT)
{
    __shared__ union {
        struct { unsigned short As[2][4096]; unsigned short Bs[2][2048]; } st;
        unsigned short vt[64][136];   // 17408 B < 24576 B
    } u;
    const int K = 256;
    int t = threadIdx.x;
    int bm = blockIdx.y * 128, bn = blockIdx.x * 64;
    int grp = bn >> 8, lbn = bn & 255;
    const unsigned short* Bt = (grp == 0) ? Wqt : (grp == 1) ? Wkt : Wvt;
    const float* bias = (grp == 0) ? bq : (grp == 1) ? bk : bv;
    int w = t >> 6, l = t & 63, lm16 = l & 15, quad = l >> 4;
    int gc8 = ((l & 3) ^ ((l >> 3) & 3)) * 8;          // lane-constant source chunk swizzle
    int rc8 = (quad ^ ((lm16 >> 1) & 3)) * 8;          // read-side chunk swizzle
    const unsigned short* pa0 = A + (size_t)(bm + w * 16 + (l >> 2)) * K + gc8;
    const unsigned short* pa1 = pa0 + (size_t)64 * K;
    const unsigned short* pb0 = Bt + (size_t)(lbn + w * 16 + (l >> 2)) * K + gc8;
    auto stage = [&](int buf, int k0) {
        gload_lds16(pa0 + k0, &u.st.As[buf][w * 512]);
        gload_lds16(pa1 + k0, &u.st.As[buf][w * 512 + 2048]);
        gload_lds16(pb0 + k0, &u.st.Bs[buf][w * 512]);
    };
    stage(0, 0);
    f32x4 acc[2][4] = {};
    __syncthreads();
    for (int kt = 0; kt < 8; ++kt) {
        int cur = kt & 1;
        if (kt < 7) stage(cur ^ 1, (kt + 1) * 32);
        bf16x8 af[2], bfr[4];
        af[0] = *(const bf16x8*)&u.st.As[cur][(w * 32 + lm16) * 32 + rc8];
        af[1] = *(const bf16x8*)&u.st.As[cur][(w * 32 + 16 + lm16) * 32 + rc8];
#pragma unroll
        for (int j = 0; j < 4; j++) bfr[j] = *(const bf16x8*)&u.st.Bs[cur][(j * 16 + lm16) * 32 + rc8];
#pragma unroll
        for (int i = 0; i < 2; i++)
#pragma unroll
            for (int j = 0; j < 4; j++)
                acc[i][j] = __builtin_amdgcn_mfma_f32_16x16x32_bf16(af[i], bfr[j], acc[i][j], 0, 0, 0);
        __syncthreads();
    }
    if (grp == 2) {
        // v group: LDS transpose -> coalesced stores (staging LDS dead after loop barrier)
#pragma unroll
        for (int i = 0; i < 2; i++)
#pragma unroll
            for (int j = 0; j < 4; j++) {
                float bs = bias[lbn + j * 16 + lm16];
#pragma unroll
                for (int r = 0; r < 4; r++)
                    u.vt[j * 16 + lm16][w * 32 + i * 16 + quad * 4 + r] = f2bf(acc[i][j][r] + bs);
            }
        __syncthreads();
        int b = bm >> 12, s0 = bm & 4095;
        size_t base = (size_t)((b << 2) + (lbn >> 6)) * 64 * 4096 + s0;
        int e = t >> 2, c = t & 3;
#pragma unroll
        for (int k = 0; k < 4; k++) {
            uint4 vv = *(const uint4*)&u.vt[e][c * 32 + k * 8];
            *(uint4*)(vT + base + (size_t)e * 4096 + c * 32 + k * 8) = vv;
        }
        return;
    }
#pragma unroll
    for (int i = 0; i < 2; i++)
#pragma unroll
        for (int j = 0; j < 4; j++) {
            int lcol = lbn + j * 16 + lm16;
            float bs = bias[lcol];
            int h = lcol >> 6, e = lcol & 63;
#pragma unroll
            for (int r = 0; r < 4; r++) {
                int row = bm + w * 32 + i * 16 + quad * 4 + r;
                int b = row >> 12, s = row & 4095;
                float v = acc[i][j][r] + bs;
                if (grp == 0)
                    qbf[((size_t)((b << 2) + h) * 4096 + s) * 64 + e] = f2bf(v);
                else
                    kbf[((size_t)((b << 2) + h) * 4096 + s) * 64 + e] = f2bf(v);
            }
        }
}

// ---------------- FFN1 GEMM — 2-phase gload_lds dbuf: gelu(tanh) epilogue, bf16 out -------
__global__ __launch_bounds__(256) void ffn1_kernel(
    const unsigned short* __restrict__ A, const unsigned short* __restrict__ Bt,
    const float* __restrict__ bias, unsigned short* __restrict__ Cb, int N, int K)
{
    __shared__ unsigned short As[2][4096];
    __shared__ unsigned short Bs[2][2048];
    int t = threadIdx.x;
    int bm = blockIdx.y * 128, bn = blockIdx.x * 64;
    int w = t >> 6, l = t & 63, lm16 = l & 15, quad = l >> 4;
    int gc8 = ((l & 3) ^ ((l >> 3) & 3)) * 8;
    int rc8 = (quad ^ ((lm16 >> 1) & 3)) * 8;
    const unsigned short* pa0 = A + (size_t)(bm + w * 16 + (l >> 2)) * K + gc8;
    const unsigned short* pa1 = pa0 + (size_t)64 * K;
    const unsigned short* pb0 = Bt + (size_t)(bn + w * 16 + (l >> 2)) * K + gc8;
    auto stage = [&](int buf, int k0) {
        gload_lds16(pa0 + k0, &As[buf][w * 512]);
        gload_lds16(pa1 + k0, &As[buf][w * 512 + 2048]);
        gload_lds16(pb0 + k0, &Bs[buf][w * 512]);
    };
    stage(0, 0);
    f32x4 acc[2][4] = {};
    __syncthreads();
    int nt = K >> 5;
    for (int kt = 0; kt < nt; ++kt) {
        int cur = kt & 1;
        if (kt < nt - 1) stage(cur ^ 1, (kt + 1) * 32);
        bf16x8 af[2], bfr[4];
        af[0] = *(const bf16x8*)&As[cur][(w * 32 + lm16) * 32 + rc8];
        af[1] = *(const bf16x8*)&As[cur][(w * 32 + 16 + lm16) * 32 + rc8];
#pragma unroll
        for (int j = 0; j < 4; j++) bfr[j] = *(const bf16x8*)&Bs[cur][(j * 16 + lm16) * 32 + rc8];
#pragma unroll
        for (int i = 0; i < 2; i++)
#pragma unroll
            for (int j = 0; j < 4; j++)
                acc[i][j] = __builtin_amdgcn_mfma_f32_16x16x32_bf16(af[i], bfr[j], acc[i][j], 0, 0, 0);
        __syncthreads();
    }
#pragma unroll
    for (int i = 0; i < 2; i++)
#pragma unroll
        for (int j = 0; j < 4; j++) {
            int col = bn + j * 16 + lm16;
            float bsv = bias[col];
#pragma unroll
            for (int r = 0; r < 4; r++) {
                int row = bm + w * 32 + i * 16 + quad * 4 + r;
                float v = acc[i][j][r] + bsv;
                float inner = 0.7978845608028654f * (v + 0.044715f * v * v * v);
                float gl = 0.5f * v * (1.0f + tanhf(inner));
                Cb[(size_t)row * N + col] = f2bf(gl);
            }
        }
}

// ---------------- fused full-row GEMM: 32 rows x N=256 per block, 512 threads ----------
// 2-phase gload_lds dbuf; 36 KB LDS; grid 512 = 2 blocks/CU (mutual stall cover).
// `red` aliased onto As2 (dead after K-loop).
template <int EPI>
__global__ __launch_bounds__(512) void gemm_fullrow_kernel(
    const unsigned short* __restrict__ A, const unsigned short* __restrict__ Bt,
    const float* __restrict__ bias, float* __restrict__ xio,
    const float* __restrict__ lng, const float* __restrict__ lnb,
    unsigned short* __restrict__ outb,
    const float* __restrict__ p2w, const float* __restrict__ p2b,
    const float* __restrict__ mask, float* __restrict__ alphab, int K)
{
    __shared__ unsigned short As2[2][1024];   // [32 rows][32 hw]
    __shared__ unsigned short Bs2[2][8192];   // [256 rows][32 hw]
    float (*red)[32] = (float (*)[32])As2;    // aliased; used only after K-loop (1KB < 4KB)
    int t = threadIdx.x;
    int bm = blockIdx.x * 32;
    int w = t >> 6, l = t & 63, lm16 = l & 15, quad = l >> 4;
    int gc8 = ((l & 3) ^ ((l >> 3) & 3)) * 8;
    int rc8 = (quad ^ ((lm16 >> 1) & 3)) * 8;
    const unsigned short* pa = A + (size_t)(bm + (w & 1) * 16 + (l >> 2)) * K + gc8;
    const unsigned short* pb0 = Bt + (size_t)(w * 16 + (l >> 2)) * K + gc8;
    const unsigned short* pb1 = pb0 + (size_t)128 * K;
    auto stage = [&](int buf, int k0) {
        if (w < 2) gload_lds16(pa + k0, &As2[buf][w * 512]);
        gload_lds16(pb0 + k0, &Bs2[buf][w * 512]);
        gload_lds16(pb1 + k0, &Bs2[buf][w * 512 + 4096]);
    };
    stage(0, 0);
    f32x4 acc[2][2] = {};
    __syncthreads();
    int nt = K >> 5;
    for (int kt = 0; kt < nt; ++kt) {
        int cur = kt & 1;
        if (kt < nt - 1) stage(cur ^ 1, (kt + 1) * 32);
        bf16x8 af[2], bfv[2];
#pragma unroll
        for (int i = 0; i < 2; i++) af[i] = *(const bf16x8*)&As2[cur][(i * 16 + lm16) * 32 + rc8];
#pragma unroll
        for (int j = 0; j < 2; j++) bfv[j] = *(const bf16x8*)&Bs2[cur][(w * 32 + j * 16 + lm16) * 32 + rc8];
#pragma unroll
        for (int i = 0; i < 2; i++)
#pragma unroll
            for (int j = 0; j < 2; j++)
                acc[i][j] = __builtin_amdgcn_mfma_f32_16x16x32_bf16(af[i], bfv[j], acc[i][j], 0, 0, 0);
        __syncthreads();
    }
    int colbase = w * 32;
    if (EPI == 2) {
        float rs[2][4] = {};
#pragma unroll
        for (int j = 0; j < 2; j++) {
            int col = colbase + j * 16 + lm16;
            float bs = bias[col], pw = p2w[col];
#pragma unroll
            for (int i = 0; i < 2; i++)
#pragma unroll
                for (int r = 0; r < 4; r++)
                    rs[i][r] += tanhf(acc[i][j][r] + bs) * pw;
        }
#pragma unroll
        for (int m2 = 1; m2 <= 8; m2 <<= 1)
#pragma unroll
            for (int i = 0; i < 2; i++)
#pragma unroll
                for (int r = 0; r < 4; r++) rs[i][r] += __shfl_xor(rs[i][r], m2);
        __syncthreads();
        if (lm16 == 0) {
#pragma unroll
            for (int i = 0; i < 2; i++)
#pragma unroll
                for (int r = 0; r < 4; r++) red[w][i * 16 + quad * 4 + r] = rs[i][r];
        }
        __syncthreads();
        if (t < 32) {
            float sc = p2b[0];
#pragma unroll
            for (int ww = 0; ww < 8; ww++) sc += red[ww][t];
            int row = bm + t;
            alphab[row] = expf(sc) * mask[row];
        }
        return;
    }
    float rs[2][4] = {};
#pragma unroll
    for (int j = 0; j < 2; j++) {
        int col = colbase + j * 16 + lm16;
        float bs = bias[col];
#pragma unroll
        for (int i = 0; i < 2; i++)
#pragma unroll
            for (int r = 0; r < 4; r++) {
                int row = bm + i * 16 + quad * 4 + r;
                float v = acc[i][j][r] + bs + xio[(size_t)row * 256 + col];
                acc[i][j][r] = v;
                rs[i][r] += v;
            }
    }
    float mean[2][4], rstd[2][4];
    if (EPI == 0) {
#pragma unroll
        for (int m2 = 1; m2 <= 8; m2 <<= 1)
#pragma unroll
            for (int i = 0; i < 2; i++)
#pragma unroll
                for (int r = 0; r < 4; r++) rs[i][r] += __shfl_xor(rs[i][r], m2);
        __syncthreads();
        if (lm16 == 0) {
#pragma unroll
            for (int i = 0; i < 2; i++)
#pragma unroll
                for (int r = 0; r < 4; r++) red[w][i * 16 + quad * 4 + r] = rs[i][r];
        }
        __syncthreads();
        float vs[2][4] = {};
#pragma unroll
        for (int i = 0; i < 2; i++)
#pragma unroll
            for (int r = 0; r < 4; r++) {
                int rr = i * 16 + quad * 4 + r;
                float s = 0.f;
#pragma unroll
                for (int ww = 0; ww < 8; ww++) s += red[ww][rr];
                mean[i][r] = s * (1.0f / 256.0f);
            }
#pragma unroll
        for (int j = 0; j < 2; j++)
#pragma unroll
            for (int i = 0; i < 2; i++)
#pragma unroll
                for (int r = 0; r < 4; r++) {
                    float d = acc[i][j][r] - mean[i][r];
                    vs[i][r] += d * d;
                }
#pragma unroll
        for (int m2 = 1; m2 <= 8; m2 <<= 1)
#pragma unroll
            for (int i = 0; i < 2; i++)
#pragma unroll
                for (int r = 0; r < 4; r++) vs[i][r] += __shfl_xor(vs[i][r], m2);
        __syncthreads();
        if (lm16 == 0) {
#pragma unroll
            for (int i = 0; i < 2; i++)
#pragma unroll
                for (int r = 0; r < 4; r++) red[w][i * 16 + quad * 4 + r] = vs[i][r];
        }
        __syncthreads();
#pragma unroll
        for (int i = 0; i < 2; i++)
#pragma unroll
            for (int r = 0; r < 4; r++) {
                int rr = i * 16 + quad * 4 + r;
                float s = 0.f;
#pragma unroll
                for (int ww = 0; ww < 8; ww++) s += red[ww][rr];
                rstd[i][r] = rsqrtf(s * (1.0f / 256.0f) + 1e-12f);
            }
    }
#pragma unroll
    for (int j = 0; j < 2; j++) {
        int col = colbase + j * 16 + lm16;
        float g  = (EPI == 0) ? lng[col] : 0.f;
        float bb = (EPI == 0) ? lnb[col] : 0.f;
#pragma unroll
        for (int i = 0; i < 2; i++)
#pragma unroll
            for (int r = 0; r < 4; r++) {
                int row = bm + i * 16 + quad * 4 + r;
                float v = acc[i][j][r];
                xio[(size_t)row * 256 + col] = v;
                float y = (EPI == 0) ? ((v - mean[i][r]) * rstd[i][r] * g + bb) : v;
                outb[(size_t)row * 256 + col] = f2bf(y);
            }
    }
}

// ---------------- k-max kernel: dash block-max -> pmax; also zeros ksum ----------------
#define ZERO_FLOATS 4352   // 16*272 floats (ksum only; ctx partials are overwritten)
__global__ __launch_bounds__(256) void phi_kmax_kernel(
    const unsigned short* __restrict__ kbf, const unsigned short* __restrict__ projbf,
    float* __restrict__ pmax, float* __restrict__ zbase)
{
    __shared__ uint4 As[64][9];
    __shared__ uint4 Bs[272][8];   // chunk-swizzled proj (slot c holds chunk c ^ (row&7))
    __shared__ float diag_s[64];
    __shared__ float sred[4];
    int t = threadIdx.x;
    int s0 = blockIdx.x * 64;
    int bh = blockIdx.y;
    int w = t >> 6, l = t & 63, lm16 = l & 15, quad = l >> 4;
    {
        int bid = blockIdx.y * 64 + blockIdx.x;
        for (int i = bid * 256 + t; i < ZERO_FLOATS; i += 1024 * 256) zbase[i] = 0.f;
    }
    {
        int arow = t >> 2, akoff = (t & 3) * 16;
        const uint4* ga = (const uint4*)(kbf + ((size_t)bh * 4096 + s0 + arow) * 64 + akoff);
        uint4 u0 = ga[0], u1 = ga[1];
        As[arow][(akoff >> 3)] = u0; As[arow][(akoff >> 3) + 1] = u1;
        float ss = sumsq8(u0) + sumsq8(u1);
        ss += __shfl_xor(ss, 1); ss += __shfl_xor(ss, 2);
        if ((t & 3) == 0) diag_s[arow] = DIAGC * ss;
    }
    {
        unsigned short* Pl = (unsigned short*)Bs;
        int gcp8 = ((l & 7) ^ ((l >> 3) & 7)) * 8;
        const unsigned short* ps = projbf + (size_t)(l >> 3) * 64 + gcp8;
        for (int i = w; i < 34; i += 4)
            gload_lds16(ps + (size_t)i * 512, Pl + i * 512);
    }
    __syncthreads();
    f32x4 acc[17] = {};
#pragma unroll
    for (int ks = 0; ks < 2; ks++) {
        bf16x8 af = *(const bf16x8*)&As[w * 16 + lm16][ks * 4 + quad];
#pragma unroll
        for (int j = 0; j < 17; j++) {
            bf16x8 bfv = *(const bf16x8*)&Bs[j * 16 + lm16][(ks * 4 + quad) ^ (lm16 & 7)];
            acc[j] = __builtin_amdgcn_mfma_f32_16x16x32_bf16(af, bfv, acc[j], 0, 0, 0);
        }
    }
    int rloc = w * 16 + quad * 4;
    float kmax = -1e30f;
#pragma unroll
    for (int j = 0; j < 17; j++) {
        int m = j * 16 + lm16;
        bool valid = m < 266;
#pragma unroll
        for (int r = 0; r < 4; r++)
            if (valid) kmax = fmaxf(kmax, acc[j][r] * DN - diag_s[rloc + r]);
    }
    kmax = wredmax(kmax);
    if (l == 0) sred[w] = kmax;
    __syncthreads();
    if (t == 0)
        pmax[(size_t)bh * 64 + blockIdx.x] =
            fmaxf(fmaxf(sred[0], sred[1]), fmaxf(sred[2], sred[3]));
}

// ---------------- fused ctx: m-half blocks; dash->exp->LDS->ctx MFMA + ksum ------------
// grid (2 m-halves, 16 bh, 16 z) = 512 blocks (2/CU). Wave = s-tile for dash,
// e-quarter for PV. One-chunk-ahead register prefetch of K/V. ctx partials go to
// private ctxP[z][bh][64][272] slices via plain stores (NO atomics).
__global__ __launch_bounds__(256) void ctx_fused_kernel(
    const unsigned short* __restrict__ kbf, const unsigned short* __restrict__ vT,
    const unsigned short* __restrict__ projbf, const float* __restrict__ pmax,
    float* __restrict__ ksum, float* __restrict__ ctxP)
{
    __shared__ uint4 Ap[144][8];              // proj m-half, chunk-swizzled (18432 B)
    __shared__ uint4 Ks[64][9];               // 9216 B
    __shared__ uint4 Vs[64][9];               // 9216 B
    __shared__ unsigned short kp_s[144][72];  // [m][s] bf16 (20736 B)
    __shared__ float diag_s[64];
    __shared__ float sred2[4];
    int t = threadIdx.x;
    int m0 = blockIdx.x * 144;                // 0 or 144
    int bh = blockIdx.y;
    int sb = blockIdx.z * 256;                // 4 chunks of 64 s
    int w = t >> 6, l = t & 63, lm16 = l & 15, quad = l >> 4;
    // ---- stage proj half via gload_lds (lane-constant source chunk swizzle) ----
    {
        unsigned short* Pl = (unsigned short*)Ap;
        int gcp8 = ((l & 7) ^ ((l >> 3) & 7)) * 8;
        const unsigned short* ps = projbf + (size_t)(m0 + (l >> 3)) * 64 + gcp8;
        for (int i = w; i < 18; i += 4)
            gload_lds16(ps + (size_t)i * 512, Pl + i * 512);
    }
    // ---- global k stabilizer ----
    float pm = -1e30f;
    for (int i = t; i < 1024; i += 256) pm = fmaxf(pm, pmax[i]);
    pm = wredmax(pm);
    if (l == 0) sred2[w] = pm;
    // ---- preload chunk 0 K/V to regs ----
    int srow = t >> 2, skoff = (t & 3) * 16, sk4 = skoff >> 3;
    const uint4* gk = (const uint4*)(kbf + ((size_t)bh * 4096 + sb + srow) * 64 + skoff);
    uint4 k0 = gk[0], k1 = gk[1];
    const uint4* gv = (const uint4*)(vT + ((size_t)bh * 64 + srow) * 4096 + sb + skoff);
    uint4 v0 = gv[0], v1 = gv[1];
    __syncthreads();
    float st = fmaxf(fmaxf(sred2[0], sred2[1]), fmaxf(sred2[2], sred2[3]));
    f32x4 accc[9] = {};
    float ksacc[9][4] = {};
    for (int kc = 0; kc < 4; kc++) {
        if (kc) __syncthreads();                   // A: prior PV reads done
        Ks[srow][sk4] = k0; Ks[srow][sk4 + 1] = k1;
        Vs[srow][sk4] = v0; Vs[srow][sk4 + 1] = v1;
        float ss = sumsq8(k0) + sumsq8(k1);
        ss += __shfl_xor(ss, 1); ss += __shfl_xor(ss, 2);
        if ((t & 3) == 0) diag_s[srow] = DIAGC * ss;
        __syncthreads();                           // B: staging visible (drains gloads)
        if (kc < 3) {                              // prefetch next chunk; hides under dash+exp
            int sc = sb + (kc + 1) * 64;
            const uint4* gk2 = (const uint4*)(kbf + ((size_t)bh * 4096 + sc + srow) * 64 + skoff);
            k0 = gk2[0]; k1 = gk2[1];
            const uint4* gv2 = (const uint4*)(vT + ((size_t)bh * 64 + srow) * 4096 + sc + skoff);
            v0 = gv2[0]; v1 = gv2[1];
        }
        // ---- dash [144 m][64 s]: wave w owns s-tile w; diag is per-thread scalar ----
        float dgv = diag_s[w * 16 + lm16];
#pragma unroll
        for (int jm = 0; jm < 9; jm++) {
            f32x4 accd = {};
#pragma unroll
            for (int ks = 0; ks < 2; ks++) {
                bf16x8 af = *(const bf16x8*)&Ap[jm * 16 + lm16][(ks * 4 + quad) ^ (lm16 & 7)];
                bf16x8 bfv = *(const bf16x8*)&Ks[w * 16 + lm16][ks * 4 + quad];
                accd = __builtin_amdgcn_mfma_f32_16x16x32_bf16(af, bfv, accd, 0, 0, 0);
            }
#pragma unroll
            for (int r = 0; r < 4; r++) {
                int mg = m0 + jm * 16 + quad * 4 + r;
                float v = accd[r] * DN - dgv;
                float e = (mg < 266) ? RATIO * (__expf(v - st) + FEPS) : 0.f;
                kp_s[jm * 16 + quad * 4 + r][w * 16 + lm16] = f2bf(e);
                ksacc[jm][r] += e;
            }
        }
        __syncthreads();                           // C: kp visible
        // ---- PV: ctx[m][e] += kp[s][m]^T v[s][e]; wave w owns e-quarter w ----
#pragma unroll
        for (int ks = 0; ks < 2; ks++) {
            bf16x8 af = *(const bf16x8*)&Vs[w * 16 + lm16][ks * 4 + quad];
#pragma unroll
            for (int jt = 0; jt < 9; jt++) {
                bf16x8 bfv = *(const bf16x8*)&kp_s[jt * 16 + lm16][ks * 32 + quad * 8];
                accc[jt] = __builtin_amdgcn_mfma_f32_16x16x32_bf16(af, bfv, accc[jt], 0, 0, 0);
            }
        }
    }
    // ---- ksum: reduce over this wave's 16 s-lanes, one atomic per (m, wave) ----
#pragma unroll
    for (int jm = 0; jm < 9; jm++)
#pragma unroll
        for (int r = 0; r < 4; r++) {
            float vv = ksacc[jm][r];
            vv += __shfl_xor(vv, 1); vv += __shfl_xor(vv, 2);
            vv += __shfl_xor(vv, 4); vv += __shfl_xor(vv, 8);
            if (lm16 == 0) {
                int mg = m0 + jm * 16 + quad * 4 + r;
                if (mg < 272) atomicAdd(&ksum[bh * 272 + mg], vv);
            }
        }
    // ---- ctx partial store (private slice, no atomics) ----
    float* dst = ctxP + (size_t)(blockIdx.z * 16 + bh) * 64 * 272;
#pragma unroll
    for (int jt = 0; jt < 9; jt++) {
        int mg = m0 + jt * 16 + lm16;
        if (mg >= 272) continue;
#pragma unroll
        for (int r = 0; r < 4; r++) {
            int e = w * 16 + quad * 4 + r;
            dst[(size_t)e * 272 + mg] = accc[jt][r];
        }
    }
}

// ---------------- fused q-side: dash -> rowmax -> exp -> denom -> attn out ----------------
// ctx staged via global_load_lds (bf16, precast), double-buffered 16-e-row quarters,
// first two quarters prefetched under the exp phase. proj staged via global_load_lds.
__global__ __launch_bounds__(256) void phi_q_attn_kernel(
    const unsigned short* __restrict__ qbf, const unsigned short* __restrict__ projbf,
    const float* __restrict__ ksum, const unsigned short* __restrict__ ctxbf,
    unsigned short* __restrict__ abf)
{
    __shared__ uint4 uA[1152];       // stage1: q tile [64][9] (9216B); stage2: ctx dbuf 2x[16][288]us (18432B)
    __shared__ uint4 bufB[272][8];   // stage1: proj chunk-swizzled; stage2: qp ushort[64][272]
    __shared__ float diag_s[64];
    __shared__ float den_s[64];
    int t = threadIdx.x;
    int s0 = blockIdx.x * 64;
    int bh = blockIdx.y;
    int w = t >> 6, l = t & 63, lm16 = l & 15, quad = l >> 4;
    uint4 (*bufA)[9] = (uint4(*)[9])uA;
    {
        int arow = t >> 2, akoff = (t & 3) * 16;
        const uint4* ga = (const uint4*)(qbf + ((size_t)bh * 4096 + s0 + arow) * 64 + akoff);
        uint4 u0 = ga[0], u1 = ga[1];
        bufA[arow][(akoff >> 3)] = u0; bufA[arow][(akoff >> 3) + 1] = u1;
        float ss = sumsq8(u0) + sumsq8(u1);
        ss += __shfl_xor(ss, 1); ss += __shfl_xor(ss, 2);
        if ((t & 3) == 0) diag_s[arow] = DIAGC * ss;
    }
    {
        unsigned short* Pl = (unsigned short*)bufB;
        int gcp8 = ((l & 7) ^ ((l >> 3) & 7)) * 8;
        const unsigned short* ps = projbf + (size_t)(l >> 3) * 64 + gcp8;
        for (int i = w; i < 34; i += 4)
            gload_lds16(ps + (size_t)i * 512, Pl + i * 512);
    }
    // ksum -> registers (saves LDS; keeps 3 blocks/CU)
    float ksv[17];
#pragma unroll
    for (int j = 0; j < 17; j++) ksv[j] = ksum[bh * 272 + j * 16 + lm16];
    __syncthreads();
    // ---- stage 1: dash[64 s][272 m] via 34 MFMAs; swizzled proj reads are bank-uniform ----
    f32x4 acc[17] = {};
#pragma unroll
    for (int ks = 0; ks < 2; ks++) {
        bf16x8 af = *(const bf16x8*)&bufA[w * 16 + lm16][ks * 4 + quad];
#pragma unroll
        for (int j = 0; j < 17; j++) {
            bf16x8 bfv = *(const bf16x8*)&bufB[j * 16 + lm16][(ks * 4 + quad) ^ (lm16 & 7)];
            acc[j] = __builtin_amdgcn_mfma_f32_16x16x32_bf16(af, bfv, acc[j], 0, 0, 0);
        }
    }
    int rloc = w * 16 + quad * 4;
    float dg[4];
#pragma unroll
    for (int r = 0; r < 4; r++) dg[r] = diag_s[rloc + r];
    float vmax[4] = {-1e30f, -1e30f, -1e30f, -1e30f};
#pragma unroll
    for (int j = 0; j < 17; j++) {
        int m = j * 16 + lm16;
        bool valid = m < 266;
#pragma unroll
        for (int r = 0; r < 4; r++) {
            float v = acc[j][r] * DN - dg[r];
            acc[j][r] = v;
            if (valid) vmax[r] = fmaxf(vmax[r], v);
        }
    }
#pragma unroll
    for (int m2 = 1; m2 <= 8; m2 <<= 1)
#pragma unroll
        for (int r = 0; r < 4; r++) vmax[r] = fmaxf(vmax[r], __shfl_xor(vmax[r], m2));
    __syncthreads();   // all waves done reading bufA/bufB -> safe to overwrite with ctx/qp
    // ---- prefetch ctx quarters 0+1 (18KB) into dbuf; latency hides under exp phase ----
    unsigned short* ctxs = (unsigned short*)uA;
    const unsigned short* ctxg = ctxbf + (size_t)bh * 64 * 288;
    for (int i = w; i < 18; i += 4)
        gload_lds16(ctxg + i * 512 + l * 8, ctxs + i * 512);
    // ---- exp phase: qp -> LDS (bf16), denom via register ksum ----
    unsigned short* qp_s = (unsigned short*)bufB;    // [64][272]
    float den[4] = {0.f, 0.f, 0.f, 0.f};
#pragma unroll
    for (int j = 0; j < 17; j++) {
        int m = j * 16 + lm16;
        bool valid = m < 266;
#pragma unroll
        for (int r = 0; r < 4; r++) {
            float e = valid ? RATIO * (__expf(acc[j][r] - vmax[r]) + FEPS) : 0.f;
            qp_s[(rloc + r) * 272 + m] = f2bf(e);
            den[r] += e * ksv[j];
        }
    }
#pragma unroll
    for (int m2 = 1; m2 <= 8; m2 <<= 1)
#pragma unroll
        for (int r = 0; r < 4; r++) den[r] += __shfl_xor(den[r], m2);
    if (lm16 == 0) {
#pragma unroll
        for (int r = 0; r < 4; r++) den_s[rloc + r] = den[r];
    }
    // qp rows [w*16, w*16+16) written by this wave only -> A-frags readable without barrier
    bf16x8 paf[9];
#pragma unroll
    for (int kk = 0; kk < 9; kk++)
        paf[kk] = *(const bf16x8*)&qp_s[(w * 16 + lm16) * 272 + kk * 32 + quad * 8];
    __syncthreads();   // drains gload_lds vmcnt: quarters 0+1 resident
    // ---- stage 2: out[64 s][64 e] = qp @ ctx^T, 4 quarters x 9 MFMAs, dbuf'd ----
    int b = bh >> 2, h = bh & 3;
    f32x4 oacc[4] = {};
#pragma unroll
    for (int qd = 0; qd < 4; qd++) {
        const unsigned short* cs = ctxs + (qd & 1) * 4608;
#pragma unroll
        for (int kk = 0; kk < 9; kk++) {
            bf16x8 bfv = *(const bf16x8*)&cs[lm16 * 288 + kk * 32 + quad * 8];
            oacc[qd] = __builtin_amdgcn_mfma_f32_16x16x32_bf16(paf[kk], bfv, oacc[qd], 0, 0, 0);
        }
        if (qd < 3) {
            __syncthreads();   // waves done reading this buf; drains in-flight quarter loads
            if (qd < 2) {
                for (int i = w; i < 9; i += 4)
                    gload_lds16(ctxg + (qd + 2) * 4608 + i * 512 + l * 8,
                                ctxs + (qd & 1) * 4608 + i * 512);
            }
        }
    }
#pragma unroll
    for (int qd = 0; qd < 4; qd++) {
        int e = qd * 16 + lm16;
#pragma unroll
        for (int r = 0; r < 4; r++) {
            int sl = rloc + r;
            abf[((size_t)(b * 4096 + s0 + sl)) * 256 + h * 64 + e] = f2bf(oacc[qd][r] / den_s[sl]);
        }
    }
}

// ---------------- pooling tail: denom + weighted sum in ONE kernel ----------------
// Each (b,chunk) block recomputes denom with the IDENTICAL wredsum tree/order
// as the old pool_denom kernel -> bit-exact.
__global__ __launch_bounds__(256) void pool_out_kernel(
    const float* __restrict__ x, const float* __restrict__ alpha,
    float* __restrict__ out)
{
    __shared__ float sred[4];
    int b = blockIdx.x, chunk = blockIdx.y, t = threadIdx.x;
    float p = 0.f;
    for (int s = t; s < 4096; s += 256) p += alpha[b * 4096 + s];
    p = wredsum(p);
    if ((t & 63) == 0) sred[t >> 6] = p;
    __syncthreads();
    float inv = 1.0f / (sred[0] + sred[1] + sred[2] + sred[3] + 1e-8f);
    float acc = 0.f;
    int s0 = chunk * 128;
    for (int s = s0; s < s0 + 128; s++)
        acc += x[((size_t)(b << 12) + s) * 256 + t] * alpha[(b << 12) + s];
    atomicAdd(&out[b * 256 + t], acc * inv);
}

extern "C" void kernel_launch(void* const* d_in, const int* in_sizes, int n_in,
                              void* d_out, int out_size, void* d_ws, size_t ws_size,
                              hipStream_t stream)
{
    const float* input_embs = (const float*)d_in[0];
    const float* mask  = (const float*)d_in[1];
    const float* pos   = (const float*)d_in[2];
    const float* ln_g  = (const float*)d_in[3];
    const float* ln_b  = (const float*)d_in[4];
    const float* proj  = (const float*)d_in[5];
    const float* Wq = (const float*)d_in[6];  const float* bq = (const float*)d_in[7];
    const float* Wk = (const float*)d_in[8];  const float* bk = (const float*)d_in[9];
    const float* Wv = (const float*)d_in[10]; const float* bv = (const float*)d_in[11];
    const float* Wo = (const float*)d_in[12]; const float* bo = (const float*)d_in[13];
    const float* ln1g = (const float*)d_in[14]; const float* ln1b = (const float*)d_in[15];
    const float* W1 = (const float*)d_in[16]; const float* b1 = (const float*)d_in[17];
    const float* W2 = (const float*)d_in[18]; const float* b2 = (const float*)d_in[19];
    const float* ln2g = (const float*)d_in[20]; const float* ln2b = (const float*)d_in[21];
    const float* p1w = (const float*)d_in[22]; const float* p1b = (const float*)d_in[23];
    const float* p2w = (const float*)d_in[24]; const float* p2b = (const float*)d_in[25];
    float* out = (float*)d_out;
    char* ws = (char*)d_ws;

    size_t off = 0;
    auto alloc = [&](size_t bytes) { size_t o = off; off += WS_ALIGN(bytes); return o; };
    float* xbuf = (float*)(ws + alloc(16384ull * 256 * 4));
    unsigned short* hbf = (unsigned short*)(ws + alloc(16384ull * 256 * 2));   // ln-out / attn-out
    unsigned short* qbf = (unsigned short*)(ws + alloc(16384ull * 256 * 2));
    unsigned short* kbf = (unsigned short*)(ws + alloc(16384ull * 256 * 2));
    unsigned short* vT  = (unsigned short*)(ws + alloc(16384ull * 256 * 2));
    unsigned short* midbf = (unsigned short*)(ws + alloc(16384ull * 1024 * 2)); // FFN mid
    float* ksum = (float*)(ws + alloc(16ull * 272 * 4));      // zeroed in phi_kmax
    float* ctxP = (float*)(ws + alloc(16ull * 16 * 64 * 272 * 4)); // z-partials (17.8 MB)
    float* pmaxb = (float*)(ws + alloc(1024ull * 4));
    float* alphab = (float*)(ws + alloc(16384ull * 4));
    unsigned short* Wqt = (unsigned short*)(ws + alloc(4ull * 65536 * 2));
    unsigned short* Wkt = (unsigned short*)(ws + alloc(4ull * 65536 * 2));
    unsigned short* Wvt = (unsigned short*)(ws + alloc(4ull * 65536 * 2));
    unsigned short* Wot = (unsigned short*)(ws + alloc(4ull * 65536 * 2));
    unsigned short* W1t = (unsigned short*)(ws + alloc(4ull * 262144 * 2));
    unsigned short* W2t = (unsigned short*)(ws + alloc(4ull * 262144 * 2));
    unsigned short* projbf = (unsigned short*)(ws + alloc(4ull * 20480 * 2)); // padded [L][320][64]
    unsigned short* p1t = (unsigned short*)(ws + alloc(65536ull * 2));
    unsigned short* ctxbf = (unsigned short*)(ws + alloc(16ull * 64 * 288 * 2)); // padded bf16 ctx
    unsigned short* abf = hbf;
    // total ~111 MB (< 256 MiB)

    // ---- fused prelude: LN(input+pos) + all weight casts in ONE dispatch ----
    prelude_kernel<<<7272, 256, 0, stream>>>(
        input_embs, pos, ln_g, ln_b, ln1g, ln1b, xbuf, hbf,
        Wq, Wk, Wv, Wo, Wqt, Wkt, Wvt, Wot,
        W1, W1t, W2, W2t, p1w, p1t, proj, projbf);

    for (int i = 0; i < 4; i++) {
        const unsigned short* pj = projbf + (size_t)i * 20480;
        // QKV fused (2-phase gload_lds dbuf; coalesced vT epilogue)
        qkv_kernel<<<dim3(12, 128), 256, 0, stream>>>(hbf,
            Wqt + (size_t)i * 65536, Wkt + (size_t)i * 65536, Wvt + (size_t)i * 65536,
            bq + i * 256, bk + i * 256, bv + i * 256, qbf, kbf, vT);
        // k stabilizer block-max + zero ksum
        phi_kmax_kernel<<<dim3(64, 16), 256, 0, stream>>>(kbf, pj, pmaxb, ksum);
        // fused k-exp + ksum + ctx partials (m-halves, reg prefetch, no ctx atomics)
        ctx_fused_kernel<<<dim3(2, 16, 16), 256, 0, stream>>>(kbf, vT, pj, pmaxb, ksum, ctxP);
        // ctx partial reduce (16 z) + cast -> bf16 [bh][64][288]
        ctx_reduce_cast_kernel<<<144, 256, 0, stream>>>(ctxP, ctxbf);
        // fused q-side: dash + exp + denom + attn out (ctx async-staged, dbuf'd)
        phi_q_attn_kernel<<<dim3(64, 16), 256, 0, stream>>>(qbf, pj, ksum, ctxbf, abf);
        // Wo + residual + LN2 fused (32-row blocks, 2 blocks/CU)
        gemm_fullrow_kernel<0><<<512, 512, 0, stream>>>(abf, Wot + (size_t)i * 65536,
            bo + i * 256, xbuf, ln2g + i * 256, ln2b + i * 256, hbf,
            nullptr, nullptr, nullptr, nullptr, 256);
        // FFN (2-phase gload_lds dbuf)
        ffn1_kernel<<<dim3(16, 128), 256, 0, stream>>>(hbf, W1t + (size_t)i * 262144,
            b1 + i * 1024, midbf, 1024, 256);
        if (i < 3)
            gemm_fullrow_kernel<0><<<512, 512, 0, stream>>>(midbf, W2t + (size_t)i * 262144,
                b2 + i * 256, xbuf, ln1g + (i + 1) * 256, ln1b + (i + 1) * 256, hbf,
                nullptr, nullptr, nullptr, nullptr, 1024);
        else
            gemm_fullrow_kernel<1><<<512, 512, 0, stream>>>(midbf, W2t + (size_t)i * 262144,
                b2 + i * 256, xbuf, nullptr, nullptr, hbf,
                nullptr, nullptr, nullptr, nullptr, 1024);
    }

    // ---- attention pooling (score fused into GEMM) ----
    gemm_fullrow_kernel<2><<<512, 512, 0, stream>>>(hbf, p1t, p1b, nullptr, nullptr, nullptr,
        nullptr, p2w, p2b, mask, alphab, 256);
    hipMemsetAsync(d_out, 0, (size_t)out_size * sizeof(float), stream);
    pool_out_kernel<<<dim3(4, 32), 256, 0, stream>>>(xbuf, alphab, out);
}

// Round 17
// 738.508 us; speedup vs baseline: 1.0342x; 1.0070x over previous
//
#include <hip/hip_runtime.h>
#include <math.h>

// Performer encoder on MI355X: B=4, S=4096, D=256, H=4, DH=64, L=4, M=266.
// bf16 MFMA everywhere; fp32 residual stream / LN stats / softmax logic.
// Round 28: r27 base (743.7 µs) + two zero-risk micro fixes:
//   * hipMemsetAsync(d_out) moved to the FRONT (no deps until pool_out) —
//     overlaps prelude instead of serializing the tail.
//   * ctx_reduce_cast at float4 granularity: 288 blocks / 73728 threads (was
//     144/36864) — 2x latency-hiding TLP for its 36 MB latency-bound reduce.
//     Per-element z-ascending summation order unchanged -> bit-exact.

#define WS_ALIGN(x) (((x) + 255) & ~(size_t)255)

#define DN 0.35355339059327373f      // 64^-0.25
#define DIAGC 0.0625f                 // 0.5 * 64^-0.5
#define RATIO 0.06131393394849658f    // 266^-0.5
#define FEPS 1e-4f

typedef __attribute__((__ext_vector_type__(8))) __bf16 bf16x8;
typedef __attribute__((__ext_vector_type__(4))) float f32x4;

__device__ __forceinline__ float wredsum(float v) {
    v += __shfl_xor(v, 32); v += __shfl_xor(v, 16); v += __shfl_xor(v, 8);
    v += __shfl_xor(v, 4);  v += __shfl_xor(v, 2);  v += __shfl_xor(v, 1);
    return v;
}
__device__ __forceinline__ float wredmax(float v) {
    v = fmaxf(v, __shfl_xor(v, 32)); v = fmaxf(v, __shfl_xor(v, 16));
    v = fmaxf(v, __shfl_xor(v, 8));  v = fmaxf(v, __shfl_xor(v, 4));
    v = fmaxf(v, __shfl_xor(v, 2));  v = fmaxf(v, __shfl_xor(v, 1));
    return v;
}

__device__ __forceinline__ unsigned short f2bf(float f) {
    unsigned u = __builtin_bit_cast(unsigned, f);
    return (unsigned short)((u + 0x7fffu + ((u >> 16) & 1u)) >> 16);
}
__device__ __forceinline__ float blo(unsigned x) { return __builtin_bit_cast(float, x << 16); }
__device__ __forceinline__ float bhi(unsigned x) { return __builtin_bit_cast(float, x & 0xffff0000u); }
__device__ __forceinline__ float sumsq8(uint4 u) {
    float s = 0.f;
    s += blo(u.x)*blo(u.x) + bhi(u.x)*bhi(u.x);
    s += blo(u.y)*blo(u.y) + bhi(u.y)*bhi(u.y);
    s += blo(u.z)*blo(u.z) + bhi(u.z)*bhi(u.z);
    s += blo(u.w)*blo(u.w) + bhi(u.w)*bhi(u.w);
    return s;
}
__device__ __forceinline__ unsigned pack2(float a, float b) {
    return (unsigned)f2bf(a) | ((unsigned)f2bf(b) << 16);
}

// async global -> LDS, 16B per lane: LDS dest is wave-uniform base + lane*16,
// global src is per-lane.
__device__ __forceinline__ void gload_lds16(const unsigned short* g, unsigned short* lds) {
    __builtin_amdgcn_global_load_lds(
        (const __attribute__((address_space(1))) unsigned int*)g,
        (__attribute__((address_space(3))) unsigned int*)lds, 16, 0, 0);
}

// ---------------- fused prelude: add+LN2 (4096 blk) | weight transposes (3136 blk)
// | proj cast (40 blk) — all mutually independent, one dispatch ----------------
__global__ __launch_bounds__(256) void prelude_kernel(
    const float* __restrict__ in, const float* __restrict__ pos,
    const float* __restrict__ g0, const float* __restrict__ b0,
    const float* __restrict__ g1, const float* __restrict__ b1,
    float* __restrict__ xout, unsigned short* __restrict__ hout,
    const float* __restrict__ Wq, const float* __restrict__ Wk,
    const float* __restrict__ Wv, const float* __restrict__ Wo,
    unsigned short* __restrict__ Wqt, unsigned short* __restrict__ Wkt,
    unsigned short* __restrict__ Wvt, unsigned short* __restrict__ Wot,
    const float* __restrict__ W1, unsigned short* __restrict__ W1t,
    const float* __restrict__ W2, unsigned short* __restrict__ W2t,
    const float* __restrict__ p1w, unsigned short* __restrict__ p1t,
    const float* __restrict__ proj, unsigned short* __restrict__ projbf)
{
    __shared__ float tile[32][33];
    int bid = blockIdx.x;
    int t = threadIdx.x;
    if (bid < 4096) {
        // ---- add + double LN (wave-per-row; identical to r26 add_ln2_kernel) ----
        int row = bid * 4 + (t >> 6);
        int l = t & 63;
        float4 vi = ((const float4*)(in + (size_t)row * 256))[l];
        float4 vp = ((const float4*)(pos + (size_t)(row & 4095) * 256))[l];
        float4 v = {vi.x + vp.x, vi.y + vp.y, vi.z + vp.z, vi.w + vp.w};
        float mean = wredsum(v.x + v.y + v.z + v.w) * (1.0f / 256.0f);
        float4 d = {v.x - mean, v.y - mean, v.z - mean, v.w - mean};
        float var = wredsum(d.x * d.x + d.y * d.y + d.z * d.z + d.w * d.w) * (1.0f / 256.0f);
        float rs = rsqrtf(var + 1e-12f);
        float4 g = ((const float4*)g0)[l], bb = ((const float4*)b0)[l];
        float4 y1 = {d.x * rs * g.x + bb.x, d.y * rs * g.y + bb.y,
                     d.z * rs * g.z + bb.z, d.w * rs * g.w + bb.w};
        ((float4*)(xout + (size_t)row * 256))[l] = y1;
        float mean1 = wredsum(y1.x + y1.y + y1.z + y1.w) * (1.0f / 256.0f);
        float4 d1 = {y1.x - mean1, y1.y - mean1, y1.z - mean1, y1.w - mean1};
        float var1 = wredsum(d1.x * d1.x + d1.y * d1.y + d1.z * d1.z + d1.w * d1.w) * (1.0f / 256.0f);
        float rs1 = rsqrtf(var1 + 1e-12f);
        float4 g1v = ((const float4*)g1)[l], b1v = ((const float4*)b1)[l];
        ushort4 o;
        o.x = f2bf(d1.x * rs1 * g1v.x + b1v.x);
        o.y = f2bf(d1.y * rs1 * g1v.y + b1v.y);
        o.z = f2bf(d1.z * rs1 * g1v.z + b1v.z);
        o.w = f2bf(d1.w * rs1 * g1v.w + b1v.w);
        ((ushort4*)(hout + (size_t)row * 256))[l] = o;
        return;
    }
    bid -= 4096;
    if (bid < 3136) {
        // ---- fp32 [R][C] -> bf16 [C][R] transposes (identical inner body) ----
        const float* src; unsigned short* dst; int R, C, bx, by;
        size_t zo;
        if (bid < 1024) {                 // Wq/Wk/Wv/Wo: 256x256 x 4 layers x 4 mats
            int z = bid >> 6, rem = bid & 63;
            by = rem >> 3; bx = rem & 7;
            int which = z >> 2, layer = z & 3;
            src = (which == 0) ? Wq : (which == 1) ? Wk : (which == 2) ? Wv : Wo;
            dst = (which == 0) ? Wqt : (which == 1) ? Wkt : (which == 2) ? Wvt : Wot;
            R = 256; C = 256; zo = (size_t)layer * 65536;
        } else if (bid < 2048) {          // W1: R=256, C=1024, 4 layers
            int i2 = bid - 1024;
            int z = i2 >> 8, rem = i2 & 255;
            by = rem >> 5; bx = rem & 31;
            src = W1; dst = W1t; R = 256; C = 1024; zo = (size_t)z * 262144;
        } else if (bid < 3072) {          // W2: R=1024, C=256, 4 layers
            int i3 = bid - 2048;
            int z = i3 >> 8, rem = i3 & 255;
            by = rem >> 3; bx = rem & 7;
            src = W2; dst = W2t; R = 1024; C = 256; zo = (size_t)z * 262144;
        } else {                          // p1w: 256x256
            int i4 = bid - 3072;
            by = i4 >> 3; bx = i4 & 7;
            src = p1w; dst = p1t; R = 256; C = 256; zo = 0;
        }
        int c0 = bx * 32, r0 = by * 32;
        int tc = t & 31, tr = t >> 5;
#pragma unroll
        for (int j = 0; j < 4; j++)
            tile[tr + j * 8][tc] = src[zo + (size_t)(r0 + tr + j * 8) * C + c0 + tc];
        __syncthreads();
#pragma unroll
        for (int j = 0; j < 4; j++) {
            int cc = tr + j * 8, rr = tc;
            dst[zo + (size_t)(c0 + cc) * R + r0 + rr] = f2bf(tile[rr][cc]);
        }
        return;
    }
    // ---- proj fp32 [L][266][64] -> bf16 [L][320][64] (zero-padded) ----
    int idx = (bid - 3136) * 256 + t;
    if (idx >= 10240) return;
    int li = idx / 2560; int rem = idx - li * 2560;
    int m = rem >> 3; int c = rem & 7;
    uint4 pk = {0, 0, 0, 0};
    if (m < 266) {
        const float* srcp = proj + ((size_t)li * 266 + m) * 64 + c * 8;
        float4 f0 = *(const float4*)(srcp);
        float4 f1 = *(const float4*)(srcp + 4);
        pk.x = pack2(f0.x, f0.y); pk.y = pack2(f0.z, f0.w);
        pk.z = pack2(f1.x, f1.y); pk.w = pack2(f1.z, f1.w);
    }
    *(uint4*)(projbf + (size_t)idx * 8) = pk;
}

// ---------------- ctx partial reduce (16 z) + cast: fp32 -> bf16 [1024][288] -----------
// float4 granularity: 73728 chunks = 1024 rows * 72; z-ascending sum per element.
__global__ __launch_bounds__(256) void ctx_reduce_cast_kernel(
    const float* __restrict__ ctxP, unsigned short* __restrict__ ctxbf)
{
    int idx = blockIdx.x * 256 + threadIdx.x;   // 288 blocks * 256 = 73728
    int row = idx / 72;
    int c = idx - row * 72;
    int m = c * 4;
    uint2 pk = {0, 0};
    if (m < 272) {
        float4 s = {0.f, 0.f, 0.f, 0.f};
#pragma unroll
        for (int z = 0; z < 16; z++) {
            float4 a = *(const float4*)(ctxP + ((size_t)(z * 1024 + row) * 272 + m));
            s.x += a.x; s.y += a.y; s.z += a.z; s.w += a.w;
        }
        pk.x = pack2(s.x, s.y); pk.y = pack2(s.z, s.w);
    }
    *(uint2*)(ctxbf + (size_t)row * 288 + m) = pk;
}

// ---------------- fused QKV GEMM (N=768 over q|k|v), K=256 — 2-phase gload_lds dbuf ------
// vT epilogue: acc -> LDS [64e][136] (union-aliased onto staging) -> coalesced 16B stores.
__global__ __launch_bounds__(256) void qkv_kernel(
    const unsigned short* __restrict__ A,
    const unsigned short* __restrict__ Wqt, const unsigned short* __restrict__ Wkt,
    const unsigned short* __restrict__ Wvt,
    const float* __restrict__ bq, const float* __restrict__ bk, const float* __restrict__ bv,
    unsigned short* __restrict__ qbf, unsigned short* __restrict__ kbf,
    unsigned short* __restrict__ vT)
{
    __shared__ union {
        struct { unsigned short As[2][4096]; unsigned short Bs[2][2048]; } st;
        unsigned short vt[64][136];   // 17408 B < 24576 B
    } u;
    const int K = 256;
    int t = threadIdx.x;
    int bm = blockIdx.y * 128, bn = blockIdx.x * 64;
    int grp = bn >> 8, lbn = bn & 255;
    const unsigned short* Bt = (grp == 0) ? Wqt : (grp == 1) ? Wkt : Wvt;
    const float* bias = (grp == 0) ? bq : (grp == 1) ? bk : bv;
    int w = t >> 6, l = t & 63, lm16 = l & 15, quad = l >> 4;
    int gc8 = ((l & 3) ^ ((l >> 3) & 3)) * 8;          // lane-constant source chunk swizzle
    int rc8 = (quad ^ ((lm16 >> 1) & 3)) * 8;          // read-side chunk swizzle
    const unsigned short* pa0 = A + (size_t)(bm + w * 16 + (l >> 2)) * K + gc8;
    const unsigned short* pa1 = pa0 + (size_t)64 * K;
    const unsigned short* pb0 = Bt + (size_t)(lbn + w * 16 + (l >> 2)) * K + gc8;
    auto stage = [&](int buf, int k0) {
        gload_lds16(pa0 + k0, &u.st.As[buf][w * 512]);
        gload_lds16(pa1 + k0, &u.st.As[buf][w * 512 + 2048]);
        gload_lds16(pb0 + k0, &u.st.Bs[buf][w * 512]);
    };
    stage(0, 0);
    f32x4 acc[2][4] = {};
    __syncthreads();
    for (int kt = 0; kt < 8; ++kt) {
        int cur = kt & 1;
        if (kt < 7) stage(cur ^ 1, (kt + 1) * 32);
        bf16x8 af[2], bfr[4];
        af[0] = *(const bf16x8*)&u.st.As[cur][(w * 32 + lm16) * 32 + rc8];
        af[1] = *(const bf16x8*)&u.st.As[cur][(w * 32 + 16 + lm16) * 32 + rc8];
#pragma unroll
        for (int j = 0; j < 4; j++) bfr[j] = *(const bf16x8*)&u.st.Bs[cur][(j * 16 + lm16) * 32 + rc8];
#pragma unroll
        for (int i = 0; i < 2; i++)
#pragma unroll
            for (int j = 0; j < 4; j++)
                acc[i][j] = __builtin_amdgcn_mfma_f32_16x16x32_bf16(af[i], bfr[j], acc[i][j], 0, 0, 0);
        __syncthreads();
    }
    if (grp == 2) {
        // v group: LDS transpose -> coalesced stores (staging LDS dead after loop barrier)
#pragma unroll
        for (int i = 0; i < 2; i++)
#pragma unroll
            for (int j = 0; j < 4; j++) {
                float bs = bias[lbn + j * 16 + lm16];
#pragma unroll
                for (int r = 0; r < 4; r++)
                    u.vt[j * 16 + lm16][w * 32 + i * 16 + quad * 4 + r] = f2bf(acc[i][j][r] + bs);
            }
        __syncthreads();
        int b = bm >> 12, s0 = bm & 4095;
        size_t base = (size_t)((b << 2) + (lbn >> 6)) * 64 * 4096 + s0;
        int e = t >> 2, c = t & 3;
#pragma unroll
        for (int k = 0; k < 4; k++) {
            uint4 vv = *(const uint4*)&u.vt[e][c * 32 + k * 8];
            *(uint4*)(vT + base + (size_t)e * 4096 + c * 32 + k * 8) = vv;
        }
        return;
    }
#pragma unroll
    for (int i = 0; i < 2; i++)
#pragma unroll
        for (int j = 0; j < 4; j++) {
            int lcol = lbn + j * 16 + lm16;
            float bs = bias[lcol];
            int h = lcol >> 6, e = lcol & 63;
#pragma unroll
            for (int r = 0; r < 4; r++) {
                int row = bm + w * 32 + i * 16 + quad * 4 + r;
                int b = row >> 12, s = row & 4095;
                float v = acc[i][j][r] + bs;
                if (grp == 0)
                    qbf[((size_t)((b << 2) + h) * 4096 + s) * 64 + e] = f2bf(v);
                else
                    kbf[((size_t)((b << 2) + h) * 4096 + s) * 64 + e] = f2bf(v);
            }
        }
}

// ---------------- FFN1 GEMM — 2-phase gload_lds dbuf: gelu(tanh) epilogue, bf16 out -------
__global__ __launch_bounds__(256) void ffn1_kernel(
    const unsigned short* __restrict__ A, const unsigned short* __restrict__ Bt,
    const float* __restrict__ bias, unsigned short* __restrict__ Cb, int N, int K)
{
    __shared__ unsigned short As[2][4096];
    __shared__ unsigned short Bs[2][2048];
    int t = threadIdx.x;
    int bm = blockIdx.y * 128, bn = blockIdx.x * 64;
    int w = t >> 6, l = t & 63, lm16 = l & 15, quad = l >> 4;
    int gc8 = ((l & 3) ^ ((l >> 3) & 3)) * 8;
    int rc8 = (quad ^ ((lm16 >> 1) & 3)) * 8;
    const unsigned short* pa0 = A + (size_t)(bm + w * 16 + (l >> 2)) * K + gc8;
    const unsigned short* pa1 = pa0 + (size_t)64 * K;
    const unsigned short* pb0 = Bt + (size_t)(bn + w * 16 + (l >> 2)) * K + gc8;
    auto stage = [&](int buf, int k0) {
        gload_lds16(pa0 + k0, &As[buf][w * 512]);
        gload_lds16(pa1 + k0, &As[buf][w * 512 + 2048]);
        gload_lds16(pb0 + k0, &Bs[buf][w * 512]);
    };
    stage(0, 0);
    f32x4 acc[2][4] = {};
    __syncthreads();
    int nt = K >> 5;
    for (int kt = 0; kt < nt; ++kt) {
        int cur = kt & 1;
        if (kt < nt - 1) stage(cur ^ 1, (kt + 1) * 32);
        bf16x8 af[2], bfr[4];
        af[0] = *(const bf16x8*)&As[cur][(w * 32 + lm16) * 32 + rc8];
        af[1] = *(const bf16x8*)&As[cur][(w * 32 + 16 + lm16) * 32 + rc8];
#pragma unroll
        for (int j = 0; j < 4; j++) bfr[j] = *(const bf16x8*)&Bs[cur][(j * 16 + lm16) * 32 + rc8];
#pragma unroll
        for (int i = 0; i < 2; i++)
#pragma unroll
            for (int j = 0; j < 4; j++)
                acc[i][j] = __builtin_amdgcn_mfma_f32_16x16x32_bf16(af[i], bfr[j], acc[i][j], 0, 0, 0);
        __syncthreads();
    }
#pragma unroll
    for (int i = 0; i < 2; i++)
#pragma unroll
        for (int j = 0; j < 4; j++) {
            int col = bn + j * 16 + lm16;
            float bsv = bias[col];
#pragma unroll
            for (int r = 0; r < 4; r++) {
                int row = bm + w * 32 + i * 16 + quad * 4 + r;
                float v = acc[i][j][r] + bsv;
                float inner = 0.7978845608028654f * (v + 0.044715f * v * v * v);
                float gl = 0.5f * v * (1.0f + tanhf(inner));
                Cb[(size_t)row * N + col] = f2bf(gl);
            }
        }
}

// ---------------- fused full-row GEMM: 32 rows x N=256 per block, 512 threads ----------
// 2-phase gload_lds dbuf; 36 KB LDS; grid 512 = 2 blocks/CU (mutual stall cover).
// `red` aliased onto As2 (dead after K-loop).
template <int EPI>
__global__ __launch_bounds__(512) void gemm_fullrow_kernel(
    const unsigned short* __restrict__ A, const unsigned short* __restrict__ Bt,
    const float* __restrict__ bias, float* __restrict__ xio,
    const float* __restrict__ lng, const float* __restrict__ lnb,
    unsigned short* __restrict__ outb,
    const float* __restrict__ p2w, const float* __restrict__ p2b,
    const float* __restrict__ mask, float* __restrict__ alphab, int K)
{
    __shared__ unsigned short As2[2][1024];   // [32 rows][32 hw]
    __shared__ unsigned short Bs2[2][8192];   // [256 rows][32 hw]
    float (*red)[32] = (float (*)[32])As2;    // aliased; used only after K-loop (1KB < 4KB)
    int t = threadIdx.x;
    int bm = blockIdx.x * 32;
    int w = t >> 6, l = t & 63, lm16 = l & 15, quad = l >> 4;
    int gc8 = ((l & 3) ^ ((l >> 3) & 3)) * 8;
    int rc8 = (quad ^ ((lm16 >> 1) & 3)) * 8;
    const unsigned short* pa = A + (size_t)(bm + (w & 1) * 16 + (l >> 2)) * K + gc8;
    const unsigned short* pb0 = Bt + (size_t)(w * 16 + (l >> 2)) * K + gc8;
    const unsigned short* pb1 = pb0 + (size_t)128 * K;
    auto stage = [&](int buf, int k0) {
        if (w < 2) gload_lds16(pa + k0, &As2[buf][w * 512]);
        gload_lds16(pb0 + k0, &Bs2[buf][w * 512]);
        gload_lds16(pb1 + k0, &Bs2[buf][w * 512 + 4096]);
    };
    stage(0, 0);
    f32x4 acc[2][2] = {};
    __syncthreads();
    int nt = K >> 5;
    for (int kt = 0; kt < nt; ++kt) {
        int cur = kt & 1;
        if (kt < nt - 1) stage(cur ^ 1, (kt + 1) * 32);
        bf16x8 af[2], bfv[2];
#pragma unroll
        for (int i = 0; i < 2; i++) af[i] = *(const bf16x8*)&As2[cur][(i * 16 + lm16) * 32 + rc8];
#pragma unroll
        for (int j = 0; j < 2; j++) bfv[j] = *(const bf16x8*)&Bs2[cur][(w * 32 + j * 16 + lm16) * 32 + rc8];
#pragma unroll
        for (int i = 0; i < 2; i++)
#pragma unroll
            for (int j = 0; j < 2; j++)
                acc[i][j] = __builtin_amdgcn_mfma_f32_16x16x32_bf16(af[i], bfv[j], acc[i][j], 0, 0, 0);
        __syncthreads();
    }
    int colbase = w * 32;
    if (EPI == 2) {
        float rs[2][4] = {};
#pragma unroll
        for (int j = 0; j < 2; j++) {
            int col = colbase + j * 16 + lm16;
            float bs = bias[col], pw = p2w[col];
#pragma unroll
            for (int i = 0; i < 2; i++)
#pragma unroll
                for (int r = 0; r < 4; r++)
                    rs[i][r] += tanhf(acc[i][j][r] + bs) * pw;
        }
#pragma unroll
        for (int m2 = 1; m2 <= 8; m2 <<= 1)
#pragma unroll
            for (int i = 0; i < 2; i++)
#pragma unroll
                for (int r = 0; r < 4; r++) rs[i][r] += __shfl_xor(rs[i][r], m2);
        __syncthreads();
        if (lm16 == 0) {
#pragma unroll
            for (int i = 0; i < 2; i++)
#pragma unroll
                for (int r = 0; r < 4; r++) red[w][i * 16 + quad * 4 + r] = rs[i][r];
        }
        __syncthreads();
        if (t < 32) {
            float sc = p2b[0];
#pragma unroll
            for (int ww = 0; ww < 8; ww++) sc += red[ww][t];
            int row = bm + t;
            alphab[row] = expf(sc) * mask[row];
        }
        return;
    }
    float rs[2][4] = {};
#pragma unroll
    for (int j = 0; j < 2; j++) {
        int col = colbase + j * 16 + lm16;
        float bs = bias[col];
#pragma unroll
        for (int i = 0; i < 2; i++)
#pragma unroll
            for (int r = 0; r < 4; r++) {
                int row = bm + i * 16 + quad * 4 + r;
                float v = acc[i][j][r] + bs + xio[(size_t)row * 256 + col];
                acc[i][j][r] = v;
                rs[i][r] += v;
            }
    }
    float mean[2][4], rstd[2][4];
    if (EPI == 0) {
#pragma unroll
        for (int m2 = 1; m2 <= 8; m2 <<= 1)
#pragma unroll
            for (int i = 0; i < 2; i++)
#pragma unroll
                for (int r = 0; r < 4; r++) rs[i][r] += __shfl_xor(rs[i][r], m2);
        __syncthreads();
        if (lm16 == 0) {
#pragma unroll
            for (int i = 0; i < 2; i++)
#pragma unroll
                for (int r = 0; r < 4; r++) red[w][i * 16 + quad * 4 + r] = rs[i][r];
        }
        __syncthreads();
        float vs[2][4] = {};
#pragma unroll
        for (int i = 0; i < 2; i++)
#pragma unroll
            for (int r = 0; r < 4; r++) {
                int rr = i * 16 + quad * 4 + r;
                float s = 0.f;
#pragma unroll
                for (int ww = 0; ww < 8; ww++) s += red[ww][rr];
                mean[i][r] = s * (1.0f / 256.0f);
            }
#pragma unroll
        for (int j = 0; j < 2; j++)
#pragma unroll
            for (int i = 0; i < 2; i++)
#pragma unroll
                for (int r = 0; r < 4; r++) {
                    float d = acc[i][j][r] - mean[i][r];
                    vs[i][r] += d * d;
                }
#pragma unroll
        for (int m2 = 1; m2 <= 8; m2 <<= 1)
#pragma unroll
            for (int i = 0; i < 2; i++)
#pragma unroll
                for (int r = 0; r < 4; r++) vs[i][r] += __shfl_xor(vs[i][r], m2);
        __syncthreads();
        if (lm16 == 0) {
#pragma unroll
            for (int i = 0; i < 2; i++)
#pragma unroll
                for (int r = 0; r < 4; r++) red[w][i * 16 + quad * 4 + r] = vs[i][r];
        }
        __syncthreads();
#pragma unroll
        for (int i = 0; i < 2; i++)
#pragma unroll
            for (int r = 0; r < 4; r++) {
                int rr = i * 16 + quad * 4 + r;
                float s = 0.f;
#pragma unroll
                for (int ww = 0; ww < 8; ww++) s += red[ww][rr];
                rstd[i][r] = rsqrtf(s * (1.0f / 256.0f) + 1e-12f);
            }
    }
#pragma unroll
    for (int j = 0; j < 2; j++) {
        int col = colbase + j * 16 + lm16;
        float g  = (EPI == 0) ? lng[col] : 0.f;
        float bb = (EPI == 0) ? lnb[col] : 0.f;
#pragma unroll
        for (int i = 0; i < 2; i++)
#pragma unroll
            for (int r = 0; r < 4; r++) {
                int row = bm + i * 16 + quad * 4 + r;
                float v = acc[i][j][r];
                xio[(size_t)row * 256 + col] = v;
                float y = (EPI == 0) ? ((v - mean[i][r]) * rstd[i][r] * g + bb) : v;
                outb[(size_t)row * 256 + col] = f2bf(y);
            }
    }
}

// ---------------- k-max kernel: dash block-max -> pmax; also zeros ksum ----------------
#define ZERO_FLOATS 4352   // 16*272 floats (ksum only; ctx partials are overwritten)
__global__ __launch_bounds__(256) void phi_kmax_kernel(
    const unsigned short* __restrict__ kbf, const unsigned short* __restrict__ projbf,
    float* __restrict__ pmax, float* __restrict__ zbase)
{
    __shared__ uint4 As[64][9];
    __shared__ uint4 Bs[272][8];   // chunk-swizzled proj (slot c holds chunk c ^ (row&7))
    __shared__ float diag_s[64];
    __shared__ float sred[4];
    int t = threadIdx.x;
    int s0 = blockIdx.x * 64;
    int bh = blockIdx.y;
    int w = t >> 6, l = t & 63, lm16 = l & 15, quad = l >> 4;
    {
        int bid = blockIdx.y * 64 + blockIdx.x;
        for (int i = bid * 256 + t; i < ZERO_FLOATS; i += 1024 * 256) zbase[i] = 0.f;
    }
    {
        int arow = t >> 2, akoff = (t & 3) * 16;
        const uint4* ga = (const uint4*)(kbf + ((size_t)bh * 4096 + s0 + arow) * 64 + akoff);
        uint4 u0 = ga[0], u1 = ga[1];
        As[arow][(akoff >> 3)] = u0; As[arow][(akoff >> 3) + 1] = u1;
        float ss = sumsq8(u0) + sumsq8(u1);
        ss += __shfl_xor(ss, 1); ss += __shfl_xor(ss, 2);
        if ((t & 3) == 0) diag_s[arow] = DIAGC * ss;
    }
    {
        unsigned short* Pl = (unsigned short*)Bs;
        int gcp8 = ((l & 7) ^ ((l >> 3) & 7)) * 8;
        const unsigned short* ps = projbf + (size_t)(l >> 3) * 64 + gcp8;
        for (int i = w; i < 34; i += 4)
            gload_lds16(ps + (size_t)i * 512, Pl + i * 512);
    }
    __syncthreads();
    f32x4 acc[17] = {};
#pragma unroll
    for (int ks = 0; ks < 2; ks++) {
        bf16x8 af = *(const bf16x8*)&As[w * 16 + lm16][ks * 4 + quad];
#pragma unroll
        for (int j = 0; j < 17; j++) {
            bf16x8 bfv = *(const bf16x8*)&Bs[j * 16 + lm16][(ks * 4 + quad) ^ (lm16 & 7)];
            acc[j] = __builtin_amdgcn_mfma_f32_16x16x32_bf16(af, bfv, acc[j], 0, 0, 0);
        }
    }
    int rloc = w * 16 + quad * 4;
    float kmax = -1e30f;
#pragma unroll
    for (int j = 0; j < 17; j++) {
        int m = j * 16 + lm16;
        bool valid = m < 266;
#pragma unroll
        for (int r = 0; r < 4; r++)
            if (valid) kmax = fmaxf(kmax, acc[j][r] * DN - diag_s[rloc + r]);
    }
    kmax = wredmax(kmax);
    if (l == 0) sred[w] = kmax;
    __syncthreads();
    if (t == 0)
        pmax[(size_t)bh * 64 + blockIdx.x] =
            fmaxf(fmaxf(sred[0], sred[1]), fmaxf(sred[2], sred[3]));
}

// ---------------- fused ctx: m-half blocks; dash->exp->LDS->ctx MFMA + ksum ------------
// grid (2 m-halves, 16 bh, 16 z) = 512 blocks (2/CU). Wave = s-tile for dash,
// e-quarter for PV. One-chunk-ahead register prefetch of K/V. ctx partials go to
// private ctxP[z][bh][64][272] slices via plain stores (NO atomics).
__global__ __launch_bounds__(256) void ctx_fused_kernel(
    const unsigned short* __restrict__ kbf, const unsigned short* __restrict__ vT,
    const unsigned short* __restrict__ projbf, const float* __restrict__ pmax,
    float* __restrict__ ksum, float* __restrict__ ctxP)
{
    __shared__ uint4 Ap[144][8];              // proj m-half, chunk-swizzled (18432 B)
    __shared__ uint4 Ks[64][9];               // 9216 B
    __shared__ uint4 Vs[64][9];               // 9216 B
    __shared__ unsigned short kp_s[144][72];  // [m][s] bf16 (20736 B)
    __shared__ float diag_s[64];
    __shared__ float sred2[4];
    int t = threadIdx.x;
    int m0 = blockIdx.x * 144;                // 0 or 144
    int bh = blockIdx.y;
    int sb = blockIdx.z * 256;                // 4 chunks of 64 s
    int w = t >> 6, l = t & 63, lm16 = l & 15, quad = l >> 4;
    // ---- stage proj half via gload_lds (lane-constant source chunk swizzle) ----
    {
        unsigned short* Pl = (unsigned short*)Ap;
        int gcp8 = ((l & 7) ^ ((l >> 3) & 7)) * 8;
        const unsigned short* ps = projbf + (size_t)(m0 + (l >> 3)) * 64 + gcp8;
        for (int i = w; i < 18; i += 4)
            gload_lds16(ps + (size_t)i * 512, Pl + i * 512);
    }
    // ---- global k stabilizer ----
    float pm = -1e30f;
    for (int i = t; i < 1024; i += 256) pm = fmaxf(pm, pmax[i]);
    pm = wredmax(pm);
    if (l == 0) sred2[w] = pm;
    // ---- preload chunk 0 K/V to regs ----
    int srow = t >> 2, skoff = (t & 3) * 16, sk4 = skoff >> 3;
    const uint4* gk = (const uint4*)(kbf + ((size_t)bh * 4096 + sb + srow) * 64 + skoff);
    uint4 k0 = gk[0], k1 = gk[1];
    const uint4* gv = (const uint4*)(vT + ((size_t)bh * 64 + srow) * 4096 + sb + skoff);
    uint4 v0 = gv[0], v1 = gv[1];
    __syncthreads();
    float st = fmaxf(fmaxf(sred2[0], sred2[1]), fmaxf(sred2[2], sred2[3]));
    f32x4 accc[9] = {};
    float ksacc[9][4] = {};
    for (int kc = 0; kc < 4; kc++) {
        if (kc) __syncthreads();                   // A: prior PV reads done
        Ks[srow][sk4] = k0; Ks[srow][sk4 + 1] = k1;
        Vs[srow][sk4] = v0; Vs[srow][sk4 + 1] = v1;
        float ss = sumsq8(k0) + sumsq8(k1);
        ss += __shfl_xor(ss, 1); ss += __shfl_xor(ss, 2);
        if ((t & 3) == 0) diag_s[srow] = DIAGC * ss;
        __syncthreads();                           // B: staging visible (drains gloads)
        if (kc < 3) {                              // prefetch next chunk; hides under dash+exp
            int sc = sb + (kc + 1) * 64;
            const uint4* gk2 = (const uint4*)(kbf + ((size_t)bh * 4096 + sc + srow) * 64 + skoff);
            k0 = gk2[0]; k1 = gk2[1];
            const uint4* gv2 = (const uint4*)(vT + ((size_t)bh * 64 + srow) * 4096 + sc + skoff);
            v0 = gv2[0]; v1 = gv2[1];
        }
        // ---- dash [144 m][64 s]: wave w owns s-tile w; diag is per-thread scalar ----
        float dgv = diag_s[w * 16 + lm16];
#pragma unroll
        for (int jm = 0; jm < 9; jm++) {
            f32x4 accd = {};
#pragma unroll
            for (int ks = 0; ks < 2; ks++) {
                bf16x8 af = *(const bf16x8*)&Ap[jm * 16 + lm16][(ks * 4 + quad) ^ (lm16 & 7)];
                bf16x8 bfv = *(const bf16x8*)&Ks[w * 16 + lm16][ks * 4 + quad];
                accd = __builtin_amdgcn_mfma_f32_16x16x32_bf16(af, bfv, accd, 0, 0, 0);
            }
#pragma unroll
            for (int r = 0; r < 4; r++) {
                int mg = m0 + jm * 16 + quad * 4 + r;
                float v = accd[r] * DN - dgv;
                float e = (mg < 266) ? RATIO * (__expf(v - st) + FEPS) : 0.f;
                kp_s[jm * 16 + quad * 4 + r][w * 16 + lm16] = f2bf(e);
                ksacc[jm][r] += e;
            }
        }
        __syncthreads();                           // C: kp visible
        // ---- PV: ctx[m][e] += kp[s][m]^T v[s][e]; wave w owns e-quarter w ----
#pragma unroll
        for (int ks = 0; ks < 2; ks++) {
            bf16x8 af = *(const bf16x8*)&Vs[w * 16 + lm16][ks * 4 + quad];
#pragma unroll
            for (int jt = 0; jt < 9; jt++) {
                bf16x8 bfv = *(const bf16x8*)&kp_s[jt * 16 + lm16][ks * 32 + quad * 8];
                accc[jt] = __builtin_amdgcn_mfma_f32_16x16x32_bf16(af, bfv, accc[jt], 0, 0, 0);
            }
        }
    }
    // ---- ksum: reduce over this wave's 16 s-lanes, one atomic per (m, wave) ----
#pragma unroll
    for (int jm = 0; jm < 9; jm++)
#pragma unroll
        for (int r = 0; r < 4; r++) {
            float vv = ksacc[jm][r];
            vv += __shfl_xor(vv, 1); vv += __shfl_xor(vv, 2);
            vv += __shfl_xor(vv, 4); vv += __shfl_xor(vv, 8);
            if (lm16 == 0) {
                int mg = m0 + jm * 16 + quad * 4 + r;
                if (mg < 272) atomicAdd(&ksum[bh * 272 + mg], vv);
            }
        }
    // ---- ctx partial store (private slice, no atomics) ----
    float* dst = ctxP + (size_t)(blockIdx.z * 16 + bh) * 64 * 272;
#pragma unroll
    for (int jt = 0; jt < 9; jt++) {
        int mg = m0 + jt * 16 + lm16;
        if (mg >= 272) continue;
#pragma unroll
        for (int r = 0; r < 4; r++) {
            int e = w * 16 + quad * 4 + r;
            dst[(size_t)e * 272 + mg] = accc[jt][r];
        }
    }
}

// ---------------- fused q-side: dash -> rowmax -> exp -> denom -> attn out ----------------
// ctx staged via global_load_lds (bf16, precast), double-buffered 16-e-row quarters,
// first two quarters prefetched under the exp phase. proj staged via global_load_lds.
__global__ __launch_bounds__(256) void phi_q_attn_kernel(
    const unsigned short* __restrict__ qbf, const unsigned short* __restrict__ projbf,
    const float* __restrict__ ksum, const unsigned short* __restrict__ ctxbf,
    unsigned short* __restrict__ abf)
{
    __shared__ uint4 uA[1152];       // stage1: q tile [64][9] (9216B); stage2: ctx dbuf 2x[16][288]us (18432B)
    __shared__ uint4 bufB[272][8];   // stage1: proj chunk-swizzled; stage2: qp ushort[64][272]
    __shared__ float diag_s[64];
    __shared__ float den_s[64];
    int t = threadIdx.x;
    int s0 = blockIdx.x * 64;
    int bh = blockIdx.y;
    int w = t >> 6, l = t & 63, lm16 = l & 15, quad = l >> 4;
    uint4 (*bufA)[9] = (uint4(*)[9])uA;
    {
        int arow = t >> 2, akoff = (t & 3) * 16;
        const uint4* ga = (const uint4*)(qbf + ((size_t)bh * 4096 + s0 + arow) * 64 + akoff);
        uint4 u0 = ga[0], u1 = ga[1];
        bufA[arow][(akoff >> 3)] = u0; bufA[arow][(akoff >> 3) + 1] = u1;
        float ss = sumsq8(u0) + sumsq8(u1);
        ss += __shfl_xor(ss, 1); ss += __shfl_xor(ss, 2);
        if ((t & 3) == 0) diag_s[arow] = DIAGC * ss;
    }
    {
        unsigned short* Pl = (unsigned short*)bufB;
        int gcp8 = ((l & 7) ^ ((l >> 3) & 7)) * 8;
        const unsigned short* ps = projbf + (size_t)(l >> 3) * 64 + gcp8;
        for (int i = w; i < 34; i += 4)
            gload_lds16(ps + (size_t)i * 512, Pl + i * 512);
    }
    // ksum -> registers (saves LDS; keeps 3 blocks/CU)
    float ksv[17];
#pragma unroll
    for (int j = 0; j < 17; j++) ksv[j] = ksum[bh * 272 + j * 16 + lm16];
    __syncthreads();
    // ---- stage 1: dash[64 s][272 m] via 34 MFMAs; swizzled proj reads are bank-uniform ----
    f32x4 acc[17] = {};
#pragma unroll
    for (int ks = 0; ks < 2; ks++) {
        bf16x8 af = *(const bf16x8*)&bufA[w * 16 + lm16][ks * 4 + quad];
#pragma unroll
        for (int j = 0; j < 17; j++) {
            bf16x8 bfv = *(const bf16x8*)&bufB[j * 16 + lm16][(ks * 4 + quad) ^ (lm16 & 7)];
            acc[j] = __builtin_amdgcn_mfma_f32_16x16x32_bf16(af, bfv, acc[j], 0, 0, 0);
        }
    }
    int rloc = w * 16 + quad * 4;
    float dg[4];
#pragma unroll
    for (int r = 0; r < 4; r++) dg[r] = diag_s[rloc + r];
    float vmax[4] = {-1e30f, -1e30f, -1e30f, -1e30f};
#pragma unroll
    for (int j = 0; j < 17; j++) {
        int m = j * 16 + lm16;
        bool valid = m < 266;
#pragma unroll
        for (int r = 0; r < 4; r++) {
            float v = acc[j][r] * DN - dg[r];
            acc[j][r] = v;
            if (valid) vmax[r] = fmaxf(vmax[r], v);
        }
    }
#pragma unroll
    for (int m2 = 1; m2 <= 8; m2 <<= 1)
#pragma unroll
        for (int r = 0; r < 4; r++) vmax[r] = fmaxf(vmax[r], __shfl_xor(vmax[r], m2));
    __syncthreads();   // all waves done reading bufA/bufB -> safe to overwrite with ctx/qp
    // ---- prefetch ctx quarters 0+1 (18KB) into dbuf; latency hides under exp phase ----
    unsigned short* ctxs = (unsigned short*)uA;
    const unsigned short* ctxg = ctxbf + (size_t)bh * 64 * 288;
    for (int i = w; i < 18; i += 4)
        gload_lds16(ctxg + i * 512 + l * 8, ctxs + i * 512);
    // ---- exp phase: qp -> LDS (bf16), denom via register ksum ----
    unsigned short* qp_s = (unsigned short*)bufB;    // [64][272]
    float den[4] = {0.f, 0.f, 0.f, 0.f};
#pragma unroll
    for (int j = 0; j < 17; j++) {
        int m = j * 16 + lm16;
        bool valid = m < 266;
#pragma unroll
        for (int r = 0; r < 4; r++) {
            float e = valid ? RATIO * (__expf(acc[j][r] - vmax[r]) + FEPS) : 0.f;
            qp_s[(rloc + r) * 272 + m] = f2bf(e);
            den[r] += e * ksv[j];
        }
    }
#pragma unroll
    for (int m2 = 1; m2 <= 8; m2 <<= 1)
#pragma unroll
        for (int r = 0; r < 4; r++) den[r] += __shfl_xor(den[r], m2);
    if (lm16 == 0) {
#pragma unroll
        for (int r = 0; r < 4; r++) den_s[rloc + r] = den[r];
    }
    // qp rows [w*16, w*16+16) written by this wave only -> A-frags readable without barrier
    bf16x8 paf[9];
#pragma unroll
    for (int kk = 0; kk < 9; kk++)
        paf[kk] = *(const bf16x8*)&qp_s[(w * 16 + lm16) * 272 + kk * 32 + quad * 8];
    __syncthreads();   // drains gload_lds vmcnt: quarters 0+1 resident
    // ---- stage 2: out[64 s][64 e] = qp @ ctx^T, 4 quarters x 9 MFMAs, dbuf'd ----
    int b = bh >> 2, h = bh & 3;
    f32x4 oacc[4] = {};
#pragma unroll
    for (int qd = 0; qd < 4; qd++) {
        const unsigned short* cs = ctxs + (qd & 1) * 4608;
#pragma unroll
        for (int kk = 0; kk < 9; kk++) {
            bf16x8 bfv = *(const bf16x8*)&cs[lm16 * 288 + kk * 32 + quad * 8];
            oacc[qd] = __builtin_amdgcn_mfma_f32_16x16x32_bf16(paf[kk], bfv, oacc[qd], 0, 0, 0);
        }
        if (qd < 3) {
            __syncthreads();   // waves done reading this buf; drains in-flight quarter loads
            if (qd < 2) {
                for (int i = w; i < 9; i += 4)
                    gload_lds16(ctxg + (qd + 2) * 4608 + i * 512 + l * 8,
                                ctxs + (qd & 1) * 4608 + i * 512);
            }
        }
    }
#pragma unroll
    for (int qd = 0; qd < 4; qd++) {
        int e = qd * 16 + lm16;
#pragma unroll
        for (int r = 0; r < 4; r++) {
            int sl = rloc + r;
            abf[((size_t)(b * 4096 + s0 + sl)) * 256 + h * 64 + e] = f2bf(oacc[qd][r] / den_s[sl]);
        }
    }
}

// ---------------- pooling tail: denom + weighted sum in ONE kernel ----------------
// Each (b,chunk) block recomputes denom with the IDENTICAL wredsum tree/order
// as the old pool_denom kernel -> bit-exact.
__global__ __launch_bounds__(256) void pool_out_kernel(
    const float* __restrict__ x, const float* __restrict__ alpha,
    float* __restrict__ out)
{
    __shared__ float sred[4];
    int b = blockIdx.x, chunk = blockIdx.y, t = threadIdx.x;
    float p = 0.f;
    for (int s = t; s < 4096; s += 256) p += alpha[b * 4096 + s];
    p = wredsum(p);
    if ((t & 63) == 0) sred[t >> 6] = p;
    __syncthreads();
    float inv = 1.0f / (sred[0] + sred[1] + sred[2] + sred[3] + 1e-8f);
    float acc = 0.f;
    int s0 = chunk * 128;
    for (int s = s0; s < s0 + 128; s++)
        acc += x[((size_t)(b << 12) + s) * 256 + t] * alpha[(b << 12) + s];
    atomicAdd(&out[b * 256 + t], acc * inv);
}

extern "C" void kernel_launch(void* const* d_in, const int* in_sizes, int n_in,
                              void* d_out, int out_size, void* d_ws, size_t ws_size,
                              hipStream_t stream)
{
    const float* input_embs = (const float*)d_in[0];
    const float* mask  = (const float*)d_in[1];
    const float* pos   = (const float*)d_in[2];
    const float* ln_g  = (const float*)d_in[3];
    const float* ln_b  = (const float*)d_in[4];
    const float* proj  = (const float*)d_in[5];
    const float* Wq = (const float*)d_in[6];  const float* bq = (const float*)d_in[7];
    const float* Wk = (const float*)d_in[8];  const float* bk = (const float*)d_in[9];
    const float* Wv = (const float*)d_in[10]; const float* bv = (const float*)d_in[11];
    const float* Wo = (const float*)d_in[12]; const float* bo = (const float*)d_in[13];
    const float* ln1g = (const float*)d_in[14]; const float* ln1b = (const float*)d_in[15];
    const float* W1 = (const float*)d_in[16]; const float* b1 = (const float*)d_in[17];
    const float* W2 = (const float*)d_in[18]; const float* b2 = (const float*)d_in[19];
    const float* ln2g = (const float*)d_in[20]; const float* ln2b = (const float*)d_in[21];
    const float* p1w = (const float*)d_in[22]; const float* p1b = (const float*)d_in[23];
    const float* p2w = (const float*)d_in[24]; const float* p2b = (const float*)d_in[25];
    float* out = (float*)d_out;
    char* ws = (char*)d_ws;

    size_t off = 0;
    auto alloc = [&](size_t bytes) { size_t o = off; off += WS_ALIGN(bytes); return o; };
    float* xbuf = (float*)(ws + alloc(16384ull * 256 * 4));
    unsigned short* hbf = (unsigned short*)(ws + alloc(16384ull * 256 * 2));   // ln-out / attn-out
    unsigned short* qbf = (unsigned short*)(ws + alloc(16384ull * 256 * 2));
    unsigned short* kbf = (unsigned short*)(ws + alloc(16384ull * 256 * 2));
    unsigned short* vT  = (unsigned short*)(ws + alloc(16384ull * 256 * 2));
    unsigned short* midbf = (unsigned short*)(ws + alloc(16384ull * 1024 * 2)); // FFN mid
    float* ksum = (float*)(ws + alloc(16ull * 272 * 4));      // zeroed in phi_kmax
    float* ctxP = (float*)(ws + alloc(16ull * 16 * 64 * 272 * 4)); // z-partials (17.8 MB)
    float* pmaxb = (float*)(ws + alloc(1024ull * 4));
    float* alphab = (float*)(ws + alloc(16384ull * 4));
    unsigned short* Wqt = (unsigned short*)(ws + alloc(4ull * 65536 * 2));
    unsigned short* Wkt = (unsigned short*)(ws + alloc(4ull * 65536 * 2));
    unsigned short* Wvt = (unsigned short*)(ws + alloc(4ull * 65536 * 2));
    unsigned short* Wot = (unsigned short*)(ws + alloc(4ull * 65536 * 2));
    unsigned short* W1t = (unsigned short*)(ws + alloc(4ull * 262144 * 2));
    unsigned short* W2t = (unsigned short*)(ws + alloc(4ull * 262144 * 2));
    unsigned short* projbf = (unsigned short*)(ws + alloc(4ull * 20480 * 2)); // padded [L][320][64]
    unsigned short* p1t = (unsigned short*)(ws + alloc(65536ull * 2));
    unsigned short* ctxbf = (unsigned short*)(ws + alloc(16ull * 64 * 288 * 2)); // padded bf16 ctx
    unsigned short* abf = hbf;
    // total ~111 MB (< 256 MiB)

    // ---- memset(d_out) up front: only pool_out depends on it; overlaps prelude ----
    hipMemsetAsync(d_out, 0, (size_t)out_size * sizeof(float), stream);

    // ---- fused prelude: LN(input+pos) + all weight casts in ONE dispatch ----
    prelude_kernel<<<7272, 256, 0, stream>>>(
        input_embs, pos, ln_g, ln_b, ln1g, ln1b, xbuf, hbf,
        Wq, Wk, Wv, Wo, Wqt, Wkt, Wvt, Wot,
        W1, W1t, W2, W2t, p1w, p1t, proj, projbf);

    for (int i = 0; i < 4; i++) {
        const unsigned short* pj = projbf + (size_t)i * 20480;
        // QKV fused (2-phase gload_lds dbuf; coalesced vT epilogue)
        qkv_kernel<<<dim3(12, 128), 256, 0, stream>>>(hbf,
            Wqt + (size_t)i * 65536, Wkt + (size_t)i * 65536, Wvt + (size_t)i * 65536,
            bq + i * 256, bk + i * 256, bv + i * 256, qbf, kbf, vT);
        // k stabilizer block-max + zero ksum
        phi_kmax_kernel<<<dim3(64, 16), 256, 0, stream>>>(kbf, pj, pmaxb, ksum);
        // fused k-exp + ksum + ctx partials (m-halves, reg prefetch, no ctx atomics)
        ctx_fused_kernel<<<dim3(2, 16, 16), 256, 0, stream>>>(kbf, vT, pj, pmaxb, ksum, ctxP);
        // ctx partial reduce (16 z) + cast -> bf16 [bh][64][288] (float4 granularity)
        ctx_reduce_cast_kernel<<<288, 256, 0, stream>>>(ctxP, ctxbf);
        // fused q-side: dash + exp + denom + attn out (ctx async-staged, dbuf'd)
        phi_q_attn_kernel<<<dim3(64, 16), 256, 0, stream>>>(qbf, pj, ksum, ctxbf, abf);
        // Wo + residual + LN2 fused (32-row blocks, 2 blocks/CU)
        gemm_fullrow_kernel<0><<<512, 512, 0, stream>>>(abf, Wot + (size_t)i * 65536,
            bo + i * 256, xbuf, ln2g + i * 256, ln2b + i * 256, hbf,
            nullptr, nullptr, nullptr, nullptr, 256);
        // FFN (2-phase gload_lds dbuf)
        ffn1_kernel<<<dim3(16, 128), 256, 0, stream>>>(hbf, W1t + (size_t)i * 262144,
            b1 + i * 1024, midbf, 1024, 256);
        if (i < 3)
            gemm_fullrow_kernel<0><<<512, 512, 0, stream>>>(midbf, W2t + (size_t)i * 262144,
                b2 + i * 256, xbuf, ln1g + (i + 1) * 256, ln1b + (i + 1) * 256, hbf,
                nullptr, nullptr, nullptr, nullptr, 1024);
        else
            gemm_fullrow_kernel<1><<<512, 512, 0, stream>>>(midbf, W2t + (size_t)i * 262144,
                b2 + i * 256, xbuf, nullptr, nullptr, hbf,
                nullptr, nullptr, nullptr, nullptr, 1024);
    }

    // ---- attention pooling (score fused into GEMM) ----
    gemm_fullrow_kernel<2><<<512, 512, 0, stream>>>(hbf, p1t, p1b, nullptr, nullptr, nullptr,
        nullptr, p2w, p2b, mask, alphab, 256);
    pool_out_kernel<<<dim3(4, 32), 256, 0, stream>>>(xbuf, alphab, out);
}